// Round 4
// baseline (734.434 us; speedup 1.0000x reference)
//
#include <hip/hip_runtime.h>

#define N_CELLS 10000
#define N_GENES 4000
#define CELL_F  2000
#define GENE_F  50
#define HID     256
#define LAT     64
#define NCLUST  20
#define N_EDGES 640000

typedef __attribute__((ext_vector_type(8))) short    bf16x8;
typedef __attribute__((ext_vector_type(8))) unsigned short u16x8;
typedef __attribute__((ext_vector_type(4))) float    f32x4;

__device__ __forceinline__ unsigned short f2bf(float f) {
    unsigned int u = __float_as_uint(f);
    unsigned int r = (u + 0x7FFFu + ((u >> 16) & 1u)) >> 16;
    return (unsigned short)r;
}
__device__ __forceinline__ float bf2f(unsigned short h) {
    return __uint_as_float(((unsigned int)h) << 16);
}

// ---------------- bf16 MFMA GEMM ----------------
// C(M,N) = A(M,K) @ BT(N,K)^T  [+bias]
// A: f32 or bf16(ushort) row-major, stride K. BT: bf16, rows padded to >= grid.x*64.
// Tile 128x64, BK=64, 4 waves; each wave: 32 rows (2 m-frags) x 64 cols (4 n-frags).
template<typename AT, bool BIAS, bool WF32, bool WBF>
__global__ __launch_bounds__(256)
void mfma_gemm(const AT* __restrict__ A, const unsigned short* __restrict__ BT,
               const float* __restrict__ bias, float* __restrict__ C,
               unsigned short* __restrict__ Cbf, int M, int N, int K)
{
    __shared__ __align__(16) unsigned short As[128][72];
    __shared__ __align__(16) unsigned short Bs[64][72];
    const int tid  = threadIdx.x;
    const int row0 = blockIdx.y * 128;
    const int col0 = blockIdx.x * 64;
    const int lane = tid & 63;
    const int w    = tid >> 6;
    const int cn   = lane & 15;
    const int rj   = lane >> 4;

    const bool avec = (sizeof(AT) == 2) ? ((K & 7) == 0) : ((K & 3) == 0);
    const bool bvec = ((K & 7) == 0);

    f32x4 acc[2][4] = {};

    for (int kt = 0; kt < K; kt += 64) {
        // A tile: 128x64 bf16 = 1024 vec8 chunks (8 per row); 4 chunks per thread.
        #pragma unroll
        for (int half = 0; half < 4; ++half) {
            int c = tid + half * 256;
            int r = c >> 3, p = c & 7;
            int gc = kt + p * 8;
            int gr = row0 + r;
            u16x8 v = {0, 0, 0, 0, 0, 0, 0, 0};
            if (gr < M) {
                if constexpr (sizeof(AT) == 2) {
                    const unsigned short* src = (const unsigned short*)A + (size_t)gr * K + gc;
                    if (avec && gc + 8 <= K) {
                        v = *(const u16x8*)src;
                    } else {
                        #pragma unroll
                        for (int j = 0; j < 8; ++j) if (gc + j < K) v[j] = src[j];
                    }
                } else {
                    const float* src = (const float*)A + (size_t)gr * K + gc;
                    if (avec && gc + 8 <= K) {
                        float4 f0 = *(const float4*)src;
                        float4 f1 = *(const float4*)(src + 4);
                        v[0] = f2bf(f0.x); v[1] = f2bf(f0.y); v[2] = f2bf(f0.z); v[3] = f2bf(f0.w);
                        v[4] = f2bf(f1.x); v[5] = f2bf(f1.y); v[6] = f2bf(f1.z); v[7] = f2bf(f1.w);
                    } else {
                        #pragma unroll
                        for (int j = 0; j < 8; ++j) if (gc + j < K) v[j] = f2bf(src[j]);
                    }
                }
            }
            *(u16x8*)&As[r][p * 8] = v;
        }
        // B tile: 64x64 = 512 chunks; 2 per thread. Rows alloc-padded, no guard.
        #pragma unroll
        for (int half = 0; half < 2; ++half) {
            int c = tid + half * 256;
            int r = c >> 3, p = c & 7;
            int gc = kt + p * 8;
            int gn = col0 + r;
            const unsigned short* src = BT + (size_t)gn * K + gc;
            u16x8 v = {0, 0, 0, 0, 0, 0, 0, 0};
            if (bvec && gc + 8 <= K) {
                v = *(const u16x8*)src;
            } else {
                #pragma unroll
                for (int j = 0; j < 8; ++j) if (gc + j < K) v[j] = src[j];
            }
            *(u16x8*)&Bs[r][p * 8] = v;
        }
        __syncthreads();
        #pragma unroll
        for (int kk = 0; kk < 64; kk += 32) {
            bf16x8 a0 = *(const bf16x8*)&As[w * 32 + cn][kk + rj * 8];
            bf16x8 a1 = *(const bf16x8*)&As[w * 32 + 16 + cn][kk + rj * 8];
            #pragma unroll
            for (int f = 0; f < 4; ++f) {
                bf16x8 b = *(const bf16x8*)&Bs[f * 16 + cn][kk + rj * 8];
                acc[0][f] = __builtin_amdgcn_mfma_f32_16x16x32_bf16(a0, b, acc[0][f], 0, 0, 0);
                acc[1][f] = __builtin_amdgcn_mfma_f32_16x16x32_bf16(a1, b, acc[1][f], 0, 0, 0);
            }
        }
        __syncthreads();
    }

    // ---- epilogue: D col = lane&15, row = (lane>>4)*4 + reg  [m89] ----
    #pragma unroll
    for (int mf = 0; mf < 2; ++mf) {
        #pragma unroll
        for (int f = 0; f < 4; ++f) {
            int col = col0 + f * 16 + cn;
            if (col >= N) continue;
            float bv = BIAS ? bias[col] : 0.0f;
            #pragma unroll
            for (int j = 0; j < 4; ++j) {
                int r = row0 + w * 32 + mf * 16 + rj * 4 + j;
                if (r < M) {
                    float val = acc[mf][f][j] + bv;
                    if (WF32) C[(size_t)r * N + col] = val;
                    if (WBF)  Cbf[(size_t)r * N + col] = f2bf(val);
                }
            }
        }
    }
}

// ---- weight pack via LDS transpose: BT[n][k] = [W1 | W2](k, n), bf16 ----
// Coalesced reads (consecutive n) and coalesced writes (consecutive k).
__global__ __launch_bounds__(256)
void pack_bt(const float* __restrict__ W1, const float* __restrict__ W2,
             unsigned short* __restrict__ BT, int K, int N1, int N2, int Np)
{
    __shared__ float tile[32][33];
    int tx = threadIdx.x & 31;        // fast dim
    int ty = threadIdx.x >> 5;        // 0..7
    int k0 = blockIdx.x * 32;
    int n0 = blockIdx.y * 32;
    #pragma unroll
    for (int yy = 0; yy < 4; ++yy) {
        int k = k0 + ty + yy * 8;
        int n = n0 + tx;
        float v = 0.0f;
        if (k < K) {
            if (n < N1) v = W1[(size_t)k * N1 + n];
            else if (n < N1 + N2) v = W2[(size_t)k * N2 + (n - N1)];
        }
        tile[ty + yy * 8][tx] = v;
    }
    __syncthreads();
    #pragma unroll
    for (int yy = 0; yy < 4; ++yy) {
        int n = n0 + ty + yy * 8;
        int k = k0 + tx;
        if (n < Np && k < K)
            BT[(size_t)n * K + k] = f2bf(tile[tx][ty + yy * 8]);
    }
}

// ---------------- CSR construction ----------------
__global__ void count_kernel(const int* __restrict__ er, const int* __restrict__ ec,
                             int* cnt_c, int* cnt_g)
{
    int e = blockIdx.x * blockDim.x + threadIdx.x;
    if (e < N_EDGES) {
        atomicAdd(&cnt_c[er[e]], 1);
        atomicAdd(&cnt_g[ec[e]], 1);
    }
}

// one launch, block 0 = cells, block 1 = genes; also seeds cur = ptr
__global__ __launch_bounds__(1024)
void scan2_kernel(const int* __restrict__ cnt_c, int* __restrict__ ptr_c, int* __restrict__ cur_c,
                  const int* __restrict__ cnt_g, int* __restrict__ ptr_g, int* __restrict__ cur_g)
{
    const int* cnt = blockIdx.x ? cnt_g : cnt_c;
    int* ptr = blockIdx.x ? ptr_g : ptr_c;
    int* cur = blockIdx.x ? cur_g : cur_c;
    int  n   = blockIdx.x ? N_GENES : N_CELLS;
    __shared__ int part[1024];
    int t = threadIdx.x;
    int chunk = (n + 1023) / 1024;
    int lo = t * chunk, hi = min(lo + chunk, n);
    int s = 0;
    for (int i = lo; i < hi; ++i) s += cnt[i];
    part[t] = s;
    __syncthreads();
    if (t == 0) {
        int run = 0;
        for (int i = 0; i < 1024; ++i) { int tmp = part[i]; part[i] = run; run += tmp; }
        ptr[n] = run;
    }
    __syncthreads();
    int run = part[t];
    for (int i = lo; i < hi; ++i) { ptr[i] = run; cur[i] = run; run += cnt[i]; }
}

__global__ void scatter_kernel(const int* __restrict__ er, const int* __restrict__ ec,
                               const float* __restrict__ ev,
                               int* cur_c, int* cur_g,
                               int* __restrict__ ci, float* __restrict__ cv,
                               int* __restrict__ gi, float* __restrict__ gv)
{
    int e = blockIdx.x * blockDim.x + threadIdx.x;
    if (e < N_EDGES) {
        int r = er[e], c = ec[e];
        float v = ev[e];
        int pc = atomicAdd(&cur_c[r], 1);
        ci[pc] = c; cv[pc] = v;
        int pg = atomicAdd(&cur_g[c], 1);
        gi[pg] = r; gv[pg] = v;
    }
}

// ---- fused segment-sum + residual + biases + relu; bf16 in/out, f32 math ----
// Wave-per-row, barrier-free. Lane handles 4 dims via ushort4 (8 B/lane).
// out[r,:] = relu(pre[r,0:256] + sum_e val[e]*src[nbr[e],256:512] + b1 + b2)
__global__ __launch_bounds__(256)
void agg_kernel(const int* __restrict__ ptr, const int* __restrict__ nbr,
                const float* __restrict__ val,
                const unsigned short* __restrict__ srcbf,  // stride 512, cols 256..511
                const unsigned short* __restrict__ prebf,  // stride 512, cols 0..255
                const float* __restrict__ b1, const float* __restrict__ b2,
                unsigned short* __restrict__ outbf,        // stride 256
                int nrows)
{
    int w = threadIdx.x >> 6;
    int lane = threadIdx.x & 63;
    int r = blockIdx.x * 4 + w;
    if (r >= nrows) return;
    int s = ptr[r], e = ptr[r + 1];
    const ushort4* src4 = (const ushort4*)srcbf;   // row stride 128 vec4, +64 = neigh half
    float4 acc = {0.0f, 0.0f, 0.0f, 0.0f};
    int i = s;
    for (; i + 1 < e; i += 2) {
        int   j0 = nbr[i],   j1 = nbr[i + 1];
        float v0 = val[i],   v1 = val[i + 1];
        ushort4 a = src4[(size_t)j0 * 128 + 64 + lane];
        ushort4 b = src4[(size_t)j1 * 128 + 64 + lane];
        acc.x += v0 * bf2f(a.x) + v1 * bf2f(b.x);
        acc.y += v0 * bf2f(a.y) + v1 * bf2f(b.y);
        acc.z += v0 * bf2f(a.z) + v1 * bf2f(b.z);
        acc.w += v0 * bf2f(a.w) + v1 * bf2f(b.w);
    }
    if (i < e) {
        int j0 = nbr[i]; float v0 = val[i];
        ushort4 a = src4[(size_t)j0 * 128 + 64 + lane];
        acc.x += v0 * bf2f(a.x);
        acc.y += v0 * bf2f(a.y);
        acc.z += v0 * bf2f(a.z);
        acc.w += v0 * bf2f(a.w);
    }
    ushort4 pr = ((const ushort4*)prebf)[(size_t)r * 128 + lane];
    float4 bb1 = ((const float4*)b1)[lane];
    float4 bb2 = ((const float4*)b2)[lane];
    ushort4 o;
    o.x = f2bf(fmaxf(bf2f(pr.x) + acc.x + bb1.x + bb2.x, 0.0f));
    o.y = f2bf(fmaxf(bf2f(pr.y) + acc.y + bb1.y + bb2.y, 0.0f));
    o.z = f2bf(fmaxf(bf2f(pr.z) + acc.z + bb1.z + bb2.z, 0.0f));
    o.w = f2bf(fmaxf(bf2f(pr.w) + acc.w + bb1.w + bb2.w, 0.0f));
    ((ushort4*)outbf)[(size_t)r * 64 + lane] = o;
}

// ---------------- Student-t cluster assignment (ALPHA=1) ----------------
__global__ __launch_bounds__(256)
void q_kernel(const float* __restrict__ z, const float* __restrict__ centers,
              float* __restrict__ q)
{
    __shared__ float cs[NCLUST * LAT];
    int tid = threadIdx.x;
    for (int l = tid; l < NCLUST * LAT; l += 256) cs[l] = centers[l];
    __syncthreads();
    int c = blockIdx.x * 256 + tid;
    if (c >= N_CELLS) return;
    float zr[LAT];
    #pragma unroll
    for (int k = 0; k < LAT; ++k) zr[k] = z[(size_t)c * LAT + k];
    float num[NCLUST];
    float denom = 0.0f;
    for (int j = 0; j < NCLUST; ++j) {
        float d = 0.0f;
        #pragma unroll
        for (int k = 0; k < LAT; ++k) {
            float t = zr[k] - cs[j * LAT + k];
            d += t * t;
        }
        float n = 1.0f / (1.0f + d);
        num[j] = n;
        denom += n;
    }
    float inv = 1.0f / denom;
    for (int j = 0; j < NCLUST; ++j) q[(size_t)c * NCLUST + j] = num[j] * inv;
}

extern "C" void kernel_launch(void* const* d_in, const int* in_sizes, int n_in,
                              void* d_out, int out_size, void* d_ws, size_t ws_size,
                              hipStream_t stream)
{
    const float* cell_x  = (const float*)d_in[0];
    const float* gene_x  = (const float*)d_in[1];
    const int*   er      = (const int*)d_in[2];
    const int*   ec      = (const int*)d_in[3];
    const float* ev      = (const float*)d_in[4];
    const float* l0_cs_w = (const float*)d_in[5];  const float* l0_cs_b = (const float*)d_in[6];
    const float* l0_cn_w = (const float*)d_in[7];  const float* l0_cn_b = (const float*)d_in[8];
    const float* l0_gs_w = (const float*)d_in[9];  const float* l0_gs_b = (const float*)d_in[10];
    const float* l0_gn_w = (const float*)d_in[11]; const float* l0_gn_b = (const float*)d_in[12];
    const float* l1_cs_w = (const float*)d_in[13]; const float* l1_cs_b = (const float*)d_in[14];
    const float* l1_cn_w = (const float*)d_in[15]; const float* l1_cn_b = (const float*)d_in[16];
    const float* l1_gs_w = (const float*)d_in[17]; const float* l1_gs_b = (const float*)d_in[18];
    const float* l1_gn_w = (const float*)d_in[19]; const float* l1_gn_b = (const float*)d_in[20];
    const float* cl_w = (const float*)d_in[21]; const float* cl_b = (const float*)d_in[22];
    const float* gl_w = (const float*)d_in[23]; const float* gl_b = (const float*)d_in[24];
    const float* cd_w = (const float*)d_in[25]; const float* cd_b = (const float*)d_in[26];
    const float* gd_w = (const float*)d_in[27]; const float* gd_b = (const float*)d_in[28];
    const float* centers = (const float*)d_in[29];

    float* out = (float*)d_out;
    float* z_cells    = out;                       // 10000*64
    float* z_genes    = out + 640000;              // 4000*64
    float* cell_recon = out + 896000;              // 10000*4000
    float* gene_recon = out + 40896000;            // 4000*10000
    float* q          = out + 80896000;            // 10000*20

    // ---- workspace arena (~46 MB, 256B-aligned blocks) ----
    char* wsp = (char*)d_ws;
    auto alloc = [&](size_t bytes) -> void* {
        void* p = (void*)wsp;
        wsp += (bytes + 255) & ~(size_t)255;
        return p;
    };
    unsigned short* pre_c_bf = (unsigned short*)alloc((size_t)N_CELLS * 512 * 2);
    unsigned short* pre_g_bf = (unsigned short*)alloc((size_t)N_GENES * 512 * 2);
    unsigned short* c1_bf    = (unsigned short*)alloc((size_t)N_CELLS * 256 * 2);
    unsigned short* g1_bf    = (unsigned short*)alloc((size_t)N_GENES * 256 * 2);
    unsigned short* c2_bf    = (unsigned short*)alloc((size_t)N_CELLS * 256 * 2);
    unsigned short* g2_bf    = (unsigned short*)alloc((size_t)N_GENES * 256 * 2);
    unsigned short* zc_bf    = (unsigned short*)alloc((size_t)N_CELLS * 64 * 2);
    unsigned short* zg_bf    = (unsigned short*)alloc((size_t)N_GENES * 64 * 2);
    unsigned short* W0cT = (unsigned short*)alloc((size_t)512 * CELL_F * 2);
    unsigned short* W0gT = (unsigned short*)alloc((size_t)512 * GENE_F * 2);
    unsigned short* W1cT = (unsigned short*)alloc((size_t)512 * HID * 2);
    unsigned short* W1gT = (unsigned short*)alloc((size_t)512 * HID * 2);
    unsigned short* WzcT = (unsigned short*)alloc((size_t)64 * HID * 2);
    unsigned short* WzgT = (unsigned short*)alloc((size_t)64 * HID * 2);
    unsigned short* WdcT = (unsigned short*)alloc((size_t)4032 * 64 * 2);
    unsigned short* WdgT = (unsigned short*)alloc((size_t)10048 * 64 * 2);
    int* cnt_c = (int*)alloc((size_t)(N_CELLS + N_GENES) * 4);   // cnt_c + cnt_g contiguous
    int* cnt_g = cnt_c + N_CELLS;
    int* ptr_c = (int*)alloc((size_t)(N_CELLS + 1) * 4);
    int* ptr_g = (int*)alloc((size_t)(N_GENES + 1) * 4);
    int* cur_c = (int*)alloc((size_t)N_CELLS * 4);
    int* cur_g = (int*)alloc((size_t)N_GENES * 4);
    int*   ci = (int*)alloc((size_t)N_EDGES * 4);
    float* cv = (float*)alloc((size_t)N_EDGES * 4);
    int*   gi = (int*)alloc((size_t)N_EDGES * 4);
    float* gv = (float*)alloc((size_t)N_EDGES * 4);

    // ---- CSR build ----
    hipMemsetAsync(cnt_c, 0, (size_t)(N_CELLS + N_GENES) * 4, stream);
    count_kernel<<<(N_EDGES + 255) / 256, 256, 0, stream>>>(er, ec, cnt_c, cnt_g);
    scan2_kernel<<<2, 1024, 0, stream>>>(cnt_c, ptr_c, cur_c, cnt_g, ptr_g, cur_g);
    scatter_kernel<<<(N_EDGES + 255) / 256, 256, 0, stream>>>(er, ec, ev, cur_c, cur_g,
                                                              ci, cv, gi, gv);

    // ---- weight packs (bf16, transposed, N-concat), LDS-tiled transpose ----
    auto packs = [&](const float* W1, const float* W2, unsigned short* BT,
                     int K, int N1, int N2, int Np) {
        pack_bt<<<dim3((K + 31) / 32, (Np + 31) / 32), 256, 0, stream>>>(W1, W2, BT, K, N1, N2, Np);
    };
    packs(l0_cs_w, l0_gn_w, W0cT, CELL_F, HID, HID, 512);
    packs(l0_gs_w, l0_cn_w, W0gT, GENE_F, HID, HID, 512);
    packs(l1_cs_w, l1_gn_w, W1cT, HID, HID, HID, 512);
    packs(l1_gs_w, l1_cn_w, W1gT, HID, HID, HID, 512);
    packs(cl_w, nullptr, WzcT, HID, LAT, 0, 64);
    packs(gl_w, nullptr, WzgT, HID, LAT, 0, 64);
    packs(cd_w, nullptr, WdcT, LAT, N_GENES, 0, 4032);
    packs(gd_w, nullptr, WdgT, LAT, N_CELLS, 0, 10048);

    #define GRID(Mv, Nv) dim3(((Nv) + 63) / 64, ((Mv) + 127) / 128)

    // ---- layer 0: [self | neigh] projections ----
    mfma_gemm<float, false, false, true><<<GRID(N_CELLS, 512), 256, 0, stream>>>(
        cell_x, W0cT, nullptr, nullptr, pre_c_bf, N_CELLS, 512, CELL_F);
    mfma_gemm<float, false, false, true><<<GRID(N_GENES, 512), 256, 0, stream>>>(
        gene_x, W0gT, nullptr, nullptr, pre_g_bf, N_GENES, 512, GENE_F);

    agg_kernel<<<(N_CELLS + 3) / 4, 256, 0, stream>>>(ptr_c, ci, cv, pre_g_bf, pre_c_bf,
                                                      l0_cs_b, l0_cn_b, c1_bf, N_CELLS);
    agg_kernel<<<(N_GENES + 3) / 4, 256, 0, stream>>>(ptr_g, gi, gv, pre_c_bf, pre_g_bf,
                                                      l0_gs_b, l0_gn_b, g1_bf, N_GENES);

    // ---- layer 1 ----
    mfma_gemm<unsigned short, false, false, true><<<GRID(N_CELLS, 512), 256, 0, stream>>>(
        c1_bf, W1cT, nullptr, nullptr, pre_c_bf, N_CELLS, 512, HID);
    mfma_gemm<unsigned short, false, false, true><<<GRID(N_GENES, 512), 256, 0, stream>>>(
        g1_bf, W1gT, nullptr, nullptr, pre_g_bf, N_GENES, 512, HID);

    agg_kernel<<<(N_CELLS + 3) / 4, 256, 0, stream>>>(ptr_c, ci, cv, pre_g_bf, pre_c_bf,
                                                      l1_cs_b, l1_cn_b, c2_bf, N_CELLS);
    agg_kernel<<<(N_GENES + 3) / 4, 256, 0, stream>>>(ptr_g, gi, gv, pre_c_bf, pre_g_bf,
                                                      l1_gs_b, l1_gn_b, g2_bf, N_GENES);

    // ---- latent heads (f32 to d_out + bf16 for decoders) ----
    mfma_gemm<unsigned short, true, true, true><<<GRID(N_CELLS, LAT), 256, 0, stream>>>(
        c2_bf, WzcT, cl_b, z_cells, zc_bf, N_CELLS, LAT, HID);
    mfma_gemm<unsigned short, true, true, true><<<GRID(N_GENES, LAT), 256, 0, stream>>>(
        g2_bf, WzgT, gl_b, z_genes, zg_bf, N_GENES, LAT, HID);

    // ---- decoders ----
    mfma_gemm<unsigned short, true, true, false><<<GRID(N_CELLS, N_GENES), 256, 0, stream>>>(
        zc_bf, WdcT, cd_b, cell_recon, nullptr, N_CELLS, N_GENES, LAT);
    mfma_gemm<unsigned short, true, true, false><<<GRID(N_GENES, N_CELLS), 256, 0, stream>>>(
        zg_bf, WdgT, gd_b, gene_recon, nullptr, N_GENES, N_CELLS, LAT);

    // ---- DEC soft assignment ----
    q_kernel<<<(N_CELLS + 255) / 256, 256, 0, stream>>>(z_cells, centers, q);
}

// Round 5
// 697.323 us; speedup vs baseline: 1.0532x; 1.0532x over previous
//
#include <hip/hip_runtime.h>

#define N_CELLS 10000
#define N_GENES 4000
#define CELL_F  2000
#define GENE_F  50
#define HID     256
#define LAT     64
#define NCLUST  20
#define N_EDGES 640000

typedef __attribute__((ext_vector_type(8))) short    bf16x8;
typedef __attribute__((ext_vector_type(8))) unsigned short u16x8;
typedef __attribute__((ext_vector_type(4))) float    f32x4;

__device__ __forceinline__ unsigned short f2bf(float f) {
    unsigned int u = __float_as_uint(f);
    unsigned int r = (u + 0x7FFFu + ((u >> 16) & 1u)) >> 16;
    return (unsigned short)r;
}
__device__ __forceinline__ float bf2f(unsigned short h) {
    return __uint_as_float(((unsigned int)h) << 16);
}

// ---------------- bf16 MFMA GEMM (round-3 proven 64x64 tile) ----------------
// C(M,N) = A(M,K) @ BT(N,K)^T  [+bias]
// A: f32 or bf16(ushort) row-major, stride K. BT: bf16, rows padded to >= grid.x*64.
// Tile 64x64, BK=64, 4 waves (each: 16 rows x 64 cols via 4 col-fragments).
template<typename AT, bool BIAS, bool WF32, bool WBF>
__global__ __launch_bounds__(256)
void mfma_gemm(const AT* __restrict__ A, const unsigned short* __restrict__ BT,
               const float* __restrict__ bias, float* __restrict__ C,
               unsigned short* __restrict__ Cbf, int M, int N, int K)
{
    __shared__ __align__(16) unsigned short As[64][72];
    __shared__ __align__(16) unsigned short Bs[64][72];
    const int tid  = threadIdx.x;
    const int row0 = blockIdx.y * 64;
    const int col0 = blockIdx.x * 64;
    const int lane = tid & 63;
    const int w    = tid >> 6;
    const int cn   = lane & 15;
    const int rj   = lane >> 4;

    const bool avec = (sizeof(AT) == 2) ? ((K & 7) == 0) : ((K & 3) == 0);
    const bool bvec = ((K & 7) == 0);

    f32x4 acc[4] = {};

    for (int kt = 0; kt < K; kt += 64) {
        // 64x64 bf16 tile = 512 vec8 chunks; 8 chunks per row.
        #pragma unroll
        for (int half = 0; half < 2; ++half) {
            int c = tid + half * 256;
            int r = c >> 3, p = c & 7;
            int gc = kt + p * 8;
            // ---- A tile ----
            {
                int gr = row0 + r;
                u16x8 v = {0, 0, 0, 0, 0, 0, 0, 0};
                if (gr < M) {
                    if constexpr (sizeof(AT) == 2) {
                        const unsigned short* src = (const unsigned short*)A + (size_t)gr * K + gc;
                        if (avec && gc + 8 <= K) {
                            v = *(const u16x8*)src;
                        } else {
                            #pragma unroll
                            for (int j = 0; j < 8; ++j) if (gc + j < K) v[j] = src[j];
                        }
                    } else {
                        const float* src = (const float*)A + (size_t)gr * K + gc;
                        if (avec && gc + 8 <= K) {
                            float4 f0 = *(const float4*)src;
                            float4 f1 = *(const float4*)(src + 4);
                            v[0] = f2bf(f0.x); v[1] = f2bf(f0.y); v[2] = f2bf(f0.z); v[3] = f2bf(f0.w);
                            v[4] = f2bf(f1.x); v[5] = f2bf(f1.y); v[6] = f2bf(f1.z); v[7] = f2bf(f1.w);
                        } else {
                            #pragma unroll
                            for (int j = 0; j < 8; ++j) if (gc + j < K) v[j] = f2bf(src[j]);
                        }
                    }
                }
                *(u16x8*)&As[r][p * 8] = v;
            }
            // ---- B tile (BT rows are alloc-padded, no row guard needed) ----
            {
                int gn = col0 + r;
                const unsigned short* src = BT + (size_t)gn * K + gc;
                u16x8 v = {0, 0, 0, 0, 0, 0, 0, 0};
                if (bvec && gc + 8 <= K) {
                    v = *(const u16x8*)src;
                } else {
                    #pragma unroll
                    for (int j = 0; j < 8; ++j) if (gc + j < K) v[j] = src[j];
                }
                *(u16x8*)&Bs[r][p * 8] = v;
            }
        }
        __syncthreads();
        #pragma unroll
        for (int kk = 0; kk < 64; kk += 32) {
            bf16x8 a = *(const bf16x8*)&As[w * 16 + cn][kk + rj * 8];
            #pragma unroll
            for (int f = 0; f < 4; ++f) {
                bf16x8 b = *(const bf16x8*)&Bs[f * 16 + cn][kk + rj * 8];
                acc[f] = __builtin_amdgcn_mfma_f32_16x16x32_bf16(a, b, acc[f], 0, 0, 0);
            }
        }
        __syncthreads();
    }

    // ---- epilogue: D col = lane&15, row = (lane>>4)*4 + reg  [m89] ----
    #pragma unroll
    for (int f = 0; f < 4; ++f) {
        int col = col0 + f * 16 + cn;
        if (col >= N) continue;
        float bv = BIAS ? bias[col] : 0.0f;
        #pragma unroll
        for (int j = 0; j < 4; ++j) {
            int r = row0 + w * 16 + rj * 4 + j;
            if (r < M) {
                float val = acc[f][j] + bv;
                if (WF32) C[(size_t)r * N + col] = val;
                if (WBF)  Cbf[(size_t)r * N + col] = f2bf(val);
            }
        }
    }
}

// ---- weight pack via LDS transpose: BT[n][k] = [W1 | W2](k, n), bf16 ----
__global__ __launch_bounds__(256)
void pack_bt(const float* __restrict__ W1, const float* __restrict__ W2,
             unsigned short* __restrict__ BT, int K, int N1, int N2, int Np)
{
    __shared__ float tile[32][33];
    int tx = threadIdx.x & 31;        // fast dim
    int ty = threadIdx.x >> 5;        // 0..7
    int k0 = blockIdx.x * 32;
    int n0 = blockIdx.y * 32;
    #pragma unroll
    for (int yy = 0; yy < 4; ++yy) {
        int k = k0 + ty + yy * 8;
        int n = n0 + tx;
        float v = 0.0f;
        if (k < K) {
            if (n < N1) v = W1[(size_t)k * N1 + n];
            else if (n < N1 + N2) v = W2[(size_t)k * N2 + (n - N1)];
        }
        tile[ty + yy * 8][tx] = v;
    }
    __syncthreads();
    #pragma unroll
    for (int yy = 0; yy < 4; ++yy) {
        int n = n0 + ty + yy * 8;
        int k = k0 + tx;
        if (n < Np && k < K)
            BT[(size_t)n * K + k] = f2bf(tile[tx][ty + yy * 8]);
    }
}

// ---------------- CSR construction ----------------
__global__ void count_kernel(const int* __restrict__ er, const int* __restrict__ ec,
                             int* cnt_c, int* cnt_g)
{
    int e = blockIdx.x * blockDim.x + threadIdx.x;
    if (e < N_EDGES) {
        atomicAdd(&cnt_c[er[e]], 1);
        atomicAdd(&cnt_g[ec[e]], 1);
    }
}

// one launch, block 0 = cells, block 1 = genes; also seeds cur = ptr
__global__ __launch_bounds__(1024)
void scan2_kernel(const int* __restrict__ cnt_c, int* __restrict__ ptr_c, int* __restrict__ cur_c,
                  const int* __restrict__ cnt_g, int* __restrict__ ptr_g, int* __restrict__ cur_g)
{
    const int* cnt = blockIdx.x ? cnt_g : cnt_c;
    int* ptr = blockIdx.x ? ptr_g : ptr_c;
    int* cur = blockIdx.x ? cur_g : cur_c;
    int  n   = blockIdx.x ? N_GENES : N_CELLS;
    __shared__ int part[1024];
    int t = threadIdx.x;
    int chunk = (n + 1023) / 1024;
    int lo = t * chunk, hi = min(lo + chunk, n);
    int s = 0;
    for (int i = lo; i < hi; ++i) s += cnt[i];
    part[t] = s;
    __syncthreads();
    if (t == 0) {
        int run = 0;
        for (int i = 0; i < 1024; ++i) { int tmp = part[i]; part[i] = run; run += tmp; }
        ptr[n] = run;
    }
    __syncthreads();
    int run = part[t];
    for (int i = lo; i < hi; ++i) { ptr[i] = run; cur[i] = run; run += cnt[i]; }
}

__global__ void scatter_kernel(const int* __restrict__ er, const int* __restrict__ ec,
                               const float* __restrict__ ev,
                               int* cur_c, int* cur_g,
                               int* __restrict__ ci, float* __restrict__ cv,
                               int* __restrict__ gi, float* __restrict__ gv)
{
    int e = blockIdx.x * blockDim.x + threadIdx.x;
    if (e < N_EDGES) {
        int r = er[e], c = ec[e];
        float v = ev[e];
        int pc = atomicAdd(&cur_c[r], 1);
        ci[pc] = c; cv[pc] = v;
        int pg = atomicAdd(&cur_g[c], 1);
        gi[pg] = r; gv[pg] = v;
    }
}

// ---- fused segment-sum + residual + biases + relu; bf16 in/out, f32 math ----
// Wave-per-row, barrier-free. Lane handles 4 dims via ushort4 (8 B/lane).
// out[r,:] = relu(pre[r,0:256] + sum_e val[e]*src[nbr[e],256:512] + b1 + b2)
__global__ __launch_bounds__(256)
void agg_kernel(const int* __restrict__ ptr, const int* __restrict__ nbr,
                const float* __restrict__ val,
                const unsigned short* __restrict__ srcbf,  // stride 512, cols 256..511
                const unsigned short* __restrict__ prebf,  // stride 512, cols 0..255
                const float* __restrict__ b1, const float* __restrict__ b2,
                unsigned short* __restrict__ outbf,        // stride 256
                int nrows)
{
    int w = threadIdx.x >> 6;
    int lane = threadIdx.x & 63;
    int r = blockIdx.x * 4 + w;
    if (r >= nrows) return;
    int s = ptr[r], e = ptr[r + 1];
    const ushort4* src4 = (const ushort4*)srcbf;   // row stride 128 vec4, +64 = neigh half
    float4 acc = {0.0f, 0.0f, 0.0f, 0.0f};
    int i = s;
    for (; i + 1 < e; i += 2) {
        int   j0 = nbr[i],   j1 = nbr[i + 1];
        float v0 = val[i],   v1 = val[i + 1];
        ushort4 a = src4[(size_t)j0 * 128 + 64 + lane];
        ushort4 b = src4[(size_t)j1 * 128 + 64 + lane];
        acc.x += v0 * bf2f(a.x) + v1 * bf2f(b.x);
        acc.y += v0 * bf2f(a.y) + v1 * bf2f(b.y);
        acc.z += v0 * bf2f(a.z) + v1 * bf2f(b.z);
        acc.w += v0 * bf2f(a.w) + v1 * bf2f(b.w);
    }
    if (i < e) {
        int j0 = nbr[i]; float v0 = val[i];
        ushort4 a = src4[(size_t)j0 * 128 + 64 + lane];
        acc.x += v0 * bf2f(a.x);
        acc.y += v0 * bf2f(a.y);
        acc.z += v0 * bf2f(a.z);
        acc.w += v0 * bf2f(a.w);
    }
    ushort4 pr = ((const ushort4*)prebf)[(size_t)r * 128 + lane];
    float4 bb1 = ((const float4*)b1)[lane];
    float4 bb2 = ((const float4*)b2)[lane];
    ushort4 o;
    o.x = f2bf(fmaxf(bf2f(pr.x) + acc.x + bb1.x + bb2.x, 0.0f));
    o.y = f2bf(fmaxf(bf2f(pr.y) + acc.y + bb1.y + bb2.y, 0.0f));
    o.z = f2bf(fmaxf(bf2f(pr.z) + acc.z + bb1.z + bb2.z, 0.0f));
    o.w = f2bf(fmaxf(bf2f(pr.w) + acc.w + bb1.w + bb2.w, 0.0f));
    ((ushort4*)outbf)[(size_t)r * 64 + lane] = o;
}

// ---------------- Student-t cluster assignment (ALPHA=1) ----------------
__global__ __launch_bounds__(256)
void q_kernel(const float* __restrict__ z, const float* __restrict__ centers,
              float* __restrict__ q)
{
    __shared__ float cs[NCLUST * LAT];
    int tid = threadIdx.x;
    for (int l = tid; l < NCLUST * LAT; l += 256) cs[l] = centers[l];
    __syncthreads();
    int c = blockIdx.x * 256 + tid;
    if (c >= N_CELLS) return;
    float zr[LAT];
    #pragma unroll
    for (int k = 0; k < LAT; ++k) zr[k] = z[(size_t)c * LAT + k];
    float num[NCLUST];
    float denom = 0.0f;
    for (int j = 0; j < NCLUST; ++j) {
        float d = 0.0f;
        #pragma unroll
        for (int k = 0; k < LAT; ++k) {
            float t = zr[k] - cs[j * LAT + k];
            d += t * t;
        }
        float n = 1.0f / (1.0f + d);
        num[j] = n;
        denom += n;
    }
    float inv = 1.0f / denom;
    for (int j = 0; j < NCLUST; ++j) q[(size_t)c * NCLUST + j] = num[j] * inv;
}

extern "C" void kernel_launch(void* const* d_in, const int* in_sizes, int n_in,
                              void* d_out, int out_size, void* d_ws, size_t ws_size,
                              hipStream_t stream)
{
    const float* cell_x  = (const float*)d_in[0];
    const float* gene_x  = (const float*)d_in[1];
    const int*   er      = (const int*)d_in[2];
    const int*   ec      = (const int*)d_in[3];
    const float* ev      = (const float*)d_in[4];
    const float* l0_cs_w = (const float*)d_in[5];  const float* l0_cs_b = (const float*)d_in[6];
    const float* l0_cn_w = (const float*)d_in[7];  const float* l0_cn_b = (const float*)d_in[8];
    const float* l0_gs_w = (const float*)d_in[9];  const float* l0_gs_b = (const float*)d_in[10];
    const float* l0_gn_w = (const float*)d_in[11]; const float* l0_gn_b = (const float*)d_in[12];
    const float* l1_cs_w = (const float*)d_in[13]; const float* l1_cs_b = (const float*)d_in[14];
    const float* l1_cn_w = (const float*)d_in[15]; const float* l1_cn_b = (const float*)d_in[16];
    const float* l1_gs_w = (const float*)d_in[17]; const float* l1_gs_b = (const float*)d_in[18];
    const float* l1_gn_w = (const float*)d_in[19]; const float* l1_gn_b = (const float*)d_in[20];
    const float* cl_w = (const float*)d_in[21]; const float* cl_b = (const float*)d_in[22];
    const float* gl_w = (const float*)d_in[23]; const float* gl_b = (const float*)d_in[24];
    const float* cd_w = (const float*)d_in[25]; const float* cd_b = (const float*)d_in[26];
    const float* gd_w = (const float*)d_in[27]; const float* gd_b = (const float*)d_in[28];
    const float* centers = (const float*)d_in[29];

    float* out = (float*)d_out;
    float* z_cells    = out;                       // 10000*64
    float* z_genes    = out + 640000;              // 4000*64
    float* cell_recon = out + 896000;              // 10000*4000
    float* gene_recon = out + 40896000;            // 4000*10000
    float* q          = out + 80896000;            // 10000*20

    // ---- workspace arena (~46 MB, 256B-aligned blocks) ----
    char* wsp = (char*)d_ws;
    auto alloc = [&](size_t bytes) -> void* {
        void* p = (void*)wsp;
        wsp += (bytes + 255) & ~(size_t)255;
        return p;
    };
    unsigned short* pre_c_bf = (unsigned short*)alloc((size_t)N_CELLS * 512 * 2);
    unsigned short* pre_g_bf = (unsigned short*)alloc((size_t)N_GENES * 512 * 2);
    unsigned short* c1_bf    = (unsigned short*)alloc((size_t)N_CELLS * 256 * 2);
    unsigned short* g1_bf    = (unsigned short*)alloc((size_t)N_GENES * 256 * 2);
    unsigned short* c2_bf    = (unsigned short*)alloc((size_t)N_CELLS * 256 * 2);
    unsigned short* g2_bf    = (unsigned short*)alloc((size_t)N_GENES * 256 * 2);
    unsigned short* zc_bf    = (unsigned short*)alloc((size_t)N_CELLS * 64 * 2);
    unsigned short* zg_bf    = (unsigned short*)alloc((size_t)N_GENES * 64 * 2);
    unsigned short* W0cT = (unsigned short*)alloc((size_t)512 * CELL_F * 2);
    unsigned short* W0gT = (unsigned short*)alloc((size_t)512 * GENE_F * 2);
    unsigned short* W1cT = (unsigned short*)alloc((size_t)512 * HID * 2);
    unsigned short* W1gT = (unsigned short*)alloc((size_t)512 * HID * 2);
    unsigned short* WzcT = (unsigned short*)alloc((size_t)64 * HID * 2);
    unsigned short* WzgT = (unsigned short*)alloc((size_t)64 * HID * 2);
    unsigned short* WdcT = (unsigned short*)alloc((size_t)4032 * 64 * 2);
    unsigned short* WdgT = (unsigned short*)alloc((size_t)10048 * 64 * 2);
    int* cnt_c = (int*)alloc((size_t)(N_CELLS + N_GENES) * 4);   // cnt_c + cnt_g contiguous
    int* cnt_g = cnt_c + N_CELLS;
    int* ptr_c = (int*)alloc((size_t)(N_CELLS + 1) * 4);
    int* ptr_g = (int*)alloc((size_t)(N_GENES + 1) * 4);
    int* cur_c = (int*)alloc((size_t)N_CELLS * 4);
    int* cur_g = (int*)alloc((size_t)N_GENES * 4);
    int*   ci = (int*)alloc((size_t)N_EDGES * 4);
    float* cv = (float*)alloc((size_t)N_EDGES * 4);
    int*   gi = (int*)alloc((size_t)N_EDGES * 4);
    float* gv = (float*)alloc((size_t)N_EDGES * 4);

    // ---- CSR build ----
    hipMemsetAsync(cnt_c, 0, (size_t)(N_CELLS + N_GENES) * 4, stream);
    count_kernel<<<(N_EDGES + 255) / 256, 256, 0, stream>>>(er, ec, cnt_c, cnt_g);
    scan2_kernel<<<2, 1024, 0, stream>>>(cnt_c, ptr_c, cur_c, cnt_g, ptr_g, cur_g);
    scatter_kernel<<<(N_EDGES + 255) / 256, 256, 0, stream>>>(er, ec, ev, cur_c, cur_g,
                                                              ci, cv, gi, gv);

    // ---- weight packs (bf16, transposed, N-concat), LDS-tiled transpose ----
    auto packs = [&](const float* W1, const float* W2, unsigned short* BT,
                     int K, int N1, int N2, int Np) {
        pack_bt<<<dim3((K + 31) / 32, (Np + 31) / 32), 256, 0, stream>>>(W1, W2, BT, K, N1, N2, Np);
    };
    packs(l0_cs_w, l0_gn_w, W0cT, CELL_F, HID, HID, 512);
    packs(l0_gs_w, l0_cn_w, W0gT, GENE_F, HID, HID, 512);
    packs(l1_cs_w, l1_gn_w, W1cT, HID, HID, HID, 512);
    packs(l1_gs_w, l1_cn_w, W1gT, HID, HID, HID, 512);
    packs(cl_w, nullptr, WzcT, HID, LAT, 0, 64);
    packs(gl_w, nullptr, WzgT, HID, LAT, 0, 64);
    packs(cd_w, nullptr, WdcT, LAT, N_GENES, 0, 4032);
    packs(gd_w, nullptr, WdgT, LAT, N_CELLS, 0, 10048);

    #define GRID(Mv, Nv) dim3(((Nv) + 63) / 64, ((Mv) + 63) / 64)

    // ---- layer 0: [self | neigh] projections ----
    mfma_gemm<float, false, false, true><<<GRID(N_CELLS, 512), 256, 0, stream>>>(
        cell_x, W0cT, nullptr, nullptr, pre_c_bf, N_CELLS, 512, CELL_F);
    mfma_gemm<float, false, false, true><<<GRID(N_GENES, 512), 256, 0, stream>>>(
        gene_x, W0gT, nullptr, nullptr, pre_g_bf, N_GENES, 512, GENE_F);

    agg_kernel<<<(N_CELLS + 3) / 4, 256, 0, stream>>>(ptr_c, ci, cv, pre_g_bf, pre_c_bf,
                                                      l0_cs_b, l0_cn_b, c1_bf, N_CELLS);
    agg_kernel<<<(N_GENES + 3) / 4, 256, 0, stream>>>(ptr_g, gi, gv, pre_c_bf, pre_g_bf,
                                                      l0_gs_b, l0_gn_b, g1_bf, N_GENES);

    // ---- layer 1 ----
    mfma_gemm<unsigned short, false, false, true><<<GRID(N_CELLS, 512), 256, 0, stream>>>(
        c1_bf, W1cT, nullptr, nullptr, pre_c_bf, N_CELLS, 512, HID);
    mfma_gemm<unsigned short, false, false, true><<<GRID(N_GENES, 512), 256, 0, stream>>>(
        g1_bf, W1gT, nullptr, nullptr, pre_g_bf, N_GENES, 512, HID);

    agg_kernel<<<(N_CELLS + 3) / 4, 256, 0, stream>>>(ptr_c, ci, cv, pre_g_bf, pre_c_bf,
                                                      l1_cs_b, l1_cn_b, c2_bf, N_CELLS);
    agg_kernel<<<(N_GENES + 3) / 4, 256, 0, stream>>>(ptr_g, gi, gv, pre_c_bf, pre_g_bf,
                                                      l1_gs_b, l1_gn_b, g2_bf, N_GENES);

    // ---- latent heads (f32 to d_out + bf16 for decoders) ----
    mfma_gemm<unsigned short, true, true, true><<<GRID(N_CELLS, LAT), 256, 0, stream>>>(
        c2_bf, WzcT, cl_b, z_cells, zc_bf, N_CELLS, LAT, HID);
    mfma_gemm<unsigned short, true, true, true><<<GRID(N_GENES, LAT), 256, 0, stream>>>(
        g2_bf, WzgT, gl_b, z_genes, zg_bf, N_GENES, LAT, HID);

    // ---- decoders ----
    mfma_gemm<unsigned short, true, true, false><<<GRID(N_CELLS, N_GENES), 256, 0, stream>>>(
        zc_bf, WdcT, cd_b, cell_recon, nullptr, N_CELLS, N_GENES, LAT);
    mfma_gemm<unsigned short, true, true, false><<<GRID(N_GENES, N_CELLS), 256, 0, stream>>>(
        zg_bf, WdgT, gd_b, gene_recon, nullptr, N_GENES, N_CELLS, LAT);

    // ---- DEC soft assignment ----
    q_kernel<<<(N_CELLS + 255) / 256, 256, 0, stream>>>(z_cells, centers, q);
}

// Round 6
// 619.839 us; speedup vs baseline: 1.1849x; 1.1250x over previous
//
#include <hip/hip_runtime.h>

#define N_CELLS 10000
#define N_GENES 4000
#define CELL_F  2000
#define GENE_F  50
#define HID     256
#define LAT     64
#define NCLUST  20
#define N_EDGES 640000

typedef __attribute__((ext_vector_type(8))) short    bf16x8;
typedef __attribute__((ext_vector_type(8))) unsigned short u16x8;
typedef __attribute__((ext_vector_type(4))) float    f32x4;

__device__ __forceinline__ unsigned short f2bf(float f) {
    unsigned int u = __float_as_uint(f);
    unsigned int r = (u + 0x7FFFu + ((u >> 16) & 1u)) >> 16;
    return (unsigned short)r;
}
__device__ __forceinline__ float bf2f(unsigned short h) {
    return __uint_as_float(((unsigned int)h) << 16);
}

// ---------------- bf16 MFMA GEMM (round-3 proven 64x64 tile) ----------------
// C(M,N) = A(M,K) @ BT(N,K)^T  [+bias]
// A: f32 or bf16(ushort) row-major, stride K. BT: bf16, rows padded to >= grid.x*64.
// Tile 64x64, BK=64, 4 waves (each: 16 rows x 64 cols via 4 col-fragments).
template<typename AT, bool BIAS, bool WF32, bool WBF>
__global__ __launch_bounds__(256)
void mfma_gemm(const AT* __restrict__ A, const unsigned short* __restrict__ BT,
               const float* __restrict__ bias, float* __restrict__ C,
               unsigned short* __restrict__ Cbf, int M, int N, int K)
{
    __shared__ __align__(16) unsigned short As[64][72];
    __shared__ __align__(16) unsigned short Bs[64][72];
    const int tid  = threadIdx.x;
    const int row0 = blockIdx.y * 64;
    const int col0 = blockIdx.x * 64;
    const int lane = tid & 63;
    const int w    = tid >> 6;
    const int cn   = lane & 15;
    const int rj   = lane >> 4;

    const bool avec = (sizeof(AT) == 2) ? ((K & 7) == 0) : ((K & 3) == 0);
    const bool bvec = ((K & 7) == 0);

    f32x4 acc[4] = {};

    for (int kt = 0; kt < K; kt += 64) {
        // 64x64 bf16 tile = 512 vec8 chunks; 8 chunks per row.
        #pragma unroll
        for (int half = 0; half < 2; ++half) {
            int c = tid + half * 256;
            int r = c >> 3, p = c & 7;
            int gc = kt + p * 8;
            // ---- A tile ----
            {
                int gr = row0 + r;
                u16x8 v = {0, 0, 0, 0, 0, 0, 0, 0};
                if (gr < M) {
                    if constexpr (sizeof(AT) == 2) {
                        const unsigned short* src = (const unsigned short*)A + (size_t)gr * K + gc;
                        if (avec && gc + 8 <= K) {
                            v = *(const u16x8*)src;
                        } else {
                            #pragma unroll
                            for (int j = 0; j < 8; ++j) if (gc + j < K) v[j] = src[j];
                        }
                    } else {
                        const float* src = (const float*)A + (size_t)gr * K + gc;
                        if (avec && gc + 8 <= K) {
                            float4 f0 = *(const float4*)src;
                            float4 f1 = *(const float4*)(src + 4);
                            v[0] = f2bf(f0.x); v[1] = f2bf(f0.y); v[2] = f2bf(f0.z); v[3] = f2bf(f0.w);
                            v[4] = f2bf(f1.x); v[5] = f2bf(f1.y); v[6] = f2bf(f1.z); v[7] = f2bf(f1.w);
                        } else {
                            #pragma unroll
                            for (int j = 0; j < 8; ++j) if (gc + j < K) v[j] = f2bf(src[j]);
                        }
                    }
                }
                *(u16x8*)&As[r][p * 8] = v;
            }
            // ---- B tile (BT rows are alloc-padded, no row guard needed) ----
            {
                int gn = col0 + r;
                const unsigned short* src = BT + (size_t)gn * K + gc;
                u16x8 v = {0, 0, 0, 0, 0, 0, 0, 0};
                if (bvec && gc + 8 <= K) {
                    v = *(const u16x8*)src;
                } else {
                    #pragma unroll
                    for (int j = 0; j < 8; ++j) if (gc + j < K) v[j] = src[j];
                }
                *(u16x8*)&Bs[r][p * 8] = v;
            }
        }
        __syncthreads();
        #pragma unroll
        for (int kk = 0; kk < 64; kk += 32) {
            bf16x8 a = *(const bf16x8*)&As[w * 16 + cn][kk + rj * 8];
            #pragma unroll
            for (int f = 0; f < 4; ++f) {
                bf16x8 b = *(const bf16x8*)&Bs[f * 16 + cn][kk + rj * 8];
                acc[f] = __builtin_amdgcn_mfma_f32_16x16x32_bf16(a, b, acc[f], 0, 0, 0);
            }
        }
        __syncthreads();
    }

    // ---- epilogue: D col = lane&15, row = (lane>>4)*4 + reg  [m89] ----
    #pragma unroll
    for (int f = 0; f < 4; ++f) {
        int col = col0 + f * 16 + cn;
        if (col >= N) continue;
        float bv = BIAS ? bias[col] : 0.0f;
        #pragma unroll
        for (int j = 0; j < 4; ++j) {
            int r = row0 + w * 16 + rj * 4 + j;
            if (r < M) {
                float val = acc[f][j] + bv;
                if (WF32) C[(size_t)r * N + col] = val;
                if (WBF)  Cbf[(size_t)r * N + col] = f2bf(val);
            }
        }
    }
}

// ---- weight pack via LDS transpose: BT[n][k] = [W1 | W2](k, n), bf16 ----
__global__ __launch_bounds__(256)
void pack_bt(const float* __restrict__ W1, const float* __restrict__ W2,
             unsigned short* __restrict__ BT, int K, int N1, int N2, int Np)
{
    __shared__ float tile[32][33];
    int tx = threadIdx.x & 31;        // fast dim
    int ty = threadIdx.x >> 5;        // 0..7
    int k0 = blockIdx.x * 32;
    int n0 = blockIdx.y * 32;
    #pragma unroll
    for (int yy = 0; yy < 4; ++yy) {
        int k = k0 + ty + yy * 8;
        int n = n0 + tx;
        float v = 0.0f;
        if (k < K) {
            if (n < N1) v = W1[(size_t)k * N1 + n];
            else if (n < N1 + N2) v = W2[(size_t)k * N2 + (n - N1)];
        }
        tile[ty + yy * 8][tx] = v;
    }
    __syncthreads();
    #pragma unroll
    for (int yy = 0; yy < 4; ++yy) {
        int n = n0 + ty + yy * 8;
        int k = k0 + tx;
        if (n < Np && k < K)
            BT[(size_t)n * K + k] = f2bf(tile[tx][ty + yy * 8]);
    }
}

// ---------------- CSR construction ----------------
__global__ void count_kernel(const int* __restrict__ er, const int* __restrict__ ec,
                             int* cnt_c, int* cnt_g)
{
    int e = blockIdx.x * blockDim.x + threadIdx.x;
    if (e < N_EDGES) {
        atomicAdd(&cnt_c[er[e]], 1);
        atomicAdd(&cnt_g[ec[e]], 1);
    }
}

// one launch, block 0 = cells, block 1 = genes; also seeds cur = ptr.
// Parallel Hillis-Steele scan of the 1024 per-thread partials.
__global__ __launch_bounds__(1024)
void scan2_kernel(const int* __restrict__ cnt_c, int* __restrict__ ptr_c, int* __restrict__ cur_c,
                  const int* __restrict__ cnt_g, int* __restrict__ ptr_g, int* __restrict__ cur_g)
{
    const int* cnt = blockIdx.x ? cnt_g : cnt_c;
    int* ptr = blockIdx.x ? ptr_g : ptr_c;
    int* cur = blockIdx.x ? cur_g : cur_c;
    int  n   = blockIdx.x ? N_GENES : N_CELLS;
    __shared__ int part[1024];
    int t = threadIdx.x;
    int chunk = (n + 1023) / 1024;
    int lo = t * chunk, hi = min(lo + chunk, n);
    int s = 0;
    for (int i = lo; i < hi; ++i) s += cnt[i];
    part[t] = s;
    __syncthreads();
    #pragma unroll
    for (int off = 1; off < 1024; off <<= 1) {
        int v = (t >= off) ? part[t - off] : 0;
        __syncthreads();
        part[t] += v;
        __syncthreads();
    }
    if (t == 1023) ptr[n] = part[1023];
    int run = part[t] - s;   // exclusive prefix for this thread's chunk
    for (int i = lo; i < hi; ++i) { ptr[i] = run; cur[i] = run; run += cnt[i]; }
}

__global__ void scatter_kernel(const int* __restrict__ er, const int* __restrict__ ec,
                               const float* __restrict__ ev,
                               int* cur_c, int* cur_g,
                               int* __restrict__ ci, float* __restrict__ cv,
                               int* __restrict__ gi, float* __restrict__ gv)
{
    int e = blockIdx.x * blockDim.x + threadIdx.x;
    if (e < N_EDGES) {
        int r = er[e], c = ec[e];
        float v = ev[e];
        int pc = atomicAdd(&cur_c[r], 1);
        ci[pc] = c; cv[pc] = v;
        int pg = atomicAdd(&cur_g[c], 1);
        gi[pg] = r; gv[pg] = v;
    }
}

// ---- fused segment-sum + residual + biases + relu; bf16 in/out, f32 math ----
// Block-per-row; 4 waves split the edge list (stride 4); each lane covers 4 dims
// via ushort4 (full 512B row gathered per instruction). LDS cross-wave reduce.
// out[r,:] = relu(pre[r,0:256] + sum_e val[e]*src[nbr[e],256:512] + b1 + b2)
__global__ __launch_bounds__(256)
void agg_kernel(const int* __restrict__ ptr, const int* __restrict__ nbr,
                const float* __restrict__ val,
                const unsigned short* __restrict__ srcbf,  // stride 512, cols 256..511
                const unsigned short* __restrict__ prebf,  // stride 512, cols 0..255
                const float* __restrict__ b1, const float* __restrict__ b2,
                unsigned short* __restrict__ outbf)        // stride 256
{
    __shared__ __align__(16) float red[4][256];
    int r = blockIdx.x;
    int t = threadIdx.x;
    int w = t >> 6;
    int lane = t & 63;
    int s = ptr[r], e = ptr[r + 1];
    const ushort4* src4 = (const ushort4*)srcbf;   // row stride 128 vec4, +64 = neigh half
    float4 acc = {0.0f, 0.0f, 0.0f, 0.0f};
    int i = s + w;
    for (; i + 4 < e; i += 8) {
        int   j0 = nbr[i],   j1 = nbr[i + 4];
        float v0 = val[i],   v1 = val[i + 4];
        ushort4 a = src4[(size_t)j0 * 128 + 64 + lane];
        ushort4 b = src4[(size_t)j1 * 128 + 64 + lane];
        acc.x += v0 * bf2f(a.x) + v1 * bf2f(b.x);
        acc.y += v0 * bf2f(a.y) + v1 * bf2f(b.y);
        acc.z += v0 * bf2f(a.z) + v1 * bf2f(b.z);
        acc.w += v0 * bf2f(a.w) + v1 * bf2f(b.w);
    }
    if (i < e) {
        int j0 = nbr[i]; float v0 = val[i];
        ushort4 a = src4[(size_t)j0 * 128 + 64 + lane];
        acc.x += v0 * bf2f(a.x);
        acc.y += v0 * bf2f(a.y);
        acc.z += v0 * bf2f(a.z);
        acc.w += v0 * bf2f(a.w);
    }
    *(float4*)&red[w][lane * 4] = acc;
    __syncthreads();
    float x = red[0][t] + red[1][t] + red[2][t] + red[3][t]
            + bf2f(prebf[(size_t)r * 512 + t]) + b1[t] + b2[t];
    outbf[(size_t)r * 256 + t] = f2bf(fmaxf(x, 0.0f));
}

// ---------------- Student-t cluster assignment (ALPHA=1) ----------------
__global__ __launch_bounds__(256)
void q_kernel(const float* __restrict__ z, const float* __restrict__ centers,
              float* __restrict__ q)
{
    __shared__ float cs[NCLUST * LAT];
    int tid = threadIdx.x;
    for (int l = tid; l < NCLUST * LAT; l += 256) cs[l] = centers[l];
    __syncthreads();
    int c = blockIdx.x * 256 + tid;
    if (c >= N_CELLS) return;
    float zr[LAT];
    #pragma unroll
    for (int k = 0; k < LAT; ++k) zr[k] = z[(size_t)c * LAT + k];
    float num[NCLUST];
    float denom = 0.0f;
    for (int j = 0; j < NCLUST; ++j) {
        float d = 0.0f;
        #pragma unroll
        for (int k = 0; k < LAT; ++k) {
            float t = zr[k] - cs[j * LAT + k];
            d += t * t;
        }
        float n = 1.0f / (1.0f + d);
        num[j] = n;
        denom += n;
    }
    float inv = 1.0f / denom;
    for (int j = 0; j < NCLUST; ++j) q[(size_t)c * NCLUST + j] = num[j] * inv;
}

extern "C" void kernel_launch(void* const* d_in, const int* in_sizes, int n_in,
                              void* d_out, int out_size, void* d_ws, size_t ws_size,
                              hipStream_t stream)
{
    const float* cell_x  = (const float*)d_in[0];
    const float* gene_x  = (const float*)d_in[1];
    const int*   er      = (const int*)d_in[2];
    const int*   ec      = (const int*)d_in[3];
    const float* ev      = (const float*)d_in[4];
    const float* l0_cs_w = (const float*)d_in[5];  const float* l0_cs_b = (const float*)d_in[6];
    const float* l0_cn_w = (const float*)d_in[7];  const float* l0_cn_b = (const float*)d_in[8];
    const float* l0_gs_w = (const float*)d_in[9];  const float* l0_gs_b = (const float*)d_in[10];
    const float* l0_gn_w = (const float*)d_in[11]; const float* l0_gn_b = (const float*)d_in[12];
    const float* l1_cs_w = (const float*)d_in[13]; const float* l1_cs_b = (const float*)d_in[14];
    const float* l1_cn_w = (const float*)d_in[15]; const float* l1_cn_b = (const float*)d_in[16];
    const float* l1_gs_w = (const float*)d_in[17]; const float* l1_gs_b = (const float*)d_in[18];
    const float* l1_gn_w = (const float*)d_in[19]; const float* l1_gn_b = (const float*)d_in[20];
    const float* cl_w = (const float*)d_in[21]; const float* cl_b = (const float*)d_in[22];
    const float* gl_w = (const float*)d_in[23]; const float* gl_b = (const float*)d_in[24];
    const float* cd_w = (const float*)d_in[25]; const float* cd_b = (const float*)d_in[26];
    const float* gd_w = (const float*)d_in[27]; const float* gd_b = (const float*)d_in[28];
    const float* centers = (const float*)d_in[29];

    float* out = (float*)d_out;
    float* z_cells    = out;                       // 10000*64
    float* z_genes    = out + 640000;              // 4000*64
    float* cell_recon = out + 896000;              // 10000*4000
    float* gene_recon = out + 40896000;            // 4000*10000
    float* q          = out + 80896000;            // 10000*20

    // ---- workspace arena (~46 MB, 256B-aligned blocks) ----
    char* wsp = (char*)d_ws;
    auto alloc = [&](size_t bytes) -> void* {
        void* p = (void*)wsp;
        wsp += (bytes + 255) & ~(size_t)255;
        return p;
    };
    unsigned short* pre_c_bf = (unsigned short*)alloc((size_t)N_CELLS * 512 * 2);
    unsigned short* pre_g_bf = (unsigned short*)alloc((size_t)N_GENES * 512 * 2);
    unsigned short* c1_bf    = (unsigned short*)alloc((size_t)N_CELLS * 256 * 2);
    unsigned short* g1_bf    = (unsigned short*)alloc((size_t)N_GENES * 256 * 2);
    unsigned short* c2_bf    = (unsigned short*)alloc((size_t)N_CELLS * 256 * 2);
    unsigned short* g2_bf    = (unsigned short*)alloc((size_t)N_GENES * 256 * 2);
    unsigned short* zc_bf    = (unsigned short*)alloc((size_t)N_CELLS * 64 * 2);
    unsigned short* zg_bf    = (unsigned short*)alloc((size_t)N_GENES * 64 * 2);
    unsigned short* W0cT = (unsigned short*)alloc((size_t)512 * CELL_F * 2);
    unsigned short* W0gT = (unsigned short*)alloc((size_t)512 * GENE_F * 2);
    unsigned short* W1cT = (unsigned short*)alloc((size_t)512 * HID * 2);
    unsigned short* W1gT = (unsigned short*)alloc((size_t)512 * HID * 2);
    unsigned short* WzcT = (unsigned short*)alloc((size_t)64 * HID * 2);
    unsigned short* WzgT = (unsigned short*)alloc((size_t)64 * HID * 2);
    unsigned short* WdcT = (unsigned short*)alloc((size_t)4032 * 64 * 2);
    unsigned short* WdgT = (unsigned short*)alloc((size_t)10048 * 64 * 2);
    int* cnt_c = (int*)alloc((size_t)(N_CELLS + N_GENES) * 4);   // cnt_c + cnt_g contiguous
    int* cnt_g = cnt_c + N_CELLS;
    int* ptr_c = (int*)alloc((size_t)(N_CELLS + 1) * 4);
    int* ptr_g = (int*)alloc((size_t)(N_GENES + 1) * 4);
    int* cur_c = (int*)alloc((size_t)N_CELLS * 4);
    int* cur_g = (int*)alloc((size_t)N_GENES * 4);
    int*   ci = (int*)alloc((size_t)N_EDGES * 4);
    float* cv = (float*)alloc((size_t)N_EDGES * 4);
    int*   gi = (int*)alloc((size_t)N_EDGES * 4);
    float* gv = (float*)alloc((size_t)N_EDGES * 4);

    // ---- CSR build ----
    hipMemsetAsync(cnt_c, 0, (size_t)(N_CELLS + N_GENES) * 4, stream);
    count_kernel<<<(N_EDGES + 255) / 256, 256, 0, stream>>>(er, ec, cnt_c, cnt_g);
    scan2_kernel<<<2, 1024, 0, stream>>>(cnt_c, ptr_c, cur_c, cnt_g, ptr_g, cur_g);
    scatter_kernel<<<(N_EDGES + 255) / 256, 256, 0, stream>>>(er, ec, ev, cur_c, cur_g,
                                                              ci, cv, gi, gv);

    // ---- weight packs (bf16, transposed, N-concat), LDS-tiled transpose ----
    auto packs = [&](const float* W1, const float* W2, unsigned short* BT,
                     int K, int N1, int N2, int Np) {
        pack_bt<<<dim3((K + 31) / 32, (Np + 31) / 32), 256, 0, stream>>>(W1, W2, BT, K, N1, N2, Np);
    };
    packs(l0_cs_w, l0_gn_w, W0cT, CELL_F, HID, HID, 512);
    packs(l0_gs_w, l0_cn_w, W0gT, GENE_F, HID, HID, 512);
    packs(l1_cs_w, l1_gn_w, W1cT, HID, HID, HID, 512);
    packs(l1_gs_w, l1_cn_w, W1gT, HID, HID, HID, 512);
    packs(cl_w, nullptr, WzcT, HID, LAT, 0, 64);
    packs(gl_w, nullptr, WzgT, HID, LAT, 0, 64);
    packs(cd_w, nullptr, WdcT, LAT, N_GENES, 0, 4032);
    packs(gd_w, nullptr, WdgT, LAT, N_CELLS, 0, 10048);

    #define GRID(Mv, Nv) dim3(((Nv) + 63) / 64, ((Mv) + 63) / 64)

    // ---- layer 0: [self | neigh] projections ----
    mfma_gemm<float, false, false, true><<<GRID(N_CELLS, 512), 256, 0, stream>>>(
        cell_x, W0cT, nullptr, nullptr, pre_c_bf, N_CELLS, 512, CELL_F);
    mfma_gemm<float, false, false, true><<<GRID(N_GENES, 512), 256, 0, stream>>>(
        gene_x, W0gT, nullptr, nullptr, pre_g_bf, N_GENES, 512, GENE_F);

    agg_kernel<<<N_CELLS, 256, 0, stream>>>(ptr_c, ci, cv, pre_g_bf, pre_c_bf,
                                            l0_cs_b, l0_cn_b, c1_bf);
    agg_kernel<<<N_GENES, 256, 0, stream>>>(ptr_g, gi, gv, pre_c_bf, pre_g_bf,
                                            l0_gs_b, l0_gn_b, g1_bf);

    // ---- layer 1 ----
    mfma_gemm<unsigned short, false, false, true><<<GRID(N_CELLS, 512), 256, 0, stream>>>(
        c1_bf, W1cT, nullptr, nullptr, pre_c_bf, N_CELLS, 512, HID);
    mfma_gemm<unsigned short, false, false, true><<<GRID(N_GENES, 512), 256, 0, stream>>>(
        g1_bf, W1gT, nullptr, nullptr, pre_g_bf, N_GENES, 512, HID);

    agg_kernel<<<N_CELLS, 256, 0, stream>>>(ptr_c, ci, cv, pre_g_bf, pre_c_bf,
                                            l1_cs_b, l1_cn_b, c2_bf);
    agg_kernel<<<N_GENES, 256, 0, stream>>>(ptr_g, gi, gv, pre_c_bf, pre_g_bf,
                                            l1_gs_b, l1_gn_b, g2_bf);

    // ---- latent heads (f32 to d_out + bf16 for decoders) ----
    mfma_gemm<unsigned short, true, true, true><<<GRID(N_CELLS, LAT), 256, 0, stream>>>(
        c2_bf, WzcT, cl_b, z_cells, zc_bf, N_CELLS, LAT, HID);
    mfma_gemm<unsigned short, true, true, true><<<GRID(N_GENES, LAT), 256, 0, stream>>>(
        g2_bf, WzgT, gl_b, z_genes, zg_bf, N_GENES, LAT, HID);

    // ---- decoders ----
    mfma_gemm<unsigned short, true, true, false><<<GRID(N_CELLS, N_GENES), 256, 0, stream>>>(
        zc_bf, WdcT, cd_b, cell_recon, nullptr, N_CELLS, N_GENES, LAT);
    mfma_gemm<unsigned short, true, true, false><<<GRID(N_GENES, N_CELLS), 256, 0, stream>>>(
        zg_bf, WdgT, gd_b, gene_recon, nullptr, N_GENES, N_CELLS, LAT);

    // ---- DEC soft assignment ----
    q_kernel<<<(N_CELLS + 255) / 256, 256, 0, stream>>>(z_cells, centers, q);
}

// Round 7
// 586.582 us; speedup vs baseline: 1.2521x; 1.0567x over previous
//
#include <hip/hip_runtime.h>

#define N_CELLS 10000
#define N_GENES 4000
#define CELL_F  2000
#define GENE_F  50
#define HID     256
#define LAT     64
#define NCLUST  20
#define N_EDGES 640000

typedef __attribute__((ext_vector_type(8))) short    bf16x8;
typedef __attribute__((ext_vector_type(8))) unsigned short u16x8;
typedef __attribute__((ext_vector_type(4))) float    f32x4;

__device__ __forceinline__ unsigned short f2bf(float f) {
    unsigned int u = __float_as_uint(f);
    unsigned int r = (u + 0x7FFFu + ((u >> 16) & 1u)) >> 16;
    return (unsigned short)r;
}
__device__ __forceinline__ float bf2f(unsigned short h) {
    return __uint_as_float(((unsigned int)h) << 16);
}

// ---------------- f32 -> bf16 bulk convert (two segments, one launch) ----------------
__global__ __launch_bounds__(256)
void cvt2_bf16(const float* __restrict__ a, unsigned short* __restrict__ oa, int na8,
               const float* __restrict__ b, unsigned short* __restrict__ ob, int nb8)
{
    int i = blockIdx.x * 256 + threadIdx.x;
    const float* src; unsigned short* dst; int idx;
    if (i < na8)            { src = a; dst = oa; idx = i; }
    else if (i < na8 + nb8) { src = b; dst = ob; idx = i - na8; }
    else return;
    float4 f0 = ((const float4*)src)[(size_t)idx * 2];
    float4 f1 = ((const float4*)src)[(size_t)idx * 2 + 1];
    u16x8 v;
    v[0] = f2bf(f0.x); v[1] = f2bf(f0.y); v[2] = f2bf(f0.z); v[3] = f2bf(f0.w);
    v[4] = f2bf(f1.x); v[5] = f2bf(f1.y); v[6] = f2bf(f1.z); v[7] = f2bf(f1.w);
    ((u16x8*)dst)[idx] = v;
}

// ---------------- bf16 MFMA GEMM (64x64 tile, XCD-swizzled) ----------------
// C(M,N) = A(M,K) @ BT(N,K)^T  [+bias]
// A: bf16(ushort) row-major, stride K. BT: bf16, rows padded to >= grid.x*64.
// Tile 64x64, BK=64, 4 waves (each: 16 rows x 64 cols via 4 col-fragments).
// Block swizzle: bijective m204 remap of the linearized block id so that
// consecutive work-ids (sharing an A row-panel) land on the SAME XCD.
template<bool BIAS, bool WF32, bool WBF>
__global__ __launch_bounds__(256)
void mfma_gemm(const unsigned short* __restrict__ A, const unsigned short* __restrict__ BT,
               const float* __restrict__ bias, float* __restrict__ C,
               unsigned short* __restrict__ Cbf, int M, int N, int K)
{
    __shared__ __align__(16) unsigned short As[64][72];
    __shared__ __align__(16) unsigned short Bs[64][72];

    // ---- XCD-aware bijective swizzle (T1, m204) ----
    const int nwg = gridDim.x * gridDim.y;
    const int lin = blockIdx.y * gridDim.x + blockIdx.x;
    const int q8 = nwg >> 3, r8 = nwg & 7;
    const int xcd = lin & 7, idx = lin >> 3;
    const int wgid = (xcd < r8 ? xcd * (q8 + 1) : r8 * (q8 + 1) + (xcd - r8) * q8) + idx;
    const int by = wgid / gridDim.x;
    const int bx = wgid - by * gridDim.x;

    const int tid  = threadIdx.x;
    const int row0 = by * 64;
    const int col0 = bx * 64;
    const int lane = tid & 63;
    const int w    = tid >> 6;
    const int cn   = lane & 15;
    const int rj   = lane >> 4;

    const bool kvec = ((K & 7) == 0);

    f32x4 acc[4] = {};

    for (int kt = 0; kt < K; kt += 64) {
        // 64x64 bf16 tile = 512 vec8 chunks; 8 chunks per row.
        #pragma unroll
        for (int half = 0; half < 2; ++half) {
            int c = tid + half * 256;
            int r = c >> 3, p = c & 7;
            int gc = kt + p * 8;
            // ---- A tile ----
            {
                int gr = row0 + r;
                u16x8 v = {0, 0, 0, 0, 0, 0, 0, 0};
                if (gr < M) {
                    const unsigned short* src = A + (size_t)gr * K + gc;
                    if (kvec && gc + 8 <= K) {
                        v = *(const u16x8*)src;
                    } else {
                        #pragma unroll
                        for (int j = 0; j < 8; ++j) if (gc + j < K) v[j] = src[j];
                    }
                }
                *(u16x8*)&As[r][p * 8] = v;
            }
            // ---- B tile (BT rows are alloc-padded, no row guard needed) ----
            {
                int gn = col0 + r;
                const unsigned short* src = BT + (size_t)gn * K + gc;
                u16x8 v = {0, 0, 0, 0, 0, 0, 0, 0};
                if (kvec && gc + 8 <= K) {
                    v = *(const u16x8*)src;
                } else {
                    #pragma unroll
                    for (int j = 0; j < 8; ++j) if (gc + j < K) v[j] = src[j];
                }
                *(u16x8*)&Bs[r][p * 8] = v;
            }
        }
        __syncthreads();
        #pragma unroll
        for (int kk = 0; kk < 64; kk += 32) {
            bf16x8 a = *(const bf16x8*)&As[w * 16 + cn][kk + rj * 8];
            #pragma unroll
            for (int f = 0; f < 4; ++f) {
                bf16x8 b = *(const bf16x8*)&Bs[f * 16 + cn][kk + rj * 8];
                acc[f] = __builtin_amdgcn_mfma_f32_16x16x32_bf16(a, b, acc[f], 0, 0, 0);
            }
        }
        __syncthreads();
    }

    // ---- epilogue: D col = lane&15, row = (lane>>4)*4 + reg  [m89] ----
    #pragma unroll
    for (int f = 0; f < 4; ++f) {
        int col = col0 + f * 16 + cn;
        if (col >= N) continue;
        float bv = BIAS ? bias[col] : 0.0f;
        #pragma unroll
        for (int j = 0; j < 4; ++j) {
            int r = row0 + w * 16 + rj * 4 + j;
            if (r < M) {
                float val = acc[f][j] + bv;
                if (WF32) C[(size_t)r * N + col] = val;
                if (WBF)  Cbf[(size_t)r * N + col] = f2bf(val);
            }
        }
    }
}

// ---- fused weight packs: BT[n][k] = [W1 | W2](k, n), bf16; 8 packs, 1 launch ----
struct PackDesc {
    const float* W1; const float* W2; unsigned short* BT;
    int K, N1, N2, Np, xb, blk0;
};
struct PackArgs { PackDesc d[8]; };

__global__ __launch_bounds__(256)
void pack_all(PackArgs pa)
{
    __shared__ float tile[32][33];
    int b = blockIdx.x;
    int p = 0;
    #pragma unroll
    for (int i = 1; i < 8; ++i) if (b >= pa.d[i].blk0) p = i;
    const PackDesc d = pa.d[p];
    int local = b - d.blk0;
    int kb = local % d.xb, nb = local / d.xb;
    int k0 = kb * 32, n0 = nb * 32;
    int tx = threadIdx.x & 31;
    int ty = threadIdx.x >> 5;
    #pragma unroll
    for (int yy = 0; yy < 4; ++yy) {
        int k = k0 + ty + yy * 8;
        int n = n0 + tx;
        float v = 0.0f;
        if (k < d.K) {
            if (n < d.N1) v = d.W1[(size_t)k * d.N1 + n];
            else if (n < d.N1 + d.N2) v = d.W2[(size_t)k * d.N2 + (n - d.N1)];
        }
        tile[ty + yy * 8][tx] = v;
    }
    __syncthreads();
    #pragma unroll
    for (int yy = 0; yy < 4; ++yy) {
        int n = n0 + ty + yy * 8;
        int k = k0 + tx;
        if (n < d.Np && k < d.K)
            d.BT[(size_t)n * d.K + k] = f2bf(tile[tx][ty + yy * 8]);
    }
}

// ---------------- CSR construction ----------------
__global__ void count_kernel(const int* __restrict__ er, const int* __restrict__ ec,
                             int* cnt_c, int* cnt_g)
{
    int e = blockIdx.x * blockDim.x + threadIdx.x;
    if (e < N_EDGES) {
        atomicAdd(&cnt_c[er[e]], 1);
        atomicAdd(&cnt_g[ec[e]], 1);
    }
}

// one launch, block 0 = cells, block 1 = genes; also seeds cur = ptr.
// Parallel Hillis-Steele scan of the 1024 per-thread partials.
__global__ __launch_bounds__(1024)
void scan2_kernel(const int* __restrict__ cnt_c, int* __restrict__ ptr_c, int* __restrict__ cur_c,
                  const int* __restrict__ cnt_g, int* __restrict__ ptr_g, int* __restrict__ cur_g)
{
    const int* cnt = blockIdx.x ? cnt_g : cnt_c;
    int* ptr = blockIdx.x ? ptr_g : ptr_c;
    int* cur = blockIdx.x ? cur_g : cur_c;
    int  n   = blockIdx.x ? N_GENES : N_CELLS;
    __shared__ int part[1024];
    int t = threadIdx.x;
    int chunk = (n + 1023) / 1024;
    int lo = t * chunk, hi = min(lo + chunk, n);
    int s = 0;
    for (int i = lo; i < hi; ++i) s += cnt[i];
    part[t] = s;
    __syncthreads();
    #pragma unroll
    for (int off = 1; off < 1024; off <<= 1) {
        int v = (t >= off) ? part[t - off] : 0;
        __syncthreads();
        part[t] += v;
        __syncthreads();
    }
    if (t == 1023) ptr[n] = part[1023];
    int run = part[t] - s;   // exclusive prefix for this thread's chunk
    for (int i = lo; i < hi; ++i) { ptr[i] = run; cur[i] = run; run += cnt[i]; }
}

__global__ void scatter_kernel(const int* __restrict__ er, const int* __restrict__ ec,
                               const float* __restrict__ ev,
                               int* cur_c, int* cur_g,
                               int* __restrict__ ci, float* __restrict__ cv,
                               int* __restrict__ gi, float* __restrict__ gv)
{
    int e = blockIdx.x * blockDim.x + threadIdx.x;
    if (e < N_EDGES) {
        int r = er[e], c = ec[e];
        float v = ev[e];
        int pc = atomicAdd(&cur_c[r], 1);
        ci[pc] = c; cv[pc] = v;
        int pg = atomicAdd(&cur_g[c], 1);
        gi[pg] = r; gv[pg] = v;
    }
}

// ---- fused segment-sum + residual + biases + relu; bf16 in/out, f32 math ----
// Block-per-row; 4 waves split the edge list (stride 4); each lane covers 4 dims
// via ushort4 (full 512B row gathered per instruction). LDS cross-wave reduce.
// out[r,:] = relu(pre[r,0:256] + sum_e val[e]*src[nbr[e],256:512] + b1 + b2)
__global__ __launch_bounds__(256)
void agg_kernel(const int* __restrict__ ptr, const int* __restrict__ nbr,
                const float* __restrict__ val,
                const unsigned short* __restrict__ srcbf,  // stride 512, cols 256..511
                const unsigned short* __restrict__ prebf,  // stride 512, cols 0..255
                const float* __restrict__ b1, const float* __restrict__ b2,
                unsigned short* __restrict__ outbf)        // stride 256
{
    __shared__ __align__(16) float red[4][256];
    int r = blockIdx.x;
    int t = threadIdx.x;
    int w = t >> 6;
    int lane = t & 63;
    int s = ptr[r], e = ptr[r + 1];
    const ushort4* src4 = (const ushort4*)srcbf;   // row stride 128 vec4, +64 = neigh half
    float4 acc = {0.0f, 0.0f, 0.0f, 0.0f};
    int i = s + w;
    for (; i + 4 < e; i += 8) {
        int   j0 = nbr[i],   j1 = nbr[i + 4];
        float v0 = val[i],   v1 = val[i + 4];
        ushort4 a = src4[(size_t)j0 * 128 + 64 + lane];
        ushort4 b = src4[(size_t)j1 * 128 + 64 + lane];
        acc.x += v0 * bf2f(a.x) + v1 * bf2f(b.x);
        acc.y += v0 * bf2f(a.y) + v1 * bf2f(b.y);
        acc.z += v0 * bf2f(a.z) + v1 * bf2f(b.z);
        acc.w += v0 * bf2f(a.w) + v1 * bf2f(b.w);
    }
    if (i < e) {
        int j0 = nbr[i]; float v0 = val[i];
        ushort4 a = src4[(size_t)j0 * 128 + 64 + lane];
        acc.x += v0 * bf2f(a.x);
        acc.y += v0 * bf2f(a.y);
        acc.z += v0 * bf2f(a.z);
        acc.w += v0 * bf2f(a.w);
    }
    *(float4*)&red[w][lane * 4] = acc;
    __syncthreads();
    float x = red[0][t] + red[1][t] + red[2][t] + red[3][t]
            + bf2f(prebf[(size_t)r * 512 + t]) + b1[t] + b2[t];
    outbf[(size_t)r * 256 + t] = f2bf(fmaxf(x, 0.0f));
}

// ---------------- Student-t cluster assignment (ALPHA=1) ----------------
__global__ __launch_bounds__(256)
void q_kernel(const float* __restrict__ z, const float* __restrict__ centers,
              float* __restrict__ q)
{
    __shared__ float cs[NCLUST * LAT];
    int tid = threadIdx.x;
    for (int l = tid; l < NCLUST * LAT; l += 256) cs[l] = centers[l];
    __syncthreads();
    int c = blockIdx.x * 256 + tid;
    if (c >= N_CELLS) return;
    float zr[LAT];
    #pragma unroll
    for (int k = 0; k < LAT; ++k) zr[k] = z[(size_t)c * LAT + k];
    float num[NCLUST];
    float denom = 0.0f;
    for (int j = 0; j < NCLUST; ++j) {
        float d = 0.0f;
        #pragma unroll
        for (int k = 0; k < LAT; ++k) {
            float t = zr[k] - cs[j * LAT + k];
            d += t * t;
        }
        float n = 1.0f / (1.0f + d);
        num[j] = n;
        denom += n;
    }
    float inv = 1.0f / denom;
    for (int j = 0; j < NCLUST; ++j) q[(size_t)c * NCLUST + j] = num[j] * inv;
}

extern "C" void kernel_launch(void* const* d_in, const int* in_sizes, int n_in,
                              void* d_out, int out_size, void* d_ws, size_t ws_size,
                              hipStream_t stream)
{
    const float* cell_x  = (const float*)d_in[0];
    const float* gene_x  = (const float*)d_in[1];
    const int*   er      = (const int*)d_in[2];
    const int*   ec      = (const int*)d_in[3];
    const float* ev      = (const float*)d_in[4];
    const float* l0_cs_w = (const float*)d_in[5];  const float* l0_cs_b = (const float*)d_in[6];
    const float* l0_cn_w = (const float*)d_in[7];  const float* l0_cn_b = (const float*)d_in[8];
    const float* l0_gs_w = (const float*)d_in[9];  const float* l0_gs_b = (const float*)d_in[10];
    const float* l0_gn_w = (const float*)d_in[11]; const float* l0_gn_b = (const float*)d_in[12];
    const float* l1_cs_w = (const float*)d_in[13]; const float* l1_cs_b = (const float*)d_in[14];
    const float* l1_cn_w = (const float*)d_in[15]; const float* l1_cn_b = (const float*)d_in[16];
    const float* l1_gs_w = (const float*)d_in[17]; const float* l1_gs_b = (const float*)d_in[18];
    const float* l1_gn_w = (const float*)d_in[19]; const float* l1_gn_b = (const float*)d_in[20];
    const float* cl_w = (const float*)d_in[21]; const float* cl_b = (const float*)d_in[22];
    const float* gl_w = (const float*)d_in[23]; const float* gl_b = (const float*)d_in[24];
    const float* cd_w = (const float*)d_in[25]; const float* cd_b = (const float*)d_in[26];
    const float* gd_w = (const float*)d_in[27]; const float* gd_b = (const float*)d_in[28];
    const float* centers = (const float*)d_in[29];

    float* out = (float*)d_out;
    float* z_cells    = out;                       // 10000*64
    float* z_genes    = out + 640000;              // 4000*64
    float* cell_recon = out + 896000;              // 10000*4000
    float* gene_recon = out + 40896000;            // 4000*10000
    float* q          = out + 80896000;            // 10000*20

    // ---- workspace arena (~87 MB, 256B-aligned blocks) ----
    char* wsp = (char*)d_ws;
    auto alloc = [&](size_t bytes) -> void* {
        void* p = (void*)wsp;
        wsp += (bytes + 255) & ~(size_t)255;
        return p;
    };
    unsigned short* pre_c_bf = (unsigned short*)alloc((size_t)N_CELLS * 512 * 2);
    unsigned short* pre_g_bf = (unsigned short*)alloc((size_t)N_GENES * 512 * 2);
    unsigned short* c1_bf    = (unsigned short*)alloc((size_t)N_CELLS * 256 * 2);
    unsigned short* g1_bf    = (unsigned short*)alloc((size_t)N_GENES * 256 * 2);
    unsigned short* c2_bf    = (unsigned short*)alloc((size_t)N_CELLS * 256 * 2);
    unsigned short* g2_bf    = (unsigned short*)alloc((size_t)N_GENES * 256 * 2);
    unsigned short* zc_bf    = (unsigned short*)alloc((size_t)N_CELLS * 64 * 2);
    unsigned short* zg_bf    = (unsigned short*)alloc((size_t)N_GENES * 64 * 2);
    unsigned short* cellx_bf = (unsigned short*)alloc((size_t)N_CELLS * CELL_F * 2);
    unsigned short* genex_bf = (unsigned short*)alloc((size_t)N_GENES * GENE_F * 2);
    unsigned short* W0cT = (unsigned short*)alloc((size_t)512 * CELL_F * 2);
    unsigned short* W0gT = (unsigned short*)alloc((size_t)512 * GENE_F * 2);
    unsigned short* W1cT = (unsigned short*)alloc((size_t)512 * HID * 2);
    unsigned short* W1gT = (unsigned short*)alloc((size_t)512 * HID * 2);
    unsigned short* WzcT = (unsigned short*)alloc((size_t)64 * HID * 2);
    unsigned short* WzgT = (unsigned short*)alloc((size_t)64 * HID * 2);
    unsigned short* WdcT = (unsigned short*)alloc((size_t)4032 * 64 * 2);
    unsigned short* WdgT = (unsigned short*)alloc((size_t)10048 * 64 * 2);
    int* cnt_c = (int*)alloc((size_t)(N_CELLS + N_GENES) * 4);   // cnt_c + cnt_g contiguous
    int* cnt_g = cnt_c + N_CELLS;
    int* ptr_c = (int*)alloc((size_t)(N_CELLS + 1) * 4);
    int* ptr_g = (int*)alloc((size_t)(N_GENES + 1) * 4);
    int* cur_c = (int*)alloc((size_t)N_CELLS * 4);
    int* cur_g = (int*)alloc((size_t)N_GENES * 4);
    int*   ci = (int*)alloc((size_t)N_EDGES * 4);
    float* cv = (float*)alloc((size_t)N_EDGES * 4);
    int*   gi = (int*)alloc((size_t)N_EDGES * 4);
    float* gv = (float*)alloc((size_t)N_EDGES * 4);

    // ---- CSR build ----
    hipMemsetAsync(cnt_c, 0, (size_t)(N_CELLS + N_GENES) * 4, stream);
    count_kernel<<<(N_EDGES + 255) / 256, 256, 0, stream>>>(er, ec, cnt_c, cnt_g);
    scan2_kernel<<<2, 1024, 0, stream>>>(cnt_c, ptr_c, cur_c, cnt_g, ptr_g, cur_g);
    scatter_kernel<<<(N_EDGES + 255) / 256, 256, 0, stream>>>(er, ec, ev, cur_c, cur_g,
                                                              ci, cv, gi, gv);

    // ---- input f32 -> bf16 (one launch, both matrices) ----
    {
        int na8 = N_CELLS * CELL_F / 8;   // 2,500,000
        int nb8 = N_GENES * GENE_F / 8;   // 25,000
        cvt2_bf16<<<(na8 + nb8 + 255) / 256, 256, 0, stream>>>(
            cell_x, cellx_bf, na8, gene_x, genex_bf, nb8);
    }

    // ---- weight packs: 8 packs in one launch ----
    {
        PackArgs pa;
        auto set = [&](int i, const float* W1, const float* W2, unsigned short* BT,
                       int K, int N1, int N2, int Np, int blk0) -> int {
            int xb = (K + 31) / 32, yb = (Np + 31) / 32;
            pa.d[i] = {W1, W2, BT, K, N1, N2, Np, xb, blk0};
            return blk0 + xb * yb;
        };
        int nb = 0;
        nb = set(0, l0_cs_w, l0_gn_w, W0cT, CELL_F, HID, HID, 512, nb);
        nb = set(1, l0_gs_w, l0_cn_w, W0gT, GENE_F, HID, HID, 512, nb);
        nb = set(2, l1_cs_w, l1_gn_w, W1cT, HID, HID, HID, 512, nb);
        nb = set(3, l1_gs_w, l1_cn_w, W1gT, HID, HID, HID, 512, nb);
        nb = set(4, cl_w, nullptr, WzcT, HID, LAT, 0, 64, nb);
        nb = set(5, gl_w, nullptr, WzgT, HID, LAT, 0, 64, nb);
        nb = set(6, cd_w, nullptr, WdcT, LAT, N_GENES, 0, 4032, nb);
        nb = set(7, gd_w, nullptr, WdgT, LAT, N_CELLS, 0, 10048, nb);
        pack_all<<<nb, 256, 0, stream>>>(pa);
    }

    #define GRID(Mv, Nv) dim3(((Nv) + 63) / 64, ((Mv) + 63) / 64)

    // ---- layer 0: [self | neigh] projections ----
    mfma_gemm<false, false, true><<<GRID(N_CELLS, 512), 256, 0, stream>>>(
        cellx_bf, W0cT, nullptr, nullptr, pre_c_bf, N_CELLS, 512, CELL_F);
    mfma_gemm<false, false, true><<<GRID(N_GENES, 512), 256, 0, stream>>>(
        genex_bf, W0gT, nullptr, nullptr, pre_g_bf, N_GENES, 512, GENE_F);

    agg_kernel<<<N_CELLS, 256, 0, stream>>>(ptr_c, ci, cv, pre_g_bf, pre_c_bf,
                                            l0_cs_b, l0_cn_b, c1_bf);
    agg_kernel<<<N_GENES, 256, 0, stream>>>(ptr_g, gi, gv, pre_c_bf, pre_g_bf,
                                            l0_gs_b, l0_gn_b, g1_bf);

    // ---- layer 1 ----
    mfma_gemm<false, false, true><<<GRID(N_CELLS, 512), 256, 0, stream>>>(
        c1_bf, W1cT, nullptr, nullptr, pre_c_bf, N_CELLS, 512, HID);
    mfma_gemm<false, false, true><<<GRID(N_GENES, 512), 256, 0, stream>>>(
        g1_bf, W1gT, nullptr, nullptr, pre_g_bf, N_GENES, 512, HID);

    agg_kernel<<<N_CELLS, 256, 0, stream>>>(ptr_c, ci, cv, pre_g_bf, pre_c_bf,
                                            l1_cs_b, l1_cn_b, c2_bf);
    agg_kernel<<<N_GENES, 256, 0, stream>>>(ptr_g, gi, gv, pre_c_bf, pre_g_bf,
                                            l1_gs_b, l1_gn_b, g2_bf);

    // ---- latent heads (f32 to d_out + bf16 for decoders) ----
    mfma_gemm<true, true, true><<<GRID(N_CELLS, LAT), 256, 0, stream>>>(
        c2_bf, WzcT, cl_b, z_cells, zc_bf, N_CELLS, LAT, HID);
    mfma_gemm<true, true, true><<<GRID(N_GENES, LAT), 256, 0, stream>>>(
        g2_bf, WzgT, gl_b, z_genes, zg_bf, N_GENES, LAT, HID);

    // ---- decoders ----
    mfma_gemm<true, true, false><<<GRID(N_CELLS, N_GENES), 256, 0, stream>>>(
        zc_bf, WdcT, cd_b, cell_recon, nullptr, N_CELLS, N_GENES, LAT);
    mfma_gemm<true, true, false><<<GRID(N_GENES, N_CELLS), 256, 0, stream>>>(
        zg_bf, WdgT, gd_b, gene_recon, nullptr, N_GENES, N_CELLS, LAT);

    // ---- DEC soft assignment ----
    q_kernel<<<(N_CELLS + 255) / 256, 256, 0, stream>>>(z_cells, centers, q);
}

// Round 8
// 513.720 us; speedup vs baseline: 1.4296x; 1.1418x over previous
//
#include <hip/hip_runtime.h>

#define N_CELLS 10000
#define N_GENES 4000
#define CELL_F  2000
#define CELL_FP 2048
#define GENE_F  50
#define GENE_FP 64
#define HID     256
#define LAT     64
#define NCLUST  20
#define N_EDGES 640000

typedef __attribute__((ext_vector_type(8))) short    bf16x8;
typedef __attribute__((ext_vector_type(8))) unsigned short u16x8;
typedef __attribute__((ext_vector_type(4))) float    f32x4;

__device__ __forceinline__ unsigned short f2bf(float f) {
    unsigned int u = __float_as_uint(f);
    unsigned int r = (u + 0x7FFFu + ((u >> 16) & 1u)) >> 16;
    return (unsigned short)r;
}
__device__ __forceinline__ float bf2f(unsigned short h) {
    return __uint_as_float(((unsigned int)h) << 16);
}

#define GLOAD_LDS16(gp, lp) __builtin_amdgcn_global_load_lds( \
    (const __attribute__((address_space(1))) void*)(gp), \
    (__attribute__((address_space(3))) void*)(lp), 16, 0, 0)

// ================= multi-GEMM (descriptor-dispatched) =================
// C(M,N) = A(M,K)@BT(N,K)^T [+bias]. K = padded stride, multiple of 64.
// 64x64 tile, BK=64, 4 waves. Staging via global_load_lds (linear LDS dest)
// with XOR chunk swizzle: slot s of row r holds global chunk s^(r&7);
// ds_read applies the same XOR (involution) -> conflict-minimal b128 reads.
struct GemmDesc {
    const unsigned short *A, *BT;
    const float *bias;
    float *C;
    unsigned short *Cbf;
    int M, N, K;        // K = padded stride (multiple of 64)
    int gx, nwg, blk0;  // gx = ceil(N/64), nwg = gx*ceil(M/64)
};
struct GemmArgs2 { GemmDesc d[2]; };

template<bool BIAS, bool WF32, bool WBF, bool TEPI, bool QTAIL>
__global__ __launch_bounds__(256)
void gemm_multi(GemmArgs2 ga, int qstart,
                const float* __restrict__ zq, const float* __restrict__ cent,
                float* __restrict__ qout)
{
    __shared__ __align__(16) unsigned char smem[16640];   // As(8K)+Bs(8K); Cs overlays
    unsigned short* As = (unsigned short*)smem;
    unsigned short* Bs = As + 4096;

    // ---------- q tail (DEC soft assignment), rides the decoder dispatch ----------
    if (QTAIL && (int)blockIdx.x >= qstart) {
        float* cs = (float*)smem;
        int tid = threadIdx.x;
        for (int l = tid; l < NCLUST * LAT; l += 256) cs[l] = cent[l];
        __syncthreads();
        int c = (blockIdx.x - qstart) * 256 + tid;
        if (c >= N_CELLS) return;
        float zr[LAT];
        #pragma unroll
        for (int k = 0; k < LAT; ++k) zr[k] = zq[(size_t)c * LAT + k];
        float num[NCLUST];
        float denom = 0.0f;
        for (int j = 0; j < NCLUST; ++j) {
            float d = 0.0f;
            #pragma unroll
            for (int k = 0; k < LAT; ++k) {
                float t = zr[k] - cs[j * LAT + k];
                d += t * t;
            }
            float n = 1.0f / (1.0f + d);
            num[j] = n;
            denom += n;
        }
        float inv = 1.0f / denom;
        for (int j = 0; j < NCLUST; ++j) qout[(size_t)c * NCLUST + j] = num[j] * inv;
        return;
    }

    // ---------- descriptor pick + XCD-bijective swizzle (m204) within desc ----------
    int b = blockIdx.x;
    int p = (b >= ga.d[1].blk0) ? 1 : 0;
    const GemmDesc d = ga.d[p];
    int lin = b - d.blk0;
    int q8 = d.nwg >> 3, r8 = d.nwg & 7;
    int xcd = lin & 7, idx = lin >> 3;
    int wgid = (xcd < r8 ? xcd * (q8 + 1) : r8 * (q8 + 1) + (xcd - r8) * q8) + idx;
    int by = wgid / d.gx;
    int bx = wgid - by * d.gx;

    const int tid  = threadIdx.x;
    const int lane = tid & 63;
    const int w    = tid >> 6;
    const int cn   = lane & 15;
    const int rj   = lane >> 4;
    const int row0 = by * 64;
    const int col0 = bx * 64;

    // per-lane staging slots: instruction (w,h) covers slots (w*2+h)*64 + lane
    const int slot0 = (w * 2) * 64 + lane;
    const int slot1 = slot0 + 64;
    const int r0s = slot0 >> 3, s0s = slot0 & 7, c0s = s0s ^ (r0s & 7);
    const int r1s = slot1 >> 3, s1s = slot1 & 7, c1s = s1s ^ (r1s & 7);
    const size_t arow0 = (size_t)min(row0 + r0s, d.M - 1) * d.K + c0s * 8;
    const size_t arow1 = (size_t)min(row0 + r1s, d.M - 1) * d.K + c1s * 8;
    const size_t brow0 = (size_t)(col0 + r0s) * d.K + c0s * 8;   // BT rows alloc-padded
    const size_t brow1 = (size_t)(col0 + r1s) * d.K + c1s * 8;
    unsigned short* ldsA = As + (w * 2) * 512;
    unsigned short* ldsB = Bs + (w * 2) * 512;

    f32x4 acc[4] = {};

    // ds_read swizzled offsets (A side)
    const int rA = w * 16 + cn, swA = rA & 7, abase = rA * 64;
    const int aoff0 = abase + ((rj)     ^ swA) * 8;   // kk=0
    const int aoff1 = abase + ((rj + 4) ^ swA) * 8;   // kk=32

    for (int kt = 0; kt < d.K; kt += 64) {
        GLOAD_LDS16(d.A  + arow0 + kt, ldsA);
        GLOAD_LDS16(d.A  + arow1 + kt, ldsA + 512);
        GLOAD_LDS16(d.BT + brow0 + kt, ldsB);
        GLOAD_LDS16(d.BT + brow1 + kt, ldsB + 512);
        __syncthreads();
        bf16x8 a0 = *(const bf16x8*)&As[aoff0];
        bf16x8 a1 = *(const bf16x8*)&As[aoff1];
        #pragma unroll
        for (int f = 0; f < 4; ++f) {
            int rB = f * 16 + cn, swB = rB & 7, bb = rB * 64;
            bf16x8 b0 = *(const bf16x8*)&Bs[bb + ((rj)     ^ swB) * 8];
            bf16x8 b1 = *(const bf16x8*)&Bs[bb + ((rj + 4) ^ swB) * 8];
            acc[f] = __builtin_amdgcn_mfma_f32_16x16x32_bf16(a0, b0, acc[f], 0, 0, 0);
            acc[f] = __builtin_amdgcn_mfma_f32_16x16x32_bf16(a1, b1, acc[f], 0, 0, 0);
        }
        __syncthreads();
    }

    if (TEPI) {
        // ---- LDS-transpose epilogue: 256B-contiguous f32 writes ----
        float* Cs = (float*)smem;     // [64][65]
        #pragma unroll
        for (int f = 0; f < 4; ++f)
            #pragma unroll
            for (int j = 0; j < 4; ++j)
                Cs[(w * 16 + rj * 4 + j) * 65 + f * 16 + cn] = acc[f][j];
        __syncthreads();
        #pragma unroll
        for (int i = 0; i < 4; ++i) {
            int slot = tid + i * 256;             // 0..1023
            int rr = slot >> 4, c4 = (slot & 15) * 4;
            int gr = row0 + rr, gc = col0 + c4;
            if (gr < d.M && gc < d.N) {           // N%4==0 for all TEPI users
                const float* cp = &Cs[rr * 65 + c4];
                float4 bv = BIAS ? *(const float4*)&d.bias[gc] : float4{0,0,0,0};
                float4 v;
                v.x = cp[0] + bv.x; v.y = cp[1] + bv.y;
                v.z = cp[2] + bv.z; v.w = cp[3] + bv.w;
                *(float4*)&d.C[(size_t)gr * d.N + gc] = v;
            }
        }
    } else {
        // ---- direct epilogue: D col = lane&15, row = (lane>>4)*4 + reg [m89] ----
        #pragma unroll
        for (int f = 0; f < 4; ++f) {
            int col = col0 + f * 16 + cn;
            if (col >= d.N) continue;
            float bv = BIAS ? d.bias[col] : 0.0f;
            #pragma unroll
            for (int j = 0; j < 4; ++j) {
                int r = row0 + w * 16 + rj * 4 + j;
                if (r < d.M) {
                    float val = acc[f][j] + bv;
                    if (WF32) d.C[(size_t)r * d.N + col] = val;
                    if (WBF)  d.Cbf[(size_t)r * d.N + col] = f2bf(val);
                }
            }
        }
    }
}

// ================= prep: count + input-cvt + weight packs, one dispatch =================
struct PackDesc {
    const float* W1; const float* W2; unsigned short* BT;
    int Kr, Kp, N1, N2, Np, xb, blk0;
};
struct PackArgs { PackDesc d[8]; };

#define CNT_BLK   2500        /* N_EDGES/256 */
#define CVTC_BLK  10000       /* one row each (256 chunks of 8 = 2048) */
#define CVTG_BLK  125         /* 4000*64/8/256 */
#define PACK_BLK0 (CNT_BLK + CVTC_BLK + CVTG_BLK)

__global__ __launch_bounds__(256)
void prep_kernel(const int* __restrict__ er, const int* __restrict__ ec,
                 int* __restrict__ cnt_c, int* __restrict__ cnt_g,
                 const float* __restrict__ cell_x, unsigned short* __restrict__ cellx_bf,
                 const float* __restrict__ gene_x, unsigned short* __restrict__ genex_bf,
                 PackArgs pa)
{
    __shared__ float tile[32][33];
    int b = blockIdx.x;
    int tid = threadIdx.x;
    if (b < CNT_BLK) {
        int e = b * 256 + tid;
        atomicAdd(&cnt_c[er[e]], 1);
        atomicAdd(&cnt_g[ec[e]], 1);
        return;
    }
    if (b < CNT_BLK + CVTC_BLK) {
        int row = b - CNT_BLK;
        int col = tid * 8;
        u16x8 v = {0, 0, 0, 0, 0, 0, 0, 0};
        if (col < CELL_F) {   // CELL_F%8==0: chunk fully real
            const float* src = cell_x + (size_t)row * CELL_F + col;
            float4 f0 = *(const float4*)src;
            float4 f1 = *(const float4*)(src + 4);
            v[0] = f2bf(f0.x); v[1] = f2bf(f0.y); v[2] = f2bf(f0.z); v[3] = f2bf(f0.w);
            v[4] = f2bf(f1.x); v[5] = f2bf(f1.y); v[6] = f2bf(f1.z); v[7] = f2bf(f1.w);
        }
        ((u16x8*)(cellx_bf + (size_t)row * CELL_FP))[tid] = v;
        return;
    }
    if (b < PACK_BLK0) {
        int idx = (b - CNT_BLK - CVTC_BLK) * 256 + tid;   // [0, 32000)
        int row = idx >> 3, c8 = idx & 7;
        int col = c8 * 8;
        u16x8 v = {0, 0, 0, 0, 0, 0, 0, 0};
        #pragma unroll
        for (int j = 0; j < 8; ++j)
            if (col + j < GENE_F) v[j] = f2bf(gene_x[(size_t)row * GENE_F + col + j]);
        ((u16x8*)(genex_bf + (size_t)row * GENE_FP))[c8] = v;
        return;
    }
    // ---- weight pack via LDS transpose; BT[n][k] over padded Kp, zeros beyond Kr ----
    int pb = b;
    int p = 0;
    #pragma unroll
    for (int i = 1; i < 8; ++i) if (pb >= pa.d[i].blk0) p = i;
    const PackDesc d = pa.d[p];
    int local = pb - d.blk0;
    int kb = local % d.xb, nb = local / d.xb;
    int k0 = kb * 32, n0 = nb * 32;
    int tx = tid & 31, ty = tid >> 5;
    #pragma unroll
    for (int yy = 0; yy < 4; ++yy) {
        int k = k0 + ty + yy * 8;
        int n = n0 + tx;
        float v = 0.0f;
        if (k < d.Kr) {
            if (n < d.N1) v = d.W1[(size_t)k * d.N1 + n];
            else if (n < d.N1 + d.N2) v = d.W2[(size_t)k * d.N2 + (n - d.N1)];
        }
        tile[ty + yy * 8][tx] = v;
    }
    __syncthreads();
    #pragma unroll
    for (int yy = 0; yy < 4; ++yy) {
        int n = n0 + ty + yy * 8;
        int k = k0 + tx;
        if (n < d.Np)
            d.BT[(size_t)n * d.Kp + k] = f2bf(tile[tx][ty + yy * 8]);
    }
}

// ================= CSR =================
__global__ __launch_bounds__(1024)
void scan2_kernel(const int* __restrict__ cnt_c, int* __restrict__ ptr_c, int* __restrict__ cur_c,
                  const int* __restrict__ cnt_g, int* __restrict__ ptr_g, int* __restrict__ cur_g)
{
    const int* cnt = blockIdx.x ? cnt_g : cnt_c;
    int* ptr = blockIdx.x ? ptr_g : ptr_c;
    int* cur = blockIdx.x ? cur_g : cur_c;
    int  n   = blockIdx.x ? N_GENES : N_CELLS;
    __shared__ int part[1024];
    int t = threadIdx.x;
    int chunk = (n + 1023) / 1024;
    int lo = t * chunk, hi = min(lo + chunk, n);
    int s = 0;
    for (int i = lo; i < hi; ++i) s += cnt[i];
    part[t] = s;
    __syncthreads();
    #pragma unroll
    for (int off = 1; off < 1024; off <<= 1) {
        int v = (t >= off) ? part[t - off] : 0;
        __syncthreads();
        part[t] += v;
        __syncthreads();
    }
    if (t == 1023) ptr[n] = part[1023];
    int run = part[t] - s;
    for (int i = lo; i < hi; ++i) { ptr[i] = run; cur[i] = run; run += cnt[i]; }
}

__global__ void scatter_kernel(const int* __restrict__ er, const int* __restrict__ ec,
                               const float* __restrict__ ev,
                               int* cur_c, int* cur_g,
                               int* __restrict__ ci, float* __restrict__ cv,
                               int* __restrict__ gi, float* __restrict__ gv)
{
    int e = blockIdx.x * blockDim.x + threadIdx.x;
    if (e < N_EDGES) {
        int r = er[e], c = ec[e];
        float v = ev[e];
        int pc = atomicAdd(&cur_c[r], 1);
        ci[pc] = c; cv[pc] = v;
        int pg = atomicAdd(&cur_g[c], 1);
        gi[pg] = r; gv[pg] = v;
    }
}

// ================= fused agg pair (cells + genes in one dispatch) =================
struct AggSide {
    const int *ptr, *nbr; const float *val;
    const unsigned short *src, *pre;
    const float *b1, *b2;
    unsigned short *out;
};
struct AggArgs { AggSide s[2]; };

__global__ __launch_bounds__(256)
void agg2_kernel(AggArgs aa)
{
    __shared__ __align__(16) float red[4][256];
    int b = blockIdx.x;
    int side = (b >= N_CELLS) ? 1 : 0;
    const AggSide S = aa.s[side];
    int r = side ? b - N_CELLS : b;
    int t = threadIdx.x;
    int w = t >> 6;
    int lane = t & 63;
    int s = S.ptr[r], e = S.ptr[r + 1];
    const ushort4* src4 = (const ushort4*)S.src;   // row stride 128 vec4, +64 = neigh half
    float4 acc = {0.0f, 0.0f, 0.0f, 0.0f};
    int i = s + w;
    for (; i + 4 < e; i += 8) {
        int   j0 = S.nbr[i],   j1 = S.nbr[i + 4];
        float v0 = S.val[i],   v1 = S.val[i + 4];
        ushort4 a = src4[(size_t)j0 * 128 + 64 + lane];
        ushort4 bb = src4[(size_t)j1 * 128 + 64 + lane];
        acc.x += v0 * bf2f(a.x) + v1 * bf2f(bb.x);
        acc.y += v0 * bf2f(a.y) + v1 * bf2f(bb.y);
        acc.z += v0 * bf2f(a.z) + v1 * bf2f(bb.z);
        acc.w += v0 * bf2f(a.w) + v1 * bf2f(bb.w);
    }
    if (i < e) {
        int j0 = S.nbr[i]; float v0 = S.val[i];
        ushort4 a = src4[(size_t)j0 * 128 + 64 + lane];
        acc.x += v0 * bf2f(a.x);
        acc.y += v0 * bf2f(a.y);
        acc.z += v0 * bf2f(a.z);
        acc.w += v0 * bf2f(a.w);
    }
    *(float4*)&red[w][lane * 4] = acc;
    __syncthreads();
    float x = red[0][t] + red[1][t] + red[2][t] + red[3][t]
            + bf2f(S.pre[(size_t)r * 512 + t]) + S.b1[t] + S.b2[t];
    S.out[(size_t)r * 256 + t] = f2bf(fmaxf(x, 0.0f));
}

extern "C" void kernel_launch(void* const* d_in, const int* in_sizes, int n_in,
                              void* d_out, int out_size, void* d_ws, size_t ws_size,
                              hipStream_t stream)
{
    const float* cell_x  = (const float*)d_in[0];
    const float* gene_x  = (const float*)d_in[1];
    const int*   er      = (const int*)d_in[2];
    const int*   ec      = (const int*)d_in[3];
    const float* ev      = (const float*)d_in[4];
    const float* l0_cs_w = (const float*)d_in[5];  const float* l0_cs_b = (const float*)d_in[6];
    const float* l0_cn_w = (const float*)d_in[7];  const float* l0_cn_b = (const float*)d_in[8];
    const float* l0_gs_w = (const float*)d_in[9];  const float* l0_gs_b = (const float*)d_in[10];
    const float* l0_gn_w = (const float*)d_in[11]; const float* l0_gn_b = (const float*)d_in[12];
    const float* l1_cs_w = (const float*)d_in[13]; const float* l1_cs_b = (const float*)d_in[14];
    const float* l1_cn_w = (const float*)d_in[15]; const float* l1_cn_b = (const float*)d_in[16];
    const float* l1_gs_w = (const float*)d_in[17]; const float* l1_gs_b = (const float*)d_in[18];
    const float* l1_gn_w = (const float*)d_in[19]; const float* l1_gn_b = (const float*)d_in[20];
    const float* cl_w = (const float*)d_in[21]; const float* cl_b = (const float*)d_in[22];
    const float* gl_w = (const float*)d_in[23]; const float* gl_b = (const float*)d_in[24];
    const float* cd_w = (const float*)d_in[25]; const float* cd_b = (const float*)d_in[26];
    const float* gd_w = (const float*)d_in[27]; const float* gd_b = (const float*)d_in[28];
    const float* centers = (const float*)d_in[29];

    float* out = (float*)d_out;
    float* z_cells    = out;
    float* z_genes    = out + 640000;
    float* cell_recon = out + 896000;
    float* gene_recon = out + 40896000;
    float* q          = out + 80896000;

    // ---- workspace arena (~90 MB) ----
    char* wsp = (char*)d_ws;
    auto alloc = [&](size_t bytes) -> void* {
        void* p = (void*)wsp;
        wsp += (bytes + 255) & ~(size_t)255;
        return p;
    };
    unsigned short* pre_c_bf = (unsigned short*)alloc((size_t)N_CELLS * 512 * 2);
    unsigned short* pre_g_bf = (unsigned short*)alloc((size_t)N_GENES * 512 * 2);
    unsigned short* c1_bf    = (unsigned short*)alloc((size_t)N_CELLS * 256 * 2);
    unsigned short* g1_bf    = (unsigned short*)alloc((size_t)N_GENES * 256 * 2);
    unsigned short* c2_bf    = (unsigned short*)alloc((size_t)N_CELLS * 256 * 2);
    unsigned short* g2_bf    = (unsigned short*)alloc((size_t)N_GENES * 256 * 2);
    unsigned short* zc_bf    = (unsigned short*)alloc((size_t)N_CELLS * 64 * 2);
    unsigned short* zg_bf    = (unsigned short*)alloc((size_t)N_GENES * 64 * 2);
    unsigned short* cellx_bf = (unsigned short*)alloc((size_t)N_CELLS * CELL_FP * 2);
    unsigned short* genex_bf = (unsigned short*)alloc((size_t)N_GENES * GENE_FP * 2);
    unsigned short* W0cT = (unsigned short*)alloc((size_t)512 * CELL_FP * 2);
    unsigned short* W0gT = (unsigned short*)alloc((size_t)512 * GENE_FP * 2);
    unsigned short* W1cT = (unsigned short*)alloc((size_t)512 * HID * 2);
    unsigned short* W1gT = (unsigned short*)alloc((size_t)512 * HID * 2);
    unsigned short* WzcT = (unsigned short*)alloc((size_t)64 * HID * 2);
    unsigned short* WzgT = (unsigned short*)alloc((size_t)64 * HID * 2);
    unsigned short* WdcT = (unsigned short*)alloc((size_t)4032 * 64 * 2);
    unsigned short* WdgT = (unsigned short*)alloc((size_t)10048 * 64 * 2);
    int* cnt_c = (int*)alloc((size_t)(N_CELLS + N_GENES) * 4);
    int* cnt_g = cnt_c + N_CELLS;
    int* ptr_c = (int*)alloc((size_t)(N_CELLS + 1) * 4);
    int* ptr_g = (int*)alloc((size_t)(N_GENES + 1) * 4);
    int* cur_c = (int*)alloc((size_t)N_CELLS * 4);
    int* cur_g = (int*)alloc((size_t)N_GENES * 4);
    int*   ci = (int*)alloc((size_t)N_EDGES * 4);
    float* cv = (float*)alloc((size_t)N_EDGES * 4);
    int*   gi = (int*)alloc((size_t)N_EDGES * 4);
    float* gv = (float*)alloc((size_t)N_EDGES * 4);

    // ---- D1: zero counters ----
    hipMemsetAsync(cnt_c, 0, (size_t)(N_CELLS + N_GENES) * 4, stream);

    // ---- D2: count + input cvt + weight packs (fused) ----
    {
        PackArgs pa;
        auto set = [&](int i, const float* W1, const float* W2, unsigned short* BT,
                       int Kr, int Kp, int N1, int N2, int Np, int blk0) -> int {
            int xb = Kp / 32, yb = Np / 32;
            pa.d[i] = {W1, W2, BT, Kr, Kp, N1, N2, Np, xb, blk0};
            return blk0 + xb * yb;
        };
        int nb = PACK_BLK0;
        nb = set(0, l0_cs_w, l0_gn_w, W0cT, CELL_F, CELL_FP, HID, HID, 512, nb);
        nb = set(1, l0_gs_w, l0_cn_w, W0gT, GENE_F, GENE_FP, HID, HID, 512, nb);
        nb = set(2, l1_cs_w, l1_gn_w, W1cT, HID, HID, HID, HID, 512, nb);
        nb = set(3, l1_gs_w, l1_cn_w, W1gT, HID, HID, HID, HID, 512, nb);
        nb = set(4, cl_w, nullptr, WzcT, HID, HID, LAT, 0, 64, nb);
        nb = set(5, gl_w, nullptr, WzgT, HID, HID, LAT, 0, 64, nb);
        nb = set(6, cd_w, nullptr, WdcT, LAT, LAT, N_GENES, 0, 4032, nb);
        nb = set(7, gd_w, nullptr, WdgT, LAT, LAT, N_CELLS, 0, 10048, nb);
        prep_kernel<<<nb, 256, 0, stream>>>(er, ec, cnt_c, cnt_g,
                                            cell_x, cellx_bf, gene_x, genex_bf, pa);
    }

    // ---- D3/D4: scan + scatter ----
    scan2_kernel<<<2, 1024, 0, stream>>>(cnt_c, ptr_c, cur_c, cnt_g, ptr_g, cur_g);
    scatter_kernel<<<(N_EDGES + 255) / 256, 256, 0, stream>>>(er, ec, ev, cur_c, cur_g,
                                                              ci, cv, gi, gv);

    auto mkdesc = [](const unsigned short* A, const unsigned short* BT, const float* bias,
                     float* C, unsigned short* Cbf, int M, int N, int K, int blk0) -> GemmDesc {
        int gx = (N + 63) / 64, gy = (M + 63) / 64;
        return {A, BT, bias, C, Cbf, M, N, K, gx, gx * gy, blk0};
    };

    // ---- D5: layer-0 projections (cell + gene GEMMs fused) ----
    {
        GemmArgs2 ga;
        ga.d[0] = mkdesc(cellx_bf, W0cT, nullptr, nullptr, pre_c_bf, N_CELLS, 512, CELL_FP, 0);
        ga.d[1] = mkdesc(genex_bf, W0gT, nullptr, nullptr, pre_g_bf, N_GENES, 512, GENE_FP,
                         ga.d[0].nwg);
        gemm_multi<false, false, true, false, false><<<ga.d[1].blk0 + ga.d[1].nwg, 256, 0, stream>>>(
            ga, 1 << 30, nullptr, nullptr, nullptr);
    }

    // ---- D6: layer-0 aggregation (both sides) ----
    {
        AggArgs aa;
        aa.s[0] = {ptr_c, ci, cv, pre_g_bf, pre_c_bf, l0_cs_b, l0_cn_b, c1_bf};
        aa.s[1] = {ptr_g, gi, gv, pre_c_bf, pre_g_bf, l0_gs_b, l0_gn_b, g1_bf};
        agg2_kernel<<<N_CELLS + N_GENES, 256, 0, stream>>>(aa);
    }

    // ---- D7: layer-1 projections ----
    {
        GemmArgs2 ga;
        ga.d[0] = mkdesc(c1_bf, W1cT, nullptr, nullptr, pre_c_bf, N_CELLS, 512, HID, 0);
        ga.d[1] = mkdesc(g1_bf, W1gT, nullptr, nullptr, pre_g_bf, N_GENES, 512, HID,
                         ga.d[0].nwg);
        gemm_multi<false, false, true, false, false><<<ga.d[1].blk0 + ga.d[1].nwg, 256, 0, stream>>>(
            ga, 1 << 30, nullptr, nullptr, nullptr);
    }

    // ---- D8: layer-1 aggregation ----
    {
        AggArgs aa;
        aa.s[0] = {ptr_c, ci, cv, pre_g_bf, pre_c_bf, l1_cs_b, l1_cn_b, c2_bf};
        aa.s[1] = {ptr_g, gi, gv, pre_c_bf, pre_g_bf, l1_gs_b, l1_gn_b, g2_bf};
        agg2_kernel<<<N_CELLS + N_GENES, 256, 0, stream>>>(aa);
    }

    // ---- D9: latent heads (f32 to d_out + bf16 for decoders) ----
    {
        GemmArgs2 ga;
        ga.d[0] = mkdesc(c2_bf, WzcT, cl_b, z_cells, zc_bf, N_CELLS, LAT, HID, 0);
        ga.d[1] = mkdesc(g2_bf, WzgT, gl_b, z_genes, zg_bf, N_GENES, LAT, HID, ga.d[0].nwg);
        gemm_multi<true, true, true, false, false><<<ga.d[1].blk0 + ga.d[1].nwg, 256, 0, stream>>>(
            ga, 1 << 30, nullptr, nullptr, nullptr);
    }

    // ---- D10: decoders (transpose epilogue) + q tail ----
    {
        GemmArgs2 ga;
        ga.d[0] = mkdesc(zc_bf, WdcT, cd_b, cell_recon, nullptr, N_CELLS, N_GENES, LAT, 0);
        ga.d[1] = mkdesc(zg_bf, WdgT, gd_b, gene_recon, nullptr, N_GENES, N_CELLS, LAT,
                         ga.d[0].nwg);
        int qstart = ga.d[1].blk0 + ga.d[1].nwg;
        int qblocks = (N_CELLS + 255) / 256;
        gemm_multi<true, true, false, true, true><<<qstart + qblocks, 256, 0, stream>>>(
            ga, qstart, z_cells, centers, q);
    }
}

// Round 9
// 495.212 us; speedup vs baseline: 1.4831x; 1.0374x over previous
//
#include <hip/hip_runtime.h>

#define N_CELLS 10000
#define N_GENES 4000
#define CELL_F  2000
#define CELL_FP 2048
#define GENE_F  50
#define GENE_FP 64
#define HID     256
#define LAT     64
#define NCLUST  20
#define N_EDGES 640000

typedef __attribute__((ext_vector_type(8))) short    bf16x8;
typedef __attribute__((ext_vector_type(8))) unsigned short u16x8;
typedef __attribute__((ext_vector_type(4))) float    f32x4;

__device__ __forceinline__ unsigned short f2bf(float f) {
    unsigned int u = __float_as_uint(f);
    unsigned int r = (u + 0x7FFFu + ((u >> 16) & 1u)) >> 16;
    return (unsigned short)r;
}
__device__ __forceinline__ float bf2f(unsigned short h) {
    return __uint_as_float(((unsigned int)h) << 16);
}

#define GLOAD_LDS16(gp, lp) __builtin_amdgcn_global_load_lds( \
    (const __attribute__((address_space(1))) void*)(gp), \
    (__attribute__((address_space(3))) void*)(lp), 16, 0, 0)

// ================= multi-GEMM (descriptor-dispatched, templated tile) =================
// C(M,N) = A(M,K)@BT(N,K)^T [+bias]. K = padded stride, multiple of 64.
// Tile TM x 64, BK=64, 4 waves. Staging via global_load_lds (linear LDS dest)
// with XOR chunk swizzle: slot s of row r holds global chunk s^(r&7);
// ds_read applies the same XOR (involution) -> conflict-minimal b128 reads.
struct GemmDesc {
    const unsigned short *A, *BT;
    const float *bias;
    float *C;
    unsigned short *Cbf;
    int M, N, K;
    int gx, nwg, blk0;
};
struct GemmArgs2 { GemmDesc d[2]; };
struct ScatArgs {
    const int *er, *ec; const float *ev;
    int *cur_c, *cur_g;
    int *ci; float *cv; int *gi; float *gv;
};

template<int TM, bool BIAS, bool WF32, bool WBF, bool TEPI, bool QTAIL, bool SCAT>
__global__ __launch_bounds__(256)
void gemm_multi(GemmArgs2 ga, int gemm0, int qstart,
                const float* __restrict__ zq, const float* __restrict__ cent,
                float* __restrict__ qout, ScatArgs sa)
{
    constexpr int SMEM = (TM * 128 + 8192) > 16640 ? (TM * 128 + 8192) : 16640;
    __shared__ __align__(16) unsigned char smem[SMEM];
    unsigned short* As = (unsigned short*)smem;
    unsigned short* Bs = As + TM * 64;

    // ---------- scatter head (CSR edge scatter), rides the L0-GEMM dispatch ----------
    if (SCAT && (int)blockIdx.x < gemm0) {
        int e = blockIdx.x * 256 + threadIdx.x;
        int r = sa.er[e], c = sa.ec[e];
        float v = sa.ev[e];
        int pc = atomicAdd(&sa.cur_c[r], 1);
        sa.ci[pc] = c; sa.cv[pc] = v;
        int pg = atomicAdd(&sa.cur_g[c], 1);
        sa.gi[pg] = r; sa.gv[pg] = v;
        return;
    }

    // ---------- q tail (DEC soft assignment), rides the decoder dispatch ----------
    if (QTAIL && (int)blockIdx.x >= qstart) {
        float* cs = (float*)smem;
        int tid = threadIdx.x;
        for (int l = tid; l < NCLUST * LAT; l += 256) cs[l] = cent[l];
        __syncthreads();
        int c = (blockIdx.x - qstart) * 256 + tid;
        if (c >= N_CELLS) return;
        float zr[LAT];
        #pragma unroll
        for (int k = 0; k < LAT; ++k) zr[k] = zq[(size_t)c * LAT + k];
        float num[NCLUST];
        float denom = 0.0f;
        for (int j = 0; j < NCLUST; ++j) {
            float d = 0.0f;
            #pragma unroll
            for (int k = 0; k < LAT; ++k) {
                float t = zr[k] - cs[j * LAT + k];
                d += t * t;
            }
            float n = 1.0f / (1.0f + d);
            num[j] = n;
            denom += n;
        }
        float inv = 1.0f / denom;
        for (int j = 0; j < NCLUST; ++j) qout[(size_t)c * NCLUST + j] = num[j] * inv;
        return;
    }

    // ---------- descriptor pick + XCD-bijective swizzle (m204) within desc ----------
    int b = blockIdx.x;
    int p = (b >= ga.d[1].blk0) ? 1 : 0;
    const GemmDesc d = ga.d[p];
    int lin = b - d.blk0;
    int q8 = d.nwg >> 3, r8 = d.nwg & 7;
    int xcd = lin & 7, idx = lin >> 3;
    int wgid = (xcd < r8 ? xcd * (q8 + 1) : r8 * (q8 + 1) + (xcd - r8) * q8) + idx;
    int by = wgid / d.gx;
    int bx = wgid - by * d.gx;

    const int tid  = threadIdx.x;
    const int lane = tid & 63;
    const int w    = tid >> 6;
    const int cn   = lane & 15;
    const int rj   = lane >> 4;
    const int row0 = by * TM;
    const int col0 = bx * 64;

    constexpr int AI = TM / 32;   // A gload_lds instructions per wave
    constexpr int MF = TM / 64;   // m-fragments per wave

    // staging addresses (A: AI insts/wave; B: 2 insts/wave)
    size_t arow[AI];
    unsigned short* ldsA[AI];
    #pragma unroll
    for (int j = 0; j < AI; ++j) {
        int slot = (w * AI + j) * 64 + lane;
        int rs = slot >> 3, ss = slot & 7, cs = ss ^ (rs & 7);
        arow[j] = (size_t)min(row0 + rs, d.M - 1) * d.K + cs * 8;
        ldsA[j] = As + (w * AI + j) * 512;
    }
    const int sb0 = (w * 2) * 64 + lane;
    const int sb1 = sb0 + 64;
    const int rb0 = sb0 >> 3, cb0 = (sb0 & 7) ^ (rb0 & 7);
    const int rb1 = sb1 >> 3, cb1 = (sb1 & 7) ^ (rb1 & 7);
    const size_t brow0 = (size_t)(col0 + rb0) * d.K + cb0 * 8;   // BT rows alloc-padded
    const size_t brow1 = (size_t)(col0 + rb1) * d.K + cb1 * 8;
    unsigned short* ldsB = Bs + (w * 2) * 512;

    // ds_read swizzled offsets (A side, per m-frag)
    int aoff0[MF], aoff1[MF];
    #pragma unroll
    for (int mf = 0; mf < MF; ++mf) {
        int rA = w * (TM / 4) + mf * 16 + cn, swA = rA & 7, abase = rA * 64;
        aoff0[mf] = abase + ((rj)     ^ swA) * 8;
        aoff1[mf] = abase + ((rj + 4) ^ swA) * 8;
    }

    f32x4 acc[MF][4] = {};

    for (int kt = 0; kt < d.K; kt += 64) {
        #pragma unroll
        for (int j = 0; j < AI; ++j) GLOAD_LDS16(d.A + arow[j] + kt, ldsA[j]);
        GLOAD_LDS16(d.BT + brow0 + kt, ldsB);
        GLOAD_LDS16(d.BT + brow1 + kt, ldsB + 512);
        __syncthreads();
        bf16x8 a0[MF], a1[MF];
        #pragma unroll
        for (int mf = 0; mf < MF; ++mf) {
            a0[mf] = *(const bf16x8*)&As[aoff0[mf]];
            a1[mf] = *(const bf16x8*)&As[aoff1[mf]];
        }
        #pragma unroll
        for (int f = 0; f < 4; ++f) {
            int rB = f * 16 + cn, swB = rB & 7, bb = rB * 64;
            bf16x8 b0 = *(const bf16x8*)&Bs[bb + ((rj)     ^ swB) * 8];
            bf16x8 b1 = *(const bf16x8*)&Bs[bb + ((rj + 4) ^ swB) * 8];
            #pragma unroll
            for (int mf = 0; mf < MF; ++mf) {
                acc[mf][f] = __builtin_amdgcn_mfma_f32_16x16x32_bf16(a0[mf], b0, acc[mf][f], 0, 0, 0);
                acc[mf][f] = __builtin_amdgcn_mfma_f32_16x16x32_bf16(a1[mf], b1, acc[mf][f], 0, 0, 0);
            }
        }
        __syncthreads();
    }

    if (TEPI) {
        // ---- LDS-transpose epilogue (TM=64 only): 256B-contiguous f32 writes ----
        float* Cs = (float*)smem;     // [64][65]
        __syncthreads();
        #pragma unroll
        for (int f = 0; f < 4; ++f)
            #pragma unroll
            for (int j = 0; j < 4; ++j)
                Cs[(w * 16 + rj * 4 + j) * 65 + f * 16 + cn] = acc[0][f][j];
        __syncthreads();
        #pragma unroll
        for (int i = 0; i < 4; ++i) {
            int slot = tid + i * 256;
            int rr = slot >> 4, c4 = (slot & 15) * 4;
            int gr = row0 + rr, gc = col0 + c4;
            if (gr < d.M && gc < d.N) {
                const float* cp = &Cs[rr * 65 + c4];
                float4 bv = BIAS ? *(const float4*)&d.bias[gc] : float4{0, 0, 0, 0};
                float4 v;
                v.x = cp[0] + bv.x; v.y = cp[1] + bv.y;
                v.z = cp[2] + bv.z; v.w = cp[3] + bv.w;
                *(float4*)&d.C[(size_t)gr * d.N + gc] = v;
            }
        }
    } else {
        // ---- direct epilogue: D col = lane&15, row = (lane>>4)*4 + reg [m89] ----
        #pragma unroll
        for (int mf = 0; mf < MF; ++mf) {
            #pragma unroll
            for (int f = 0; f < 4; ++f) {
                int col = col0 + f * 16 + cn;
                if (col >= d.N) continue;
                float bv = BIAS ? d.bias[col] : 0.0f;
                #pragma unroll
                for (int j = 0; j < 4; ++j) {
                    int r = row0 + w * (TM / 4) + mf * 16 + rj * 4 + j;
                    if (r < d.M) {
                        float val = acc[mf][f][j] + bv;
                        if (WF32) d.C[(size_t)r * d.N + col] = val;
                        if (WBF)  d.Cbf[(size_t)r * d.N + col] = f2bf(val);
                    }
                }
            }
        }
    }
}

// ================= prep: count + input-cvt + weight packs, one dispatch =================
struct PackDesc {
    const float* W1; const float* W2; unsigned short* BT;
    int Kr, Kp, N1, N2, Np, xb, blk0;
};
struct PackArgs { PackDesc d[8]; };

#define CNT_BLK   2500        /* N_EDGES/256 */
#define CVTC_BLK  10000
#define CVTG_BLK  125
#define PACK_BLK0 (CNT_BLK + CVTC_BLK + CVTG_BLK)

__global__ __launch_bounds__(256)
void prep_kernel(const int* __restrict__ er, const int* __restrict__ ec,
                 int* __restrict__ cnt_c, int* __restrict__ cnt_g,
                 const float* __restrict__ cell_x, unsigned short* __restrict__ cellx_bf,
                 const float* __restrict__ gene_x, unsigned short* __restrict__ genex_bf,
                 PackArgs pa)
{
    __shared__ float tile[32][33];
    int b = blockIdx.x;
    int tid = threadIdx.x;
    if (b < CNT_BLK) {
        int e = b * 256 + tid;
        atomicAdd(&cnt_c[er[e]], 1);
        atomicAdd(&cnt_g[ec[e]], 1);
        return;
    }
    if (b < CNT_BLK + CVTC_BLK) {
        int row = b - CNT_BLK;
        int col = tid * 8;
        u16x8 v = {0, 0, 0, 0, 0, 0, 0, 0};
        if (col < CELL_F) {
            const float* src = cell_x + (size_t)row * CELL_F + col;
            float4 f0 = *(const float4*)src;
            float4 f1 = *(const float4*)(src + 4);
            v[0] = f2bf(f0.x); v[1] = f2bf(f0.y); v[2] = f2bf(f0.z); v[3] = f2bf(f0.w);
            v[4] = f2bf(f1.x); v[5] = f2bf(f1.y); v[6] = f2bf(f1.z); v[7] = f2bf(f1.w);
        }
        ((u16x8*)(cellx_bf + (size_t)row * CELL_FP))[tid] = v;
        return;
    }
    if (b < PACK_BLK0) {
        int idx = (b - CNT_BLK - CVTC_BLK) * 256 + tid;
        int row = idx >> 3, c8 = idx & 7;
        int col = c8 * 8;
        u16x8 v = {0, 0, 0, 0, 0, 0, 0, 0};
        #pragma unroll
        for (int j = 0; j < 8; ++j)
            if (col + j < GENE_F) v[j] = f2bf(gene_x[(size_t)row * GENE_F + col + j]);
        ((u16x8*)(genex_bf + (size_t)row * GENE_FP))[c8] = v;
        return;
    }
    int pb = b;
    int p = 0;
    #pragma unroll
    for (int i = 1; i < 8; ++i) if (pb >= pa.d[i].blk0) p = i;
    const PackDesc d = pa.d[p];
    int local = pb - d.blk0;
    int kb = local % d.xb, nb = local / d.xb;
    int k0 = kb * 32, n0 = nb * 32;
    int tx = tid & 31, ty = tid >> 5;
    #pragma unroll
    for (int yy = 0; yy < 4; ++yy) {
        int k = k0 + ty + yy * 8;
        int n = n0 + tx;
        float v = 0.0f;
        if (k < d.Kr) {
            if (n < d.N1) v = d.W1[(size_t)k * d.N1 + n];
            else if (n < d.N1 + d.N2) v = d.W2[(size_t)k * d.N2 + (n - d.N1)];
        }
        tile[ty + yy * 8][tx] = v;
    }
    __syncthreads();
    #pragma unroll
    for (int yy = 0; yy < 4; ++yy) {
        int n = n0 + ty + yy * 8;
        int k = k0 + tx;
        if (n < d.Np)
            d.BT[(size_t)n * d.Kp + k] = f2bf(tile[tx][ty + yy * 8]);
    }
}

// ================= CSR scan =================
__global__ __launch_bounds__(1024)
void scan2_kernel(const int* __restrict__ cnt_c, int* __restrict__ ptr_c, int* __restrict__ cur_c,
                  const int* __restrict__ cnt_g, int* __restrict__ ptr_g, int* __restrict__ cur_g)
{
    const int* cnt = blockIdx.x ? cnt_g : cnt_c;
    int* ptr = blockIdx.x ? ptr_g : ptr_c;
    int* cur = blockIdx.x ? cur_g : cur_c;
    int  n   = blockIdx.x ? N_GENES : N_CELLS;
    __shared__ int part[1024];
    int t = threadIdx.x;
    int chunk = (n + 1023) / 1024;
    int lo = t * chunk, hi = min(lo + chunk, n);
    int s = 0;
    for (int i = lo; i < hi; ++i) s += cnt[i];
    part[t] = s;
    __syncthreads();
    #pragma unroll
    for (int off = 1; off < 1024; off <<= 1) {
        int v = (t >= off) ? part[t - off] : 0;
        __syncthreads();
        part[t] += v;
        __syncthreads();
    }
    if (t == 1023) ptr[n] = part[1023];
    int run = part[t] - s;
    for (int i = lo; i < hi; ++i) { ptr[i] = run; cur[i] = run; run += cnt[i]; }
}

// ================= fused agg pair (cells + genes, unroll-4) =================
struct AggSide {
    const int *ptr, *nbr; const float *val;
    const unsigned short *src, *pre;
    const float *b1, *b2;
    unsigned short *out;
};
struct AggArgs { AggSide s[2]; };

__global__ __launch_bounds__(256)
void agg2_kernel(AggArgs aa)
{
    __shared__ __align__(16) float red[4][256];
    int b = blockIdx.x;
    int side = (b >= N_CELLS) ? 1 : 0;
    const AggSide S = aa.s[side];
    int r = side ? b - N_CELLS : b;
    int t = threadIdx.x;
    int w = t >> 6;
    int lane = t & 63;
    int s = S.ptr[r], e = S.ptr[r + 1];
    const ushort4* src4 = (const ushort4*)S.src;   // row stride 128 vec4, +64 = neigh half
    float4 acc = {0.0f, 0.0f, 0.0f, 0.0f};
    int i = s + w;
    // 4-deep ILP: four independent nbr->gather chains in flight
    for (; i + 12 < e; i += 16) {
        int   j0 = S.nbr[i],     j1 = S.nbr[i + 4];
        int   j2 = S.nbr[i + 8], j3 = S.nbr[i + 12];
        float v0 = S.val[i],     v1 = S.val[i + 4];
        float v2 = S.val[i + 8], v3 = S.val[i + 12];
        ushort4 a0 = src4[(size_t)j0 * 128 + 64 + lane];
        ushort4 a1 = src4[(size_t)j1 * 128 + 64 + lane];
        ushort4 a2 = src4[(size_t)j2 * 128 + 64 + lane];
        ushort4 a3 = src4[(size_t)j3 * 128 + 64 + lane];
        acc.x += v0 * bf2f(a0.x) + v1 * bf2f(a1.x) + v2 * bf2f(a2.x) + v3 * bf2f(a3.x);
        acc.y += v0 * bf2f(a0.y) + v1 * bf2f(a1.y) + v2 * bf2f(a2.y) + v3 * bf2f(a3.y);
        acc.z += v0 * bf2f(a0.z) + v1 * bf2f(a1.z) + v2 * bf2f(a2.z) + v3 * bf2f(a3.z);
        acc.w += v0 * bf2f(a0.w) + v1 * bf2f(a1.w) + v2 * bf2f(a2.w) + v3 * bf2f(a3.w);
    }
    for (; i < e; i += 4) {
        int j0 = S.nbr[i]; float v0 = S.val[i];
        ushort4 a = src4[(size_t)j0 * 128 + 64 + lane];
        acc.x += v0 * bf2f(a.x);
        acc.y += v0 * bf2f(a.y);
        acc.z += v0 * bf2f(a.z);
        acc.w += v0 * bf2f(a.w);
    }
    *(float4*)&red[w][lane * 4] = acc;
    __syncthreads();
    float x = red[0][t] + red[1][t] + red[2][t] + red[3][t]
            + bf2f(S.pre[(size_t)r * 512 + t]) + S.b1[t] + S.b2[t];
    S.out[(size_t)r * 256 + t] = f2bf(fmaxf(x, 0.0f));
}

extern "C" void kernel_launch(void* const* d_in, const int* in_sizes, int n_in,
                              void* d_out, int out_size, void* d_ws, size_t ws_size,
                              hipStream_t stream)
{
    const float* cell_x  = (const float*)d_in[0];
    const float* gene_x  = (const float*)d_in[1];
    const int*   er      = (const int*)d_in[2];
    const int*   ec      = (const int*)d_in[3];
    const float* ev      = (const float*)d_in[4];
    const float* l0_cs_w = (const float*)d_in[5];  const float* l0_cs_b = (const float*)d_in[6];
    const float* l0_cn_w = (const float*)d_in[7];  const float* l0_cn_b = (const float*)d_in[8];
    const float* l0_gs_w = (const float*)d_in[9];  const float* l0_gs_b = (const float*)d_in[10];
    const float* l0_gn_w = (const float*)d_in[11]; const float* l0_gn_b = (const float*)d_in[12];
    const float* l1_cs_w = (const float*)d_in[13]; const float* l1_cs_b = (const float*)d_in[14];
    const float* l1_cn_w = (const float*)d_in[15]; const float* l1_cn_b = (const float*)d_in[16];
    const float* l1_gs_w = (const float*)d_in[17]; const float* l1_gs_b = (const float*)d_in[18];
    const float* l1_gn_w = (const float*)d_in[19]; const float* l1_gn_b = (const float*)d_in[20];
    const float* cl_w = (const float*)d_in[21]; const float* cl_b = (const float*)d_in[22];
    const float* gl_w = (const float*)d_in[23]; const float* gl_b = (const float*)d_in[24];
    const float* cd_w = (const float*)d_in[25]; const float* cd_b = (const float*)d_in[26];
    const float* gd_w = (const float*)d_in[27]; const float* gd_b = (const float*)d_in[28];
    const float* centers = (const float*)d_in[29];

    float* out = (float*)d_out;
    float* z_cells    = out;
    float* z_genes    = out + 640000;
    float* cell_recon = out + 896000;
    float* gene_recon = out + 40896000;
    float* q          = out + 80896000;

    // ---- workspace arena ----
    char* wsp = (char*)d_ws;
    auto alloc = [&](size_t bytes) -> void* {
        void* p = (void*)wsp;
        wsp += (bytes + 255) & ~(size_t)255;
        return p;
    };
    unsigned short* pre_c_bf = (unsigned short*)alloc((size_t)N_CELLS * 512 * 2);
    unsigned short* pre_g_bf = (unsigned short*)alloc((size_t)N_GENES * 512 * 2);
    unsigned short* c1_bf    = (unsigned short*)alloc((size_t)N_CELLS * 256 * 2);
    unsigned short* g1_bf    = (unsigned short*)alloc((size_t)N_GENES * 256 * 2);
    unsigned short* c2_bf    = (unsigned short*)alloc((size_t)N_CELLS * 256 * 2);
    unsigned short* g2_bf    = (unsigned short*)alloc((size_t)N_GENES * 256 * 2);
    unsigned short* zc_bf    = (unsigned short*)alloc((size_t)N_CELLS * 64 * 2);
    unsigned short* zg_bf    = (unsigned short*)alloc((size_t)N_GENES * 64 * 2);
    unsigned short* cellx_bf = (unsigned short*)alloc((size_t)N_CELLS * CELL_FP * 2);
    unsigned short* genex_bf = (unsigned short*)alloc((size_t)N_GENES * GENE_FP * 2);
    unsigned short* W0cT = (unsigned short*)alloc((size_t)512 * CELL_FP * 2);
    unsigned short* W0gT = (unsigned short*)alloc((size_t)512 * GENE_FP * 2);
    unsigned short* W1cT = (unsigned short*)alloc((size_t)512 * HID * 2);
    unsigned short* W1gT = (unsigned short*)alloc((size_t)512 * HID * 2);
    unsigned short* WzcT = (unsigned short*)alloc((size_t)64 * HID * 2);
    unsigned short* WzgT = (unsigned short*)alloc((size_t)64 * HID * 2);
    unsigned short* WdcT = (unsigned short*)alloc((size_t)4032 * 64 * 2);
    unsigned short* WdgT = (unsigned short*)alloc((size_t)10048 * 64 * 2);
    int* cnt_c = (int*)alloc((size_t)(N_CELLS + N_GENES) * 4);
    int* cnt_g = cnt_c + N_CELLS;
    int* ptr_c = (int*)alloc((size_t)(N_CELLS + 1) * 4);
    int* ptr_g = (int*)alloc((size_t)(N_GENES + 1) * 4);
    int* cur_c = (int*)alloc((size_t)N_CELLS * 4);
    int* cur_g = (int*)alloc((size_t)N_GENES * 4);
    int*   ci = (int*)alloc((size_t)N_EDGES * 4);
    float* cv = (float*)alloc((size_t)N_EDGES * 4);
    int*   gi = (int*)alloc((size_t)N_EDGES * 4);
    float* gv = (float*)alloc((size_t)N_EDGES * 4);

    // ---- D1: zero counters ----
    hipMemsetAsync(cnt_c, 0, (size_t)(N_CELLS + N_GENES) * 4, stream);

    // ---- D2: count + input cvt + weight packs (fused) ----
    {
        PackArgs pa;
        auto set = [&](int i, const float* W1, const float* W2, unsigned short* BT,
                       int Kr, int Kp, int N1, int N2, int Np, int blk0) -> int {
            int xb = Kp / 32, yb = Np / 32;
            pa.d[i] = {W1, W2, BT, Kr, Kp, N1, N2, Np, xb, blk0};
            return blk0 + xb * yb;
        };
        int nb = PACK_BLK0;
        nb = set(0, l0_cs_w, l0_gn_w, W0cT, CELL_F, CELL_FP, HID, HID, 512, nb);
        nb = set(1, l0_gs_w, l0_cn_w, W0gT, GENE_F, GENE_FP, HID, HID, 512, nb);
        nb = set(2, l1_cs_w, l1_gn_w, W1cT, HID, HID, HID, HID, 512, nb);
        nb = set(3, l1_gs_w, l1_cn_w, W1gT, HID, HID, HID, HID, 512, nb);
        nb = set(4, cl_w, nullptr, WzcT, HID, HID, LAT, 0, 64, nb);
        nb = set(5, gl_w, nullptr, WzgT, HID, HID, LAT, 0, 64, nb);
        nb = set(6, cd_w, nullptr, WdcT, LAT, LAT, N_GENES, 0, 4032, nb);
        nb = set(7, gd_w, nullptr, WdgT, LAT, LAT, N_CELLS, 0, 10048, nb);
        prep_kernel<<<nb, 256, 0, stream>>>(er, ec, cnt_c, cnt_g,
                                            cell_x, cellx_bf, gene_x, genex_bf, pa);
    }

    // ---- D3: scan (seeds cur = ptr) ----
    scan2_kernel<<<2, 1024, 0, stream>>>(cnt_c, ptr_c, cur_c, cnt_g, ptr_g, cur_g);

    auto mkdesc = [](const unsigned short* A, const unsigned short* BT, const float* bias,
                     float* C, unsigned short* Cbf, int M, int N, int K, int TMv,
                     int blk0) -> GemmDesc {
        int gx = (N + 63) / 64, gy = (M + TMv - 1) / TMv;
        return {A, BT, bias, C, Cbf, M, N, K, gx, gx * gy, blk0};
    };
    ScatArgs sa0 = {er, ec, ev, cur_c, cur_g, ci, cv, gi, gv};
    ScatArgs saN = {};

    // ---- D4: scatter + layer-0 projections (TM=128) ----
    {
        GemmArgs2 ga;
        ga.d[0] = mkdesc(cellx_bf, W0cT, nullptr, nullptr, pre_c_bf, N_CELLS, 512, CELL_FP, 128, CNT_BLK);
        ga.d[1] = mkdesc(genex_bf, W0gT, nullptr, nullptr, pre_g_bf, N_GENES, 512, GENE_FP, 128,
                         CNT_BLK + ga.d[0].nwg);
        gemm_multi<128, false, false, true, false, false, true>
            <<<ga.d[1].blk0 + ga.d[1].nwg, 256, 0, stream>>>(
            ga, CNT_BLK, 1 << 30, nullptr, nullptr, nullptr, sa0);
    }

    // ---- D5: layer-0 aggregation ----
    {
        AggArgs aa;
        aa.s[0] = {ptr_c, ci, cv, pre_g_bf, pre_c_bf, l0_cs_b, l0_cn_b, c1_bf};
        aa.s[1] = {ptr_g, gi, gv, pre_c_bf, pre_g_bf, l0_gs_b, l0_gn_b, g1_bf};
        agg2_kernel<<<N_CELLS + N_GENES, 256, 0, stream>>>(aa);
    }

    // ---- D6: layer-1 projections (TM=128) ----
    {
        GemmArgs2 ga;
        ga.d[0] = mkdesc(c1_bf, W1cT, nullptr, nullptr, pre_c_bf, N_CELLS, 512, HID, 128, 0);
        ga.d[1] = mkdesc(g1_bf, W1gT, nullptr, nullptr, pre_g_bf, N_GENES, 512, HID, 128,
                         ga.d[0].nwg);
        gemm_multi<128, false, false, true, false, false, false>
            <<<ga.d[1].blk0 + ga.d[1].nwg, 256, 0, stream>>>(
            ga, 0, 1 << 30, nullptr, nullptr, nullptr, saN);
    }

    // ---- D7: layer-1 aggregation ----
    {
        AggArgs aa;
        aa.s[0] = {ptr_c, ci, cv, pre_g_bf, pre_c_bf, l1_cs_b, l1_cn_b, c2_bf};
        aa.s[1] = {ptr_g, gi, gv, pre_c_bf, pre_g_bf, l1_gs_b, l1_gn_b, g2_bf};
        agg2_kernel<<<N_CELLS + N_GENES, 256, 0, stream>>>(aa);
    }

    // ---- D8: latent heads (TM=64) ----
    {
        GemmArgs2 ga;
        ga.d[0] = mkdesc(c2_bf, WzcT, cl_b, z_cells, zc_bf, N_CELLS, LAT, HID, 64, 0);
        ga.d[1] = mkdesc(g2_bf, WzgT, gl_b, z_genes, zg_bf, N_GENES, LAT, HID, 64, ga.d[0].nwg);
        gemm_multi<64, true, true, true, false, false, false>
            <<<ga.d[1].blk0 + ga.d[1].nwg, 256, 0, stream>>>(
            ga, 0, 1 << 30, nullptr, nullptr, nullptr, saN);
    }

    // ---- D9: decoders (TM=64, transpose epilogue) + q tail ----
    {
        GemmArgs2 ga;
        ga.d[0] = mkdesc(zc_bf, WdcT, cd_b, cell_recon, nullptr, N_CELLS, N_GENES, LAT, 64, 0);
        ga.d[1] = mkdesc(zg_bf, WdgT, gd_b, gene_recon, nullptr, N_GENES, N_CELLS, LAT, 64,
                         ga.d[0].nwg);
        int qstart = ga.d[1].blk0 + ga.d[1].nwg;
        int qblocks = (N_CELLS + 255) / 256;
        gemm_multi<64, true, true, false, true, true, false>
            <<<qstart + qblocks, 256, 0, stream>>>(
            ga, 0, qstart, z_cells, centers, q, saN);
    }
}

// Round 10
// 480.158 us; speedup vs baseline: 1.5296x; 1.0314x over previous
//
#include <hip/hip_runtime.h>

#define N_CELLS 10000
#define N_GENES 4000
#define CELL_F  2000
#define CELL_FP 2048
#define GENE_F  50
#define GENE_FP 64
#define HID     256
#define LAT     64
#define NCLUST  20
#define N_EDGES 640000

typedef __attribute__((ext_vector_type(8))) short    bf16x8;
typedef __attribute__((ext_vector_type(8))) unsigned short u16x8;
typedef __attribute__((ext_vector_type(4))) float    f32x4;

__device__ __forceinline__ unsigned short f2bf(float f) {
    unsigned int u = __float_as_uint(f);
    unsigned int r = (u + 0x7FFFu + ((u >> 16) & 1u)) >> 16;
    return (unsigned short)r;
}
__device__ __forceinline__ float bf2f(unsigned short h) {
    return __uint_as_float(((unsigned int)h) << 16);
}

#define GLOAD_LDS16(gp, lp) __builtin_amdgcn_global_load_lds( \
    (const __attribute__((address_space(1))) void*)(gp), \
    (__attribute__((address_space(3))) void*)(lp), 16, 0, 0)

// ================= multi-GEMM (descriptor-dispatched, templated tile) =================
// C(M,N) = A(M,K)@BT(N,K)^T [+bias]. K = padded stride, multiple of 64.
// Tile TM x 64, BK=64, 4 waves. Staging via global_load_lds (linear LDS dest)
// with XOR chunk swizzle: slot s of row r holds global chunk s^(r&7);
// ds_read applies the same XOR (involution) -> conflict-minimal b128 reads.
struct GemmDesc {
    const unsigned short *A, *BT;
    const float *bias;
    float *C;
    unsigned short *Cbf;
    int M, N, K;
    int gx, nwg, blk0;
};
struct GemmArgs2 { GemmDesc d[2]; };
struct ScatArgs {
    const int *er, *ec; const float *ev;
    int *cur_c, *cur_g;
    int *ci; float *cv; int *gi; float *gv;
};

template<int TM, bool BIAS, bool WF32, bool WBF, bool TEPI, bool QTAIL, bool SCAT>
__global__ __launch_bounds__(256)
void gemm_multi(GemmArgs2 ga, int gemm0, int qstart,
                const float* __restrict__ zq, const float* __restrict__ cent,
                float* __restrict__ qout, ScatArgs sa)
{
    constexpr int SMEM = (TM * 128 + 8192) > 16640 ? (TM * 128 + 8192) : 16640;
    __shared__ __align__(16) unsigned char smem[SMEM];
    unsigned short* As = (unsigned short*)smem;
    unsigned short* Bs = As + TM * 64;

    // ---------- scatter head (CSR edge scatter), rides the L0-GEMM dispatch ----------
    if (SCAT && (int)blockIdx.x < gemm0) {
        int e = blockIdx.x * 256 + threadIdx.x;
        int r = sa.er[e], c = sa.ec[e];
        float v = sa.ev[e];
        int pc = atomicAdd(&sa.cur_c[r], 1);
        sa.ci[pc] = c; sa.cv[pc] = v;
        int pg = atomicAdd(&sa.cur_g[c], 1);
        sa.gi[pg] = r; sa.gv[pg] = v;
        return;
    }

    // ---------- q tail (DEC soft assignment), rides the decoder dispatch ----------
    if (QTAIL && (int)blockIdx.x >= qstart) {
        float* cs = (float*)smem;
        int tid = threadIdx.x;
        for (int l = tid; l < NCLUST * LAT; l += 256) cs[l] = cent[l];
        __syncthreads();
        int c = (blockIdx.x - qstart) * 256 + tid;
        if (c >= N_CELLS) return;
        float zr[LAT];
        #pragma unroll
        for (int k = 0; k < LAT; ++k) zr[k] = zq[(size_t)c * LAT + k];
        float num[NCLUST];
        float denom = 0.0f;
        for (int j = 0; j < NCLUST; ++j) {
            float d = 0.0f;
            #pragma unroll
            for (int k = 0; k < LAT; ++k) {
                float t = zr[k] - cs[j * LAT + k];
                d += t * t;
            }
            float n = 1.0f / (1.0f + d);
            num[j] = n;
            denom += n;
        }
        float inv = 1.0f / denom;
        for (int j = 0; j < NCLUST; ++j) qout[(size_t)c * NCLUST + j] = num[j] * inv;
        return;
    }

    // ---------- descriptor pick + XCD-bijective swizzle (m204) within desc ----------
    int b = blockIdx.x;
    int p = (b >= ga.d[1].blk0) ? 1 : 0;
    const GemmDesc d = ga.d[p];
    int lin = b - d.blk0;
    int q8 = d.nwg >> 3, r8 = d.nwg & 7;
    int xcd = lin & 7, idx = lin >> 3;
    int wgid = (xcd < r8 ? xcd * (q8 + 1) : r8 * (q8 + 1) + (xcd - r8) * q8) + idx;
    int by = wgid / d.gx;
    int bx = wgid - by * d.gx;

    const int tid  = threadIdx.x;
    const int lane = tid & 63;
    const int w    = tid >> 6;
    const int cn   = lane & 15;
    const int rj   = lane >> 4;
    const int row0 = by * TM;
    const int col0 = bx * 64;

    constexpr int AI = TM / 32;   // A gload_lds instructions per wave
    constexpr int MF = TM / 64;   // m-fragments per wave

    // staging addresses (A: AI insts/wave; B: 2 insts/wave)
    size_t arow[AI];
    unsigned short* ldsA[AI];
    #pragma unroll
    for (int j = 0; j < AI; ++j) {
        int slot = (w * AI + j) * 64 + lane;
        int rs = slot >> 3, ss = slot & 7, cs = ss ^ (rs & 7);
        arow[j] = (size_t)min(row0 + rs, d.M - 1) * d.K + cs * 8;
        ldsA[j] = As + (w * AI + j) * 512;
    }
    const int sb0 = (w * 2) * 64 + lane;
    const int sb1 = sb0 + 64;
    const int rb0 = sb0 >> 3, cb0 = (sb0 & 7) ^ (rb0 & 7);
    const int rb1 = sb1 >> 3, cb1 = (sb1 & 7) ^ (rb1 & 7);
    const size_t brow0 = (size_t)(col0 + rb0) * d.K + cb0 * 8;   // BT rows alloc-padded
    const size_t brow1 = (size_t)(col0 + rb1) * d.K + cb1 * 8;
    unsigned short* ldsB = Bs + (w * 2) * 512;

    // ds_read swizzled offsets (A side, per m-frag)
    int aoff0[MF], aoff1[MF];
    #pragma unroll
    for (int mf = 0; mf < MF; ++mf) {
        int rA = w * (TM / 4) + mf * 16 + cn, swA = rA & 7, abase = rA * 64;
        aoff0[mf] = abase + ((rj)     ^ swA) * 8;
        aoff1[mf] = abase + ((rj + 4) ^ swA) * 8;
    }

    f32x4 acc[MF][4] = {};

    for (int kt = 0; kt < d.K; kt += 64) {
        #pragma unroll
        for (int j = 0; j < AI; ++j) GLOAD_LDS16(d.A + arow[j] + kt, ldsA[j]);
        GLOAD_LDS16(d.BT + brow0 + kt, ldsB);
        GLOAD_LDS16(d.BT + brow1 + kt, ldsB + 512);
        __syncthreads();
        bf16x8 a0[MF], a1[MF];
        #pragma unroll
        for (int mf = 0; mf < MF; ++mf) {
            a0[mf] = *(const bf16x8*)&As[aoff0[mf]];
            a1[mf] = *(const bf16x8*)&As[aoff1[mf]];
        }
        #pragma unroll
        for (int f = 0; f < 4; ++f) {
            int rB = f * 16 + cn, swB = rB & 7, bb = rB * 64;
            bf16x8 b0 = *(const bf16x8*)&Bs[bb + ((rj)     ^ swB) * 8];
            bf16x8 b1 = *(const bf16x8*)&Bs[bb + ((rj + 4) ^ swB) * 8];
            #pragma unroll
            for (int mf = 0; mf < MF; ++mf) {
                acc[mf][f] = __builtin_amdgcn_mfma_f32_16x16x32_bf16(a0[mf], b0, acc[mf][f], 0, 0, 0);
                acc[mf][f] = __builtin_amdgcn_mfma_f32_16x16x32_bf16(a1[mf], b1, acc[mf][f], 0, 0, 0);
            }
        }
        __syncthreads();
    }

    if (TEPI) {
        // ---- LDS-transpose epilogue (TM=64 only): 256B-contiguous f32 writes ----
        float* Cs = (float*)smem;     // [64][65]
        __syncthreads();
        #pragma unroll
        for (int f = 0; f < 4; ++f)
            #pragma unroll
            for (int j = 0; j < 4; ++j)
                Cs[(w * 16 + rj * 4 + j) * 65 + f * 16 + cn] = acc[0][f][j];
        __syncthreads();
        #pragma unroll
        for (int i = 0; i < 4; ++i) {
            int slot = tid + i * 256;
            int rr = slot >> 4, c4 = (slot & 15) * 4;
            int gr = row0 + rr, gc = col0 + c4;
            if (gr < d.M && gc < d.N) {
                const float* cp = &Cs[rr * 65 + c4];
                float4 bv = BIAS ? *(const float4*)&d.bias[gc] : float4{0, 0, 0, 0};
                float4 v;
                v.x = cp[0] + bv.x; v.y = cp[1] + bv.y;
                v.z = cp[2] + bv.z; v.w = cp[3] + bv.w;
                *(float4*)&d.C[(size_t)gr * d.N + gc] = v;
            }
        }
    } else {
        // ---- direct epilogue: D col = lane&15, row = (lane>>4)*4 + reg [m89] ----
        #pragma unroll
        for (int mf = 0; mf < MF; ++mf) {
            #pragma unroll
            for (int f = 0; f < 4; ++f) {
                int col = col0 + f * 16 + cn;
                if (col >= d.N) continue;
                float bv = BIAS ? d.bias[col] : 0.0f;
                #pragma unroll
                for (int j = 0; j < 4; ++j) {
                    int r = row0 + w * (TM / 4) + mf * 16 + rj * 4 + j;
                    if (r < d.M) {
                        float val = acc[mf][f][j] + bv;
                        if (WF32) d.C[(size_t)r * d.N + col] = val;
                        if (WBF)  d.Cbf[(size_t)r * d.N + col] = f2bf(val);
                    }
                }
            }
        }
    }
}

// ================= prep: count + input-cvt + weight packs, one dispatch =================
struct PackDesc {
    const float* W1; const float* W2; unsigned short* BT;
    int Kr, Kp, N1, N2, Np, xb, blk0;
};
struct PackArgs { PackDesc d[8]; };

#define CNT_BLK   2500        /* N_EDGES/256 */
#define CVTC_BLK  10000
#define CVTG_BLK  125
#define PACK_BLK0 (CNT_BLK + CVTC_BLK + CVTG_BLK)

__global__ __launch_bounds__(256)
void prep_kernel(const int* __restrict__ er, const int* __restrict__ ec,
                 int* __restrict__ cnt_c, int* __restrict__ cnt_g,
                 const float* __restrict__ cell_x, unsigned short* __restrict__ cellx_bf,
                 const float* __restrict__ gene_x, unsigned short* __restrict__ genex_bf,
                 PackArgs pa)
{
    __shared__ float tile[32][33];
    int b = blockIdx.x;
    int tid = threadIdx.x;
    if (b < CNT_BLK) {
        int e = b * 256 + tid;
        atomicAdd(&cnt_c[er[e]], 1);
        atomicAdd(&cnt_g[ec[e]], 1);
        return;
    }
    if (b < CNT_BLK + CVTC_BLK) {
        int row = b - CNT_BLK;
        int col = tid * 8;
        u16x8 v = {0, 0, 0, 0, 0, 0, 0, 0};
        if (col < CELL_F) {
            const float* src = cell_x + (size_t)row * CELL_F + col;
            float4 f0 = *(const float4*)src;
            float4 f1 = *(const float4*)(src + 4);
            v[0] = f2bf(f0.x); v[1] = f2bf(f0.y); v[2] = f2bf(f0.z); v[3] = f2bf(f0.w);
            v[4] = f2bf(f1.x); v[5] = f2bf(f1.y); v[6] = f2bf(f1.z); v[7] = f2bf(f1.w);
        }
        ((u16x8*)(cellx_bf + (size_t)row * CELL_FP))[tid] = v;
        return;
    }
    if (b < PACK_BLK0) {
        int idx = (b - CNT_BLK - CVTC_BLK) * 256 + tid;
        int row = idx >> 3, c8 = idx & 7;
        int col = c8 * 8;
        u16x8 v = {0, 0, 0, 0, 0, 0, 0, 0};
        #pragma unroll
        for (int j = 0; j < 8; ++j)
            if (col + j < GENE_F) v[j] = f2bf(gene_x[(size_t)row * GENE_F + col + j]);
        ((u16x8*)(genex_bf + (size_t)row * GENE_FP))[c8] = v;
        return;
    }
    int pb = b;
    int p = 0;
    #pragma unroll
    for (int i = 1; i < 8; ++i) if (pb >= pa.d[i].blk0) p = i;
    const PackDesc d = pa.d[p];
    int local = pb - d.blk0;
    int kb = local % d.xb, nb = local / d.xb;
    int k0 = kb * 32, n0 = nb * 32;
    int tx = tid & 31, ty = tid >> 5;
    #pragma unroll
    for (int yy = 0; yy < 4; ++yy) {
        int k = k0 + ty + yy * 8;
        int n = n0 + tx;
        float v = 0.0f;
        if (k < d.Kr) {
            if (n < d.N1) v = d.W1[(size_t)k * d.N1 + n];
            else if (n < d.N1 + d.N2) v = d.W2[(size_t)k * d.N2 + (n - d.N1)];
        }
        tile[ty + yy * 8][tx] = v;
    }
    __syncthreads();
    #pragma unroll
    for (int yy = 0; yy < 4; ++yy) {
        int n = n0 + ty + yy * 8;
        int k = k0 + tx;
        if (n < d.Np)
            d.BT[(size_t)n * d.Kp + k] = f2bf(tile[tx][ty + yy * 8]);
    }
}

// ================= CSR scan =================
__global__ __launch_bounds__(1024)
void scan2_kernel(const int* __restrict__ cnt_c, int* __restrict__ ptr_c, int* __restrict__ cur_c,
                  const int* __restrict__ cnt_g, int* __restrict__ ptr_g, int* __restrict__ cur_g)
{
    const int* cnt = blockIdx.x ? cnt_g : cnt_c;
    int* ptr = blockIdx.x ? ptr_g : ptr_c;
    int* cur = blockIdx.x ? cur_g : cur_c;
    int  n   = blockIdx.x ? N_GENES : N_CELLS;
    __shared__ int part[1024];
    int t = threadIdx.x;
    int chunk = (n + 1023) / 1024;
    int lo = t * chunk, hi = min(lo + chunk, n);
    int s = 0;
    for (int i = lo; i < hi; ++i) s += cnt[i];
    part[t] = s;
    __syncthreads();
    #pragma unroll
    for (int off = 1; off < 1024; off <<= 1) {
        int v = (t >= off) ? part[t - off] : 0;
        __syncthreads();
        part[t] += v;
        __syncthreads();
    }
    if (t == 1023) ptr[n] = part[1023];
    int run = part[t] - s;
    for (int i = lo; i < hi; ++i) { ptr[i] = run; cur[i] = run; run += cnt[i]; }
}

// ================= fused agg pair — shuffle-batched gathers =================
// Block-per-row; each wave takes a CONTIGUOUS quarter of the row's edges.
// Per 16-edge batch: lanes 0-15 load (nbr,val) coalesced, __shfl-broadcast,
// then a fully-unrolled block of 16 INDEPENDENT 512B gathers (deep MLP).
// Invalid slots gather row 0 scaled by 0.0 (exact no-op).
struct AggSide {
    const int *ptr, *nbr; const float *val;
    const unsigned short *src, *pre;
    const float *b1, *b2;
    unsigned short *out;
};
struct AggArgs { AggSide s[2]; };

__global__ __launch_bounds__(256)
void agg2_kernel(AggArgs aa)
{
    __shared__ __align__(16) float red[4][256];
    int b = blockIdx.x;
    int side = (b >= N_CELLS) ? 1 : 0;
    const AggSide S = aa.s[side];
    int r = side ? b - N_CELLS : b;
    int t = threadIdx.x;
    int w = t >> 6;
    int lane = t & 63;
    int s = S.ptr[r], e = S.ptr[r + 1];
    int n = e - s;
    int chunk = (n + 3) >> 2;
    int ws = s + w * chunk;
    int we = min(ws + chunk, e);
    const ushort4* src4 = (const ushort4*)S.src;   // row stride 128 vec4, +64 = neigh half
    float4 acc = {0.0f, 0.0f, 0.0f, 0.0f};
    for (int base = ws; base < we; base += 16) {
        int   nb = 0;
        float vb = 0.0f;
        if (lane < 16 && base + lane < we) {
            nb = S.nbr[base + lane];
            vb = S.val[base + lane];
        }
        #pragma unroll
        for (int j = 0; j < 16; ++j) {
            int   jj = __shfl(nb, j);
            float vv = __shfl(vb, j);
            ushort4 a = src4[(size_t)jj * 128 + 64 + lane];
            acc.x += vv * bf2f(a.x);
            acc.y += vv * bf2f(a.y);
            acc.z += vv * bf2f(a.z);
            acc.w += vv * bf2f(a.w);
        }
    }
    *(float4*)&red[w][lane * 4] = acc;
    __syncthreads();
    float x = red[0][t] + red[1][t] + red[2][t] + red[3][t]
            + bf2f(S.pre[(size_t)r * 512 + t]) + S.b1[t] + S.b2[t];
    S.out[(size_t)r * 256 + t] = f2bf(fmaxf(x, 0.0f));
}

extern "C" void kernel_launch(void* const* d_in, const int* in_sizes, int n_in,
                              void* d_out, int out_size, void* d_ws, size_t ws_size,
                              hipStream_t stream)
{
    const float* cell_x  = (const float*)d_in[0];
    const float* gene_x  = (const float*)d_in[1];
    const int*   er      = (const int*)d_in[2];
    const int*   ec      = (const int*)d_in[3];
    const float* ev      = (const float*)d_in[4];
    const float* l0_cs_w = (const float*)d_in[5];  const float* l0_cs_b = (const float*)d_in[6];
    const float* l0_cn_w = (const float*)d_in[7];  const float* l0_cn_b = (const float*)d_in[8];
    const float* l0_gs_w = (const float*)d_in[9];  const float* l0_gs_b = (const float*)d_in[10];
    const float* l0_gn_w = (const float*)d_in[11]; const float* l0_gn_b = (const float*)d_in[12];
    const float* l1_cs_w = (const float*)d_in[13]; const float* l1_cs_b = (const float*)d_in[14];
    const float* l1_cn_w = (const float*)d_in[15]; const float* l1_cn_b = (const float*)d_in[16];
    const float* l1_gs_w = (const float*)d_in[17]; const float* l1_gs_b = (const float*)d_in[18];
    const float* l1_gn_w = (const float*)d_in[19]; const float* l1_gn_b = (const float*)d_in[20];
    const float* cl_w = (const float*)d_in[21]; const float* cl_b = (const float*)d_in[22];
    const float* gl_w = (const float*)d_in[23]; const float* gl_b = (const float*)d_in[24];
    const float* cd_w = (const float*)d_in[25]; const float* cd_b = (const float*)d_in[26];
    const float* gd_w = (const float*)d_in[27]; const float* gd_b = (const float*)d_in[28];
    const float* centers = (const float*)d_in[29];

    float* out = (float*)d_out;
    float* z_cells    = out;
    float* z_genes    = out + 640000;
    float* cell_recon = out + 896000;
    float* gene_recon = out + 40896000;
    float* q          = out + 80896000;

    // ---- workspace arena ----
    char* wsp = (char*)d_ws;
    auto alloc = [&](size_t bytes) -> void* {
        void* p = (void*)wsp;
        wsp += (bytes + 255) & ~(size_t)255;
        return p;
    };
    unsigned short* pre_c_bf = (unsigned short*)alloc((size_t)N_CELLS * 512 * 2);
    unsigned short* pre_g_bf = (unsigned short*)alloc((size_t)N_GENES * 512 * 2);
    unsigned short* c1_bf    = (unsigned short*)alloc((size_t)N_CELLS * 256 * 2);
    unsigned short* g1_bf    = (unsigned short*)alloc((size_t)N_GENES * 256 * 2);
    unsigned short* c2_bf    = (unsigned short*)alloc((size_t)N_CELLS * 256 * 2);
    unsigned short* g2_bf    = (unsigned short*)alloc((size_t)N_GENES * 256 * 2);
    unsigned short* zc_bf    = (unsigned short*)alloc((size_t)N_CELLS * 64 * 2);
    unsigned short* zg_bf    = (unsigned short*)alloc((size_t)N_GENES * 64 * 2);
    unsigned short* cellx_bf = (unsigned short*)alloc((size_t)N_CELLS * CELL_FP * 2);
    unsigned short* genex_bf = (unsigned short*)alloc((size_t)N_GENES * GENE_FP * 2);
    unsigned short* W0cT = (unsigned short*)alloc((size_t)512 * CELL_FP * 2);
    unsigned short* W0gT = (unsigned short*)alloc((size_t)512 * GENE_FP * 2);
    unsigned short* W1cT = (unsigned short*)alloc((size_t)512 * HID * 2);
    unsigned short* W1gT = (unsigned short*)alloc((size_t)512 * HID * 2);
    unsigned short* WzcT = (unsigned short*)alloc((size_t)64 * HID * 2);
    unsigned short* WzgT = (unsigned short*)alloc((size_t)64 * HID * 2);
    unsigned short* WdcT = (unsigned short*)alloc((size_t)4032 * 64 * 2);
    unsigned short* WdgT = (unsigned short*)alloc((size_t)10048 * 64 * 2);
    int* cnt_c = (int*)alloc((size_t)(N_CELLS + N_GENES) * 4);
    int* cnt_g = cnt_c + N_CELLS;
    int* ptr_c = (int*)alloc((size_t)(N_CELLS + 1) * 4);
    int* ptr_g = (int*)alloc((size_t)(N_GENES + 1) * 4);
    int* cur_c = (int*)alloc((size_t)N_CELLS * 4);
    int* cur_g = (int*)alloc((size_t)N_GENES * 4);
    int*   ci = (int*)alloc((size_t)N_EDGES * 4);
    float* cv = (float*)alloc((size_t)N_EDGES * 4);
    int*   gi = (int*)alloc((size_t)N_EDGES * 4);
    float* gv = (float*)alloc((size_t)N_EDGES * 4);

    // ---- D1: zero counters ----
    hipMemsetAsync(cnt_c, 0, (size_t)(N_CELLS + N_GENES) * 4, stream);

    // ---- D2: count + input cvt + weight packs (fused) ----
    {
        PackArgs pa;
        auto set = [&](int i, const float* W1, const float* W2, unsigned short* BT,
                       int Kr, int Kp, int N1, int N2, int Np, int blk0) -> int {
            int xb = Kp / 32, yb = Np / 32;
            pa.d[i] = {W1, W2, BT, Kr, Kp, N1, N2, Np, xb, blk0};
            return blk0 + xb * yb;
        };
        int nb = PACK_BLK0;
        nb = set(0, l0_cs_w, l0_gn_w, W0cT, CELL_F, CELL_FP, HID, HID, 512, nb);
        nb = set(1, l0_gs_w, l0_cn_w, W0gT, GENE_F, GENE_FP, HID, HID, 512, nb);
        nb = set(2, l1_cs_w, l1_gn_w, W1cT, HID, HID, HID, HID, 512, nb);
        nb = set(3, l1_gs_w, l1_cn_w, W1gT, HID, HID, HID, HID, 512, nb);
        nb = set(4, cl_w, nullptr, WzcT, HID, HID, LAT, 0, 64, nb);
        nb = set(5, gl_w, nullptr, WzgT, HID, HID, LAT, 0, 64, nb);
        nb = set(6, cd_w, nullptr, WdcT, LAT, LAT, N_GENES, 0, 4032, nb);
        nb = set(7, gd_w, nullptr, WdgT, LAT, LAT, N_CELLS, 0, 10048, nb);
        prep_kernel<<<nb, 256, 0, stream>>>(er, ec, cnt_c, cnt_g,
                                            cell_x, cellx_bf, gene_x, genex_bf, pa);
    }

    // ---- D3: scan (seeds cur = ptr) ----
    scan2_kernel<<<2, 1024, 0, stream>>>(cnt_c, ptr_c, cur_c, cnt_g, ptr_g, cur_g);

    auto mkdesc = [](const unsigned short* A, const unsigned short* BT, const float* bias,
                     float* C, unsigned short* Cbf, int M, int N, int K, int TMv,
                     int blk0) -> GemmDesc {
        int gx = (N + 63) / 64, gy = (M + TMv - 1) / TMv;
        return {A, BT, bias, C, Cbf, M, N, K, gx, gx * gy, blk0};
    };
    ScatArgs sa0 = {er, ec, ev, cur_c, cur_g, ci, cv, gi, gv};
    ScatArgs saN = {};

    // ---- D4: scatter + layer-0 projections (TM=128) ----
    {
        GemmArgs2 ga;
        ga.d[0] = mkdesc(cellx_bf, W0cT, nullptr, nullptr, pre_c_bf, N_CELLS, 512, CELL_FP, 128, CNT_BLK);
        ga.d[1] = mkdesc(genex_bf, W0gT, nullptr, nullptr, pre_g_bf, N_GENES, 512, GENE_FP, 128,
                         CNT_BLK + ga.d[0].nwg);
        gemm_multi<128, false, false, true, false, false, true>
            <<<ga.d[1].blk0 + ga.d[1].nwg, 256, 0, stream>>>(
            ga, CNT_BLK, 1 << 30, nullptr, nullptr, nullptr, sa0);
    }

    // ---- D5: layer-0 aggregation ----
    {
        AggArgs aa;
        aa.s[0] = {ptr_c, ci, cv, pre_g_bf, pre_c_bf, l0_cs_b, l0_cn_b, c1_bf};
        aa.s[1] = {ptr_g, gi, gv, pre_c_bf, pre_g_bf, l0_gs_b, l0_gn_b, g1_bf};
        agg2_kernel<<<N_CELLS + N_GENES, 256, 0, stream>>>(aa);
    }

    // ---- D6: layer-1 projections (TM=128) ----
    {
        GemmArgs2 ga;
        ga.d[0] = mkdesc(c1_bf, W1cT, nullptr, nullptr, pre_c_bf, N_CELLS, 512, HID, 128, 0);
        ga.d[1] = mkdesc(g1_bf, W1gT, nullptr, nullptr, pre_g_bf, N_GENES, 512, HID, 128,
                         ga.d[0].nwg);
        gemm_multi<128, false, false, true, false, false, false>
            <<<ga.d[1].blk0 + ga.d[1].nwg, 256, 0, stream>>>(
            ga, 0, 1 << 30, nullptr, nullptr, nullptr, saN);
    }

    // ---- D7: layer-1 aggregation ----
    {
        AggArgs aa;
        aa.s[0] = {ptr_c, ci, cv, pre_g_bf, pre_c_bf, l1_cs_b, l1_cn_b, c2_bf};
        aa.s[1] = {ptr_g, gi, gv, pre_c_bf, pre_g_bf, l1_gs_b, l1_gn_b, g2_bf};
        agg2_kernel<<<N_CELLS + N_GENES, 256, 0, stream>>>(aa);
    }

    // ---- D8: latent heads (TM=64) ----
    {
        GemmArgs2 ga;
        ga.d[0] = mkdesc(c2_bf, WzcT, cl_b, z_cells, zc_bf, N_CELLS, LAT, HID, 64, 0);
        ga.d[1] = mkdesc(g2_bf, WzgT, gl_b, z_genes, zg_bf, N_GENES, LAT, HID, 64, ga.d[0].nwg);
        gemm_multi<64, true, true, true, false, false, false>
            <<<ga.d[1].blk0 + ga.d[1].nwg, 256, 0, stream>>>(
            ga, 0, 1 << 30, nullptr, nullptr, nullptr, saN);
    }

    // ---- D9: decoders (TM=64, transpose epilogue) + q tail ----
    {
        GemmArgs2 ga;
        ga.d[0] = mkdesc(zc_bf, WdcT, cd_b, cell_recon, nullptr, N_CELLS, N_GENES, LAT, 64, 0);
        ga.d[1] = mkdesc(zg_bf, WdgT, gd_b, gene_recon, nullptr, N_GENES, N_CELLS, LAT, 64,
                         ga.d[0].nwg);
        int qstart = ga.d[1].blk0 + ga.d[1].nwg;
        int qblocks = (N_CELLS + 255) / 256;
        gemm_multi<64, true, true, false, true, true, false>
            <<<qstart + qblocks, 256, 0, stream>>>(
            ga, 0, qstart, z_cells, centers, q, saN);
    }
}

// Round 11
// 436.372 us; speedup vs baseline: 1.6830x; 1.1003x over previous
//
#include <hip/hip_runtime.h>

#define N_CELLS 10000
#define N_GENES 4000
#define CELL_F  2000
#define CELL_FX 2112   /* 2048 padded self + 64 raw-neigh columns */
#define GENE_F  50
#define GENE_FP 64
#define HID     256
#define LAT     64
#define NCLUST  20
#define N_EDGES 640000

typedef __attribute__((ext_vector_type(8))) short    bf16x8;
typedef __attribute__((ext_vector_type(8))) unsigned short u16x8;
typedef __attribute__((ext_vector_type(4))) float    f32x4;

__device__ __forceinline__ unsigned short f2bf(float f) {
    unsigned int u = __float_as_uint(f);
    unsigned int r = (u + 0x7FFFu + ((u >> 16) & 1u)) >> 16;
    return (unsigned short)r;
}
__device__ __forceinline__ float bf2f(unsigned short h) {
    return __uint_as_float(((unsigned int)h) << 16);
}

#define GLOAD_LDS16(gp, lp) __builtin_amdgcn_global_load_lds( \
    (const __attribute__((address_space(1))) void*)(gp), \
    (__attribute__((address_space(3))) void*)(lp), 16, 0, 0)

// ================= multi-GEMM (descriptor-dispatched, templated tile) =================
// C(M,N) = A(M,K)@BT(N,K)^T [+bias]. K = padded stride, multiple of 64.
// Tile TM x 64, BK=64, 4 waves. global_load_lds staging (linear LDS dest) with
// XOR chunk swizzle (involution on both sides).
struct GemmDesc {
    const unsigned short *A, *BT;
    const float *bias;
    float *C;
    unsigned short *Cbf;
    int M, N, K;
    int gx, nwg, blk0;
    const float *bias2;        // RSPLIT: second bias
    unsigned short *Cbf2;      // RSPLIT: dest for cols 256:512
};
struct GemmArgs2 { GemmDesc d[2]; };
struct ScatArgs {
    const int *er, *ec; const float *ev;
    int *cur_c, *cur_g;
    int *ci; float *cv; int *gi; float *gv;
};

template<int TM, bool BIAS, bool WF32, bool WBF, bool TEPI, bool QTAIL, bool SCAT, bool RSPLIT>
__global__ __launch_bounds__(256)
void gemm_multi(GemmArgs2 ga, int gemm0, int qstart,
                const float* __restrict__ zq, const float* __restrict__ cent,
                float* __restrict__ qout, ScatArgs sa)
{
    constexpr int SMEM = (TM * 128 + 8192) > 16640 ? (TM * 128 + 8192) : 16640;
    __shared__ __align__(16) unsigned char smem[SMEM];
    unsigned short* As = (unsigned short*)smem;
    unsigned short* Bs = As + TM * 64;

    // ---------- scatter head (CSR edge scatter) ----------
    if (SCAT && (int)blockIdx.x < gemm0) {
        int e = blockIdx.x * 256 + threadIdx.x;
        int r = sa.er[e], c = sa.ec[e];
        float v = sa.ev[e];
        int pc = atomicAdd(&sa.cur_c[r], 1);
        sa.ci[pc] = c; sa.cv[pc] = v;
        int pg = atomicAdd(&sa.cur_g[c], 1);
        sa.gi[pg] = r; sa.gv[pg] = v;
        return;
    }

    // ---------- q tail (DEC soft assignment) ----------
    if (QTAIL && (int)blockIdx.x >= qstart) {
        float* cs = (float*)smem;
        int tid = threadIdx.x;
        for (int l = tid; l < NCLUST * LAT; l += 256) cs[l] = cent[l];
        __syncthreads();
        int c = (blockIdx.x - qstart) * 256 + tid;
        if (c >= N_CELLS) return;
        float zr[LAT];
        #pragma unroll
        for (int k = 0; k < LAT; ++k) zr[k] = zq[(size_t)c * LAT + k];
        float num[NCLUST];
        float denom = 0.0f;
        for (int j = 0; j < NCLUST; ++j) {
            float d = 0.0f;
            #pragma unroll
            for (int k = 0; k < LAT; ++k) {
                float t = zr[k] - cs[j * LAT + k];
                d += t * t;
            }
            float n = 1.0f / (1.0f + d);
            num[j] = n;
            denom += n;
        }
        float inv = 1.0f / denom;
        for (int j = 0; j < NCLUST; ++j) qout[(size_t)c * NCLUST + j] = num[j] * inv;
        return;
    }

    // ---------- descriptor pick + XCD-bijective swizzle (m204) ----------
    int b = blockIdx.x;
    int p = (b >= ga.d[1].blk0) ? 1 : 0;
    const GemmDesc d = ga.d[p];
    int lin = b - d.blk0;
    int q8 = d.nwg >> 3, r8 = d.nwg & 7;
    int xcd = lin & 7, idx = lin >> 3;
    int wgid = (xcd < r8 ? xcd * (q8 + 1) : r8 * (q8 + 1) + (xcd - r8) * q8) + idx;
    int by = wgid / d.gx;
    int bx = wgid - by * d.gx;

    const int tid  = threadIdx.x;
    const int lane = tid & 63;
    const int w    = tid >> 6;
    const int cn   = lane & 15;
    const int rj   = lane >> 4;
    const int row0 = by * TM;
    const int col0 = bx * 64;

    constexpr int AI = TM / 32;
    constexpr int MF = TM / 64;

    size_t arow[AI];
    unsigned short* ldsA[AI];
    #pragma unroll
    for (int j = 0; j < AI; ++j) {
        int slot = (w * AI + j) * 64 + lane;
        int rs = slot >> 3, ss = slot & 7, cs = ss ^ (rs & 7);
        arow[j] = (size_t)min(row0 + rs, d.M - 1) * d.K + cs * 8;
        ldsA[j] = As + (w * AI + j) * 512;
    }
    const int sb0 = (w * 2) * 64 + lane;
    const int sb1 = sb0 + 64;
    const int rb0 = sb0 >> 3, cb0 = (sb0 & 7) ^ (rb0 & 7);
    const int rb1 = sb1 >> 3, cb1 = (sb1 & 7) ^ (rb1 & 7);
    const size_t brow0 = (size_t)(col0 + rb0) * d.K + cb0 * 8;
    const size_t brow1 = (size_t)(col0 + rb1) * d.K + cb1 * 8;
    unsigned short* ldsB = Bs + (w * 2) * 512;

    int aoff0[MF], aoff1[MF];
    #pragma unroll
    for (int mf = 0; mf < MF; ++mf) {
        int rA = w * (TM / 4) + mf * 16 + cn, swA = rA & 7, abase = rA * 64;
        aoff0[mf] = abase + ((rj)     ^ swA) * 8;
        aoff1[mf] = abase + ((rj + 4) ^ swA) * 8;
    }

    f32x4 acc[MF][4] = {};

    for (int kt = 0; kt < d.K; kt += 64) {
        #pragma unroll
        for (int j = 0; j < AI; ++j) GLOAD_LDS16(d.A + arow[j] + kt, ldsA[j]);
        GLOAD_LDS16(d.BT + brow0 + kt, ldsB);
        GLOAD_LDS16(d.BT + brow1 + kt, ldsB + 512);
        __syncthreads();
        bf16x8 a0[MF], a1[MF];
        #pragma unroll
        for (int mf = 0; mf < MF; ++mf) {
            a0[mf] = *(const bf16x8*)&As[aoff0[mf]];
            a1[mf] = *(const bf16x8*)&As[aoff1[mf]];
        }
        #pragma unroll
        for (int f = 0; f < 4; ++f) {
            int rB = f * 16 + cn, swB = rB & 7, bb = rB * 64;
            bf16x8 b0 = *(const bf16x8*)&Bs[bb + ((rj)     ^ swB) * 8];
            bf16x8 b1 = *(const bf16x8*)&Bs[bb + ((rj + 4) ^ swB) * 8];
            #pragma unroll
            for (int mf = 0; mf < MF; ++mf) {
                acc[mf][f] = __builtin_amdgcn_mfma_f32_16x16x32_bf16(a0[mf], b0, acc[mf][f], 0, 0, 0);
                acc[mf][f] = __builtin_amdgcn_mfma_f32_16x16x32_bf16(a1[mf], b1, acc[mf][f], 0, 0, 0);
            }
        }
        __syncthreads();
    }

    if (TEPI) {
        // ---- LDS-transpose epilogue (TM=64): 256B-contiguous f32 writes ----
        float* Cs = (float*)smem;     // [64][65]
        __syncthreads();
        #pragma unroll
        for (int f = 0; f < 4; ++f)
            #pragma unroll
            for (int j = 0; j < 4; ++j)
                Cs[(w * 16 + rj * 4 + j) * 65 + f * 16 + cn] = acc[0][f][j];
        __syncthreads();
        #pragma unroll
        for (int i = 0; i < 4; ++i) {
            int slot = tid + i * 256;
            int rr = slot >> 4, c4 = (slot & 15) * 4;
            int gr = row0 + rr, gc = col0 + c4;
            if (gr < d.M && gc < d.N) {
                const float* cp = &Cs[rr * 65 + c4];
                float4 bv = BIAS ? *(const float4*)&d.bias[gc] : float4{0, 0, 0, 0};
                float4 v;
                v.x = cp[0] + bv.x; v.y = cp[1] + bv.y;
                v.z = cp[2] + bv.z; v.w = cp[3] + bv.w;
                *(float4*)&d.C[(size_t)gr * d.N + gc] = v;
            }
        }
    } else if (RSPLIT) {
        // ---- split epilogue (L0 cell, N=512): cols<256 -> relu(acc+b1+b2) -> Cbf;
        //      cols>=256 -> raw bf16 -> Cbf2 (gn-projection for gene gathers) ----
        #pragma unroll
        for (int mf = 0; mf < MF; ++mf) {
            #pragma unroll
            for (int f = 0; f < 4; ++f) {
                int col = col0 + f * 16 + cn;
                #pragma unroll
                for (int j = 0; j < 4; ++j) {
                    int r = row0 + w * (TM / 4) + mf * 16 + rj * 4 + j;
                    if (r < d.M) {
                        float val = acc[mf][f][j];
                        if (col < 256) {
                            val += d.bias[col] + d.bias2[col];
                            d.Cbf[(size_t)r * 256 + col] = f2bf(fmaxf(val, 0.0f));
                        } else {
                            d.Cbf2[(size_t)r * 256 + (col - 256)] = f2bf(val);
                        }
                    }
                }
            }
        }
    } else {
        // ---- direct epilogue [m89] ----
        #pragma unroll
        for (int mf = 0; mf < MF; ++mf) {
            #pragma unroll
            for (int f = 0; f < 4; ++f) {
                int col = col0 + f * 16 + cn;
                if (col >= d.N) continue;
                float bv = BIAS ? d.bias[col] : 0.0f;
                #pragma unroll
                for (int j = 0; j < 4; ++j) {
                    int r = row0 + w * (TM / 4) + mf * 16 + rj * 4 + j;
                    if (r < d.M) {
                        float val = acc[mf][f][j] + bv;
                        if (WF32) d.C[(size_t)r * d.N + col] = val;
                        if (WBF)  d.Cbf[(size_t)r * d.N + col] = f2bf(val);
                    }
                }
            }
        }
    }
}

// ================= raw neighbor gather (L0 cell side) =================
// cellx[r, 2048:2112] = sum_e ev * genex_bf[nbr[e]]  (64 bf16 dims, L2-resident table)
// 4 waves/block, wave per row; 16 edges/batch via lane0-15 load + shfl;
// 16-lane groups gather one full 128B gene row each (4 edges in flight/instr).
__global__ __launch_bounds__(256)
void rawgather_kernel(const int* __restrict__ ptr, const int* __restrict__ nbr,
                      const float* __restrict__ val,
                      const unsigned short* __restrict__ gx,   // genex_bf 4000x64
                      unsigned short* __restrict__ cellx)      // stride CELL_FX
{
    int w = threadIdx.x >> 6, lane = threadIdx.x & 63;
    int r = blockIdx.x * 4 + w;
    int s = ptr[r], e = ptr[r + 1];
    int g = lane >> 4, sub = lane & 15;
    const ushort4* gx4 = (const ushort4*)gx;      // 16 ushort4 per gene row
    float4 acc = {0.0f, 0.0f, 0.0f, 0.0f};
    for (int base = s; base < e; base += 16) {
        int nb = 0; float vb = 0.0f;
        if (lane < 16 && base + lane < e) { nb = nbr[base + lane]; vb = val[base + lane]; }
        #pragma unroll
        for (int jj = 0; jj < 4; ++jj) {
            int ei = jj * 4 + g;
            int j  = __shfl(nb, ei);
            float v = __shfl(vb, ei);
            ushort4 a = gx4[(size_t)j * 16 + sub];
            acc.x += v * bf2f(a.x);
            acc.y += v * bf2f(a.y);
            acc.z += v * bf2f(a.z);
            acc.w += v * bf2f(a.w);
        }
    }
    // reduce across the 4 edge-classes (high 2 lane bits)
    acc.x += __shfl_xor(acc.x, 16); acc.x += __shfl_xor(acc.x, 32);
    acc.y += __shfl_xor(acc.y, 16); acc.y += __shfl_xor(acc.y, 32);
    acc.z += __shfl_xor(acc.z, 16); acc.z += __shfl_xor(acc.z, 32);
    acc.w += __shfl_xor(acc.w, 16); acc.w += __shfl_xor(acc.w, 32);
    if (lane < 16) {
        ushort4 o;
        o.x = f2bf(acc.x); o.y = f2bf(acc.y); o.z = f2bf(acc.z); o.w = f2bf(acc.w);
        ((ushort4*)(cellx + (size_t)r * CELL_FX + 2048))[sub] = o;
    }
}

// ================= prep: count + input-cvt + weight packs =================
struct PackDesc {
    const float* W1; const float* W2; const float* W3; unsigned short* BT;
    int Kr, Kp, N1, N2, Np, xb, blk0;
};
struct PackArgs { PackDesc d[8]; };

#define CNT_BLK   2500
#define CVTC_BLK  10000
#define CVTG_BLK  125
#define PACK_BLK0 (CNT_BLK + CVTC_BLK + CVTG_BLK)

__global__ __launch_bounds__(256)
void prep_kernel(const int* __restrict__ er, const int* __restrict__ ec,
                 int* __restrict__ cnt_c, int* __restrict__ cnt_g,
                 const float* __restrict__ cell_x, unsigned short* __restrict__ cellx_bf,
                 const float* __restrict__ gene_x, unsigned short* __restrict__ genex_bf,
                 PackArgs pa)
{
    __shared__ float tile[32][33];
    int b = blockIdx.x;
    int tid = threadIdx.x;
    if (b < CNT_BLK) {
        int e = b * 256 + tid;
        atomicAdd(&cnt_c[er[e]], 1);
        atomicAdd(&cnt_g[ec[e]], 1);
        return;
    }
    if (b < CNT_BLK + CVTC_BLK) {
        int row = b - CNT_BLK;
        int col = tid * 8;                 // cols 0:2048 (neigh cols from rawgather)
        u16x8 v = {0, 0, 0, 0, 0, 0, 0, 0};
        if (col < CELL_F) {
            const float* src = cell_x + (size_t)row * CELL_F + col;
            float4 f0 = *(const float4*)src;
            float4 f1 = *(const float4*)(src + 4);
            v[0] = f2bf(f0.x); v[1] = f2bf(f0.y); v[2] = f2bf(f0.z); v[3] = f2bf(f0.w);
            v[4] = f2bf(f1.x); v[5] = f2bf(f1.y); v[6] = f2bf(f1.z); v[7] = f2bf(f1.w);
        }
        ((u16x8*)(cellx_bf + (size_t)row * CELL_FX))[tid] = v;
        return;
    }
    if (b < PACK_BLK0) {
        int idx = (b - CNT_BLK - CVTC_BLK) * 256 + tid;
        int row = idx >> 3, c8 = idx & 7;
        int col = c8 * 8;
        u16x8 v = {0, 0, 0, 0, 0, 0, 0, 0};
        #pragma unroll
        for (int j = 0; j < 8; ++j)
            if (col + j < GENE_F) v[j] = f2bf(gene_x[(size_t)row * GENE_F + col + j]);
        ((u16x8*)(genex_bf + (size_t)row * GENE_FP))[c8] = v;
        return;
    }
    int pb = b;
    int p = 0;
    #pragma unroll
    for (int i = 1; i < 8; ++i) if (pb >= pa.d[i].blk0) p = i;
    const PackDesc d = pa.d[p];
    int local = pb - d.blk0;
    int kb = local % d.xb, nb = local / d.xb;
    int k0 = kb * 32, n0 = nb * 32;
    int tx = tid & 31, ty = tid >> 5;
    #pragma unroll
    for (int yy = 0; yy < 4; ++yy) {
        int k = k0 + ty + yy * 8;
        int n = n0 + tx;
        float v = 0.0f;
        if (k < d.Kr) {
            if (n < d.N1) v = d.W1[(size_t)k * d.N1 + n];
            else if (n < d.N1 + d.N2) v = d.W2[(size_t)k * d.N2 + (n - d.N1)];
        } else if (d.W3 && k >= 2048) {
            int kk = k - 2048;                       // cn_w zone: K rows 2048:2112
            if (kk < GENE_F && n < HID) v = d.W3[(size_t)kk * HID + n];
        }
        tile[ty + yy * 8][tx] = v;
    }
    __syncthreads();
    #pragma unroll
    for (int yy = 0; yy < 4; ++yy) {
        int n = n0 + ty + yy * 8;
        int k = k0 + tx;
        if (n < d.Np)
            d.BT[(size_t)n * d.Kp + k] = f2bf(tile[tx][ty + yy * 8]);
    }
}

// ================= CSR scan =================
__global__ __launch_bounds__(1024)
void scan2_kernel(const int* __restrict__ cnt_c, int* __restrict__ ptr_c, int* __restrict__ cur_c,
                  const int* __restrict__ cnt_g, int* __restrict__ ptr_g, int* __restrict__ cur_g)
{
    const int* cnt = blockIdx.x ? cnt_g : cnt_c;
    int* ptr = blockIdx.x ? ptr_g : ptr_c;
    int* cur = blockIdx.x ? cur_g : cur_c;
    int  n   = blockIdx.x ? N_GENES : N_CELLS;
    __shared__ int part[1024];
    int t = threadIdx.x;
    int chunk = (n + 1023) / 1024;
    int lo = t * chunk, hi = min(lo + chunk, n);
    int s = 0;
    for (int i = lo; i < hi; ++i) s += cnt[i];
    part[t] = s;
    __syncthreads();
    #pragma unroll
    for (int off = 1; off < 1024; off <<= 1) {
        int v = (t >= off) ? part[t - off] : 0;
        __syncthreads();
        part[t] += v;
        __syncthreads();
    }
    if (t == 1023) ptr[n] = part[1023];
    int run = part[t] - s;
    for (int i = lo; i < hi; ++i) { ptr[i] = run; cur[i] = run; run += cnt[i]; }
}

// ================= agg (shuffle-batched gathers, parameterized layout) =================
struct AggSide {
    const int *ptr, *nbr; const float *val;
    const unsigned short *src, *pre;
    const float *b1, *b2;
    unsigned short *out;
    int srcRow4, srcOff4, preRow;   // src row stride / offset in ushort4; pre row stride
};
struct AggArgs { AggSide s[2]; int nc; };

__global__ __launch_bounds__(256)
void agg2_kernel(AggArgs aa)
{
    __shared__ __align__(16) float red[4][256];
    int b = blockIdx.x;
    int side = (b >= aa.nc) ? 1 : 0;
    const AggSide S = aa.s[side];
    int r = side ? b - aa.nc : b;
    int t = threadIdx.x;
    int w = t >> 6;
    int lane = t & 63;
    int s = S.ptr[r], e = S.ptr[r + 1];
    int n = e - s;
    int chunk = (n + 3) >> 2;
    int ws = s + w * chunk;
    int we = min(ws + chunk, e);
    const ushort4* src4 = (const ushort4*)S.src;
    float4 acc = {0.0f, 0.0f, 0.0f, 0.0f};
    for (int base = ws; base < we; base += 16) {
        int   nb = 0;
        float vb = 0.0f;
        if (lane < 16 && base + lane < we) {
            nb = S.nbr[base + lane];
            vb = S.val[base + lane];
        }
        #pragma unroll
        for (int j = 0; j < 16; ++j) {
            int   jj = __shfl(nb, j);
            float vv = __shfl(vb, j);
            ushort4 a = src4[(size_t)jj * S.srcRow4 + S.srcOff4 + lane];
            acc.x += vv * bf2f(a.x);
            acc.y += vv * bf2f(a.y);
            acc.z += vv * bf2f(a.z);
            acc.w += vv * bf2f(a.w);
        }
    }
    *(float4*)&red[w][lane * 4] = acc;
    __syncthreads();
    float x = red[0][t] + red[1][t] + red[2][t] + red[3][t]
            + bf2f(S.pre[(size_t)r * S.preRow + t]) + S.b1[t] + S.b2[t];
    S.out[(size_t)r * 256 + t] = f2bf(fmaxf(x, 0.0f));
}

extern "C" void kernel_launch(void* const* d_in, const int* in_sizes, int n_in,
                              void* d_out, int out_size, void* d_ws, size_t ws_size,
                              hipStream_t stream)
{
    const float* cell_x  = (const float*)d_in[0];
    const float* gene_x  = (const float*)d_in[1];
    const int*   er      = (const int*)d_in[2];
    const int*   ec      = (const int*)d_in[3];
    const float* ev      = (const float*)d_in[4];
    const float* l0_cs_w = (const float*)d_in[5];  const float* l0_cs_b = (const float*)d_in[6];
    const float* l0_cn_w = (const float*)d_in[7];  const float* l0_cn_b = (const float*)d_in[8];
    const float* l0_gs_w = (const float*)d_in[9];  const float* l0_gs_b = (const float*)d_in[10];
    const float* l0_gn_w = (const float*)d_in[11]; const float* l0_gn_b = (const float*)d_in[12];
    const float* l1_cs_w = (const float*)d_in[13]; const float* l1_cs_b = (const float*)d_in[14];
    const float* l1_cn_w = (const float*)d_in[15]; const float* l1_cn_b = (const float*)d_in[16];
    const float* l1_gs_w = (const float*)d_in[17]; const float* l1_gs_b = (const float*)d_in[18];
    const float* l1_gn_w = (const float*)d_in[19]; const float* l1_gn_b = (const float*)d_in[20];
    const float* cl_w = (const float*)d_in[21]; const float* cl_b = (const float*)d_in[22];
    const float* gl_w = (const float*)d_in[23]; const float* gl_b = (const float*)d_in[24];
    const float* cd_w = (const float*)d_in[25]; const float* cd_b = (const float*)d_in[26];
    const float* gd_w = (const float*)d_in[27]; const float* gd_b = (const float*)d_in[28];
    const float* centers = (const float*)d_in[29];

    float* out = (float*)d_out;
    float* z_cells    = out;
    float* z_genes    = out + 640000;
    float* cell_recon = out + 896000;
    float* gene_recon = out + 40896000;
    float* q          = out + 80896000;

    // ---- workspace arena ----
    char* wsp = (char*)d_ws;
    auto alloc = [&](size_t bytes) -> void* {
        void* p = (void*)wsp;
        wsp += (bytes + 255) & ~(size_t)255;
        return p;
    };
    unsigned short* pre_c_bf = (unsigned short*)alloc((size_t)N_CELLS * 512 * 2);  // L1 cell pre
    unsigned short* pre_g_bf = (unsigned short*)alloc((size_t)N_GENES * 512 * 2);  // L1 gene pre
    unsigned short* c1_bf    = (unsigned short*)alloc((size_t)N_CELLS * 256 * 2);
    unsigned short* g1_bf    = (unsigned short*)alloc((size_t)N_GENES * 256 * 2);
    unsigned short* c2_bf    = (unsigned short*)alloc((size_t)N_CELLS * 256 * 2);
    unsigned short* g2_bf    = (unsigned short*)alloc((size_t)N_GENES * 256 * 2);
    unsigned short* zc_bf    = (unsigned short*)alloc((size_t)N_CELLS * 64 * 2);
    unsigned short* zg_bf    = (unsigned short*)alloc((size_t)N_GENES * 64 * 2);
    unsigned short* cellx_bf = (unsigned short*)alloc((size_t)N_CELLS * CELL_FX * 2);
    unsigned short* genex_bf = (unsigned short*)alloc((size_t)N_GENES * GENE_FP * 2);
    unsigned short* W0cT = (unsigned short*)alloc((size_t)512 * CELL_FX * 2);
    unsigned short* W0gT = (unsigned short*)alloc((size_t)256 * GENE_FP * 2);
    unsigned short* W1cT = (unsigned short*)alloc((size_t)512 * HID * 2);
    unsigned short* W1gT = (unsigned short*)alloc((size_t)512 * HID * 2);
    unsigned short* WzcT = (unsigned short*)alloc((size_t)64 * HID * 2);
    unsigned short* WzgT = (unsigned short*)alloc((size_t)64 * HID * 2);
    unsigned short* WdcT = (unsigned short*)alloc((size_t)4032 * 64 * 2);
    unsigned short* WdgT = (unsigned short*)alloc((size_t)10048 * 64 * 2);
    int* cnt_c = (int*)alloc((size_t)(N_CELLS + N_GENES) * 4);
    int* cnt_g = cnt_c + N_CELLS;
    int* ptr_c = (int*)alloc((size_t)(N_CELLS + 1) * 4);
    int* ptr_g = (int*)alloc((size_t)(N_GENES + 1) * 4);
    int* cur_c = (int*)alloc((size_t)N_CELLS * 4);
    int* cur_g = (int*)alloc((size_t)N_GENES * 4);
    int*   ci = (int*)alloc((size_t)N_EDGES * 4);
    float* cv = (float*)alloc((size_t)N_EDGES * 4);
    int*   gi = (int*)alloc((size_t)N_EDGES * 4);
    float* gv = (float*)alloc((size_t)N_EDGES * 4);
    // lifetime-disjoint overlays (L0-phase buffers reuse L1-phase outputs):
    unsigned short* pre_cgn_bf = c2_bf;   // L0: cell gn-projection (written D6, read D7)
    unsigned short* pre_gs_bf  = g2_bf;   // L0: gene self-pre (written D4, read D7)

    // ---- D1: zero counters ----
    hipMemsetAsync(cnt_c, 0, (size_t)(N_CELLS + N_GENES) * 4, stream);

    // ---- D2: count + input cvt + weight packs ----
    {
        PackArgs pa;
        auto set = [&](int i, const float* W1, const float* W2, const float* W3,
                       unsigned short* BT, int Kr, int Kp, int N1, int N2, int Np,
                       int blk0) -> int {
            int xb = Kp / 32, yb = Np / 32;
            pa.d[i] = {W1, W2, W3, BT, Kr, Kp, N1, N2, Np, xb, blk0};
            return blk0 + xb * yb;
        };
        int nb = PACK_BLK0;
        nb = set(0, l0_cs_w, l0_gn_w, l0_cn_w, W0cT, CELL_F, CELL_FX, HID, HID, 512, nb);
        nb = set(1, l0_gs_w, nullptr, nullptr, W0gT, GENE_F, GENE_FP, HID, 0, 256, nb);
        nb = set(2, l1_cs_w, l1_gn_w, nullptr, W1cT, HID, HID, HID, HID, 512, nb);
        nb = set(3, l1_gs_w, l1_cn_w, nullptr, W1gT, HID, HID, HID, HID, 512, nb);
        nb = set(4, cl_w, nullptr, nullptr, WzcT, HID, HID, LAT, 0, 64, nb);
        nb = set(5, gl_w, nullptr, nullptr, WzgT, HID, HID, LAT, 0, 64, nb);
        nb = set(6, cd_w, nullptr, nullptr, WdcT, LAT, LAT, N_GENES, 0, 4032, nb);
        nb = set(7, gd_w, nullptr, nullptr, WdgT, LAT, LAT, N_CELLS, 0, 10048, nb);
        prep_kernel<<<nb, 256, 0, stream>>>(er, ec, cnt_c, cnt_g,
                                            cell_x, cellx_bf, gene_x, genex_bf, pa);
    }

    // ---- D3: scan (seeds cur = ptr) ----
    scan2_kernel<<<2, 1024, 0, stream>>>(cnt_c, ptr_c, cur_c, cnt_g, ptr_g, cur_g);

    auto mkdesc = [](const unsigned short* A, const unsigned short* BT, const float* bias,
                     float* C, unsigned short* Cbf, int M, int N, int K, int TMv,
                     int blk0) -> GemmDesc {
        int gx = (N + 63) / 64, gy = (M + TMv - 1) / TMv;
        return {A, BT, bias, C, Cbf, M, N, K, gx, gx * gy, blk0, nullptr, nullptr};
    };
    ScatArgs sa0 = {er, ec, ev, cur_c, cur_g, ci, cv, gi, gv};
    ScatArgs saN = {};

    // ---- D4: scatter + gene L0 GEMM (N=256 self-projection only) ----
    {
        GemmArgs2 ga;
        ga.d[0] = mkdesc(genex_bf, W0gT, nullptr, nullptr, pre_gs_bf, N_GENES, 256, GENE_FP, 128, CNT_BLK);
        ga.d[1] = ga.d[0]; ga.d[1].blk0 = 1 << 30;
        gemm_multi<128, false, false, true, false, false, true, false>
            <<<CNT_BLK + ga.d[0].nwg, 256, 0, stream>>>(
            ga, CNT_BLK, 1 << 30, nullptr, nullptr, nullptr, sa0);
    }

    // ---- D5: raw gene-feature gather into cellx_bf[:, 2048:2112] ----
    rawgather_kernel<<<N_CELLS / 4, 256, 0, stream>>>(ptr_c, ci, cv, genex_bf, cellx_bf);

    // ---- D6: cell L0 GEMM (K=2112 incl. neigh; split epilogue -> c1 + gn-proj) ----
    {
        GemmArgs2 ga;
        ga.d[0] = mkdesc(cellx_bf, W0cT, l0_cs_b, nullptr, c1_bf, N_CELLS, 512, CELL_FX, 128, 0);
        ga.d[0].bias2 = l0_cn_b;
        ga.d[0].Cbf2  = pre_cgn_bf;
        ga.d[1] = ga.d[0]; ga.d[1].blk0 = 1 << 30;
        gemm_multi<128, false, false, false, false, false, false, true>
            <<<ga.d[0].nwg, 256, 0, stream>>>(
            ga, 0, 1 << 30, nullptr, nullptr, nullptr, saN);
    }

    // ---- D7: L0 aggregation (gene side only) ----
    {
        AggArgs aa;
        aa.nc = 0;
        aa.s[1] = {ptr_g, gi, gv, pre_cgn_bf, pre_gs_bf, l0_gs_b, l0_gn_b, g1_bf, 64, 0, 256};
        aa.s[0] = aa.s[1];
        agg2_kernel<<<N_GENES, 256, 0, stream>>>(aa);
    }

    // ---- D8: L1 projections (both) ----
    {
        GemmArgs2 ga;
        ga.d[0] = mkdesc(c1_bf, W1cT, nullptr, nullptr, pre_c_bf, N_CELLS, 512, HID, 128, 0);
        ga.d[1] = mkdesc(g1_bf, W1gT, nullptr, nullptr, pre_g_bf, N_GENES, 512, HID, 128,
                         ga.d[0].nwg);
        gemm_multi<128, false, false, true, false, false, false, false>
            <<<ga.d[1].blk0 + ga.d[1].nwg, 256, 0, stream>>>(
            ga, 0, 1 << 30, nullptr, nullptr, nullptr, saN);
    }

    // ---- D9: L1 aggregation (both sides) ----
    {
        AggArgs aa;
        aa.nc = N_CELLS;
        aa.s[0] = {ptr_c, ci, cv, pre_g_bf, pre_c_bf, l1_cs_b, l1_cn_b, c2_bf, 128, 64, 512};
        aa.s[1] = {ptr_g, gi, gv, pre_c_bf, pre_g_bf, l1_gs_b, l1_gn_b, g2_bf, 128, 64, 512};
        agg2_kernel<<<N_CELLS + N_GENES, 256, 0, stream>>>(aa);
    }

    // ---- D10: latent heads (TM=64) ----
    {
        GemmArgs2 ga;
        ga.d[0] = mkdesc(c2_bf, WzcT, cl_b, z_cells, zc_bf, N_CELLS, LAT, HID, 64, 0);
        ga.d[1] = mkdesc(g2_bf, WzgT, gl_b, z_genes, zg_bf, N_GENES, LAT, HID, 64, ga.d[0].nwg);
        gemm_multi<64, true, true, true, false, false, false, false>
            <<<ga.d[1].blk0 + ga.d[1].nwg, 256, 0, stream>>>(
            ga, 0, 1 << 30, nullptr, nullptr, nullptr, saN);
    }

    // ---- D11: decoders (TM=64, transpose epilogue) + q tail ----
    {
        GemmArgs2 ga;
        ga.d[0] = mkdesc(zc_bf, WdcT, cd_b, cell_recon, nullptr, N_CELLS, N_GENES, LAT, 64, 0);
        ga.d[1] = mkdesc(zg_bf, WdgT, gd_b, gene_recon, nullptr, N_GENES, N_CELLS, LAT, 64,
                         ga.d[0].nwg);
        int qstart = ga.d[1].blk0 + ga.d[1].nwg;
        int qblocks = (N_CELLS + 255) / 256;
        gemm_multi<64, true, true, false, true, true, false, false>
            <<<qstart + qblocks, 256, 0, stream>>>(
            ga, 0, qstart, z_cells, centers, q, saN);
    }
}

// Round 12
// 422.996 us; speedup vs baseline: 1.7363x; 1.0316x over previous
//
#include <hip/hip_runtime.h>

#define N_CELLS 10000
#define N_GENES 4000
#define CELL_F  2000
#define CELL_FX 2112   /* 2048 padded self + 64 raw-neigh columns */
#define GENE_F  50
#define GENE_FP 64
#define HID     256
#define LAT     64
#define NCLUST  20
#define N_EDGES 640000

typedef __attribute__((ext_vector_type(8))) short    bf16x8;
typedef __attribute__((ext_vector_type(8))) unsigned short u16x8;
typedef __attribute__((ext_vector_type(4))) float    f32x4;

__device__ __forceinline__ unsigned short f2bf(float f) {
    unsigned int u = __float_as_uint(f);
    unsigned int r = (u + 0x7FFFu + ((u >> 16) & 1u)) >> 16;
    return (unsigned short)r;
}
__device__ __forceinline__ float bf2f(unsigned short h) {
    return __uint_as_float(((unsigned int)h) << 16);
}

#define GLOAD_LDS16(gp, lp) __builtin_amdgcn_global_load_lds( \
    (const __attribute__((address_space(1))) void*)(gp), \
    (__attribute__((address_space(3))) void*)(lp), 16, 0, 0)

// ================= multi-GEMM (descriptor-dispatched, templated tile) =================
// C(M,N) = A(M,K)@BT(N,K)^T [+bias]. K = padded stride, multiple of 64.
// Tile TM x 64, BK=64, 4 waves. global_load_lds staging (linear LDS dest) with
// XOR chunk swizzle (involution on both sides).
struct GemmDesc {
    const unsigned short *A, *BT;
    const float *bias;
    float *C;
    unsigned short *Cbf;
    int M, N, K;
    int gx, nwg, blk0;
    const float *bias2;        // RSPLIT: second bias
    unsigned short *Cbf2;      // RSPLIT: dest for cols 256:512
    int ld1, ld2;              // RSPLIT: strides for Cbf / Cbf2
};
struct GemmArgs2 { GemmDesc d[2]; };
struct ScatArgs {
    const int *er, *ec; const float *ev;
    int *cur_c, *cur_g;
    int *ci; float *cv; int *gi; float *gv;
};

template<int TM, bool BIAS, bool WF32, bool WBF, bool TEPI, bool QTAIL, bool SCAT, bool RSPLIT>
__global__ __launch_bounds__(256)
void gemm_multi(GemmArgs2 ga, int gemm0, int qstart,
                const float* __restrict__ zq, const float* __restrict__ cent,
                float* __restrict__ qout, ScatArgs sa)
{
    constexpr int SMEM = (TM * 128 + 8192) > 16640 ? (TM * 128 + 8192) : 16640;
    __shared__ __align__(16) unsigned char smem[SMEM];
    unsigned short* As = (unsigned short*)smem;
    unsigned short* Bs = As + TM * 64;

    // ---------- scatter head (CSR edge scatter) ----------
    if (SCAT && (int)blockIdx.x < gemm0) {
        int e = blockIdx.x * 256 + threadIdx.x;
        int r = sa.er[e], c = sa.ec[e];
        float v = sa.ev[e];
        int pc = atomicAdd(&sa.cur_c[r], 1);
        sa.ci[pc] = c; sa.cv[pc] = v;
        int pg = atomicAdd(&sa.cur_g[c], 1);
        sa.gi[pg] = r; sa.gv[pg] = v;
        return;
    }

    // ---------- q tail (DEC soft assignment) ----------
    if (QTAIL && (int)blockIdx.x >= qstart) {
        float* cs = (float*)smem;
        int tid = threadIdx.x;
        for (int l = tid; l < NCLUST * LAT; l += 256) cs[l] = cent[l];
        __syncthreads();
        int c = (blockIdx.x - qstart) * 256 + tid;
        if (c >= N_CELLS) return;
        float zr[LAT];
        #pragma unroll
        for (int k = 0; k < LAT; ++k) zr[k] = zq[(size_t)c * LAT + k];
        float num[NCLUST];
        float denom = 0.0f;
        for (int j = 0; j < NCLUST; ++j) {
            float d = 0.0f;
            #pragma unroll
            for (int k = 0; k < LAT; ++k) {
                float t = zr[k] - cs[j * LAT + k];
                d += t * t;
            }
            float n = 1.0f / (1.0f + d);
            num[j] = n;
            denom += n;
        }
        float inv = 1.0f / denom;
        for (int j = 0; j < NCLUST; ++j) qout[(size_t)c * NCLUST + j] = num[j] * inv;
        return;
    }

    // ---------- descriptor pick + XCD-bijective swizzle (m204) ----------
    int b = blockIdx.x;
    int p = (b >= ga.d[1].blk0) ? 1 : 0;
    const GemmDesc d = ga.d[p];
    int lin = b - d.blk0;
    int q8 = d.nwg >> 3, r8 = d.nwg & 7;
    int xcd = lin & 7, idx = lin >> 3;
    int wgid = (xcd < r8 ? xcd * (q8 + 1) : r8 * (q8 + 1) + (xcd - r8) * q8) + idx;
    int by = wgid / d.gx;
    int bx = wgid - by * d.gx;

    const int tid  = threadIdx.x;
    const int lane = tid & 63;
    const int w    = tid >> 6;
    const int cn   = lane & 15;
    const int rj   = lane >> 4;
    const int row0 = by * TM;
    const int col0 = bx * 64;

    constexpr int AI = TM / 32;
    constexpr int MF = TM / 64;

    size_t arow[AI];
    unsigned short* ldsA[AI];
    #pragma unroll
    for (int j = 0; j < AI; ++j) {
        int slot = (w * AI + j) * 64 + lane;
        int rs = slot >> 3, ss = slot & 7, cs = ss ^ (rs & 7);
        arow[j] = (size_t)min(row0 + rs, d.M - 1) * d.K + cs * 8;
        ldsA[j] = As + (w * AI + j) * 512;
    }
    const int sb0 = (w * 2) * 64 + lane;
    const int sb1 = sb0 + 64;
    const int rb0 = sb0 >> 3, cb0 = (sb0 & 7) ^ (rb0 & 7);
    const int rb1 = sb1 >> 3, cb1 = (sb1 & 7) ^ (rb1 & 7);
    const size_t brow0 = (size_t)(col0 + rb0) * d.K + cb0 * 8;
    const size_t brow1 = (size_t)(col0 + rb1) * d.K + cb1 * 8;
    unsigned short* ldsB = Bs + (w * 2) * 512;

    int aoff0[MF], aoff1[MF];
    #pragma unroll
    for (int mf = 0; mf < MF; ++mf) {
        int rA = w * (TM / 4) + mf * 16 + cn, swA = rA & 7, abase = rA * 64;
        aoff0[mf] = abase + ((rj)     ^ swA) * 8;
        aoff1[mf] = abase + ((rj + 4) ^ swA) * 8;
    }

    f32x4 acc[MF][4] = {};

    for (int kt = 0; kt < d.K; kt += 64) {
        #pragma unroll
        for (int j = 0; j < AI; ++j) GLOAD_LDS16(d.A + arow[j] + kt, ldsA[j]);
        GLOAD_LDS16(d.BT + brow0 + kt, ldsB);
        GLOAD_LDS16(d.BT + brow1 + kt, ldsB + 512);
        __syncthreads();
        bf16x8 a0[MF], a1[MF];
        #pragma unroll
        for (int mf = 0; mf < MF; ++mf) {
            a0[mf] = *(const bf16x8*)&As[aoff0[mf]];
            a1[mf] = *(const bf16x8*)&As[aoff1[mf]];
        }
        #pragma unroll
        for (int f = 0; f < 4; ++f) {
            int rB = f * 16 + cn, swB = rB & 7, bb = rB * 64;
            bf16x8 b0 = *(const bf16x8*)&Bs[bb + ((rj)     ^ swB) * 8];
            bf16x8 b1 = *(const bf16x8*)&Bs[bb + ((rj + 4) ^ swB) * 8];
            #pragma unroll
            for (int mf = 0; mf < MF; ++mf) {
                acc[mf][f] = __builtin_amdgcn_mfma_f32_16x16x32_bf16(a0[mf], b0, acc[mf][f], 0, 0, 0);
                acc[mf][f] = __builtin_amdgcn_mfma_f32_16x16x32_bf16(a1[mf], b1, acc[mf][f], 0, 0, 0);
            }
        }
        __syncthreads();
    }

    if (TEPI) {
        // ---- LDS-transpose epilogue (TM=64): 256B-contiguous f32 writes ----
        float* Cs = (float*)smem;     // [64][65]
        __syncthreads();
        #pragma unroll
        for (int f = 0; f < 4; ++f)
            #pragma unroll
            for (int j = 0; j < 4; ++j)
                Cs[(w * 16 + rj * 4 + j) * 65 + f * 16 + cn] = acc[0][f][j];
        __syncthreads();
        #pragma unroll
        for (int i = 0; i < 4; ++i) {
            int slot = tid + i * 256;
            int rr = slot >> 4, c4 = (slot & 15) * 4;
            int gr = row0 + rr, gc = col0 + c4;
            if (gr < d.M && gc < d.N) {
                const float* cp = &Cs[rr * 65 + c4];
                float4 bv = BIAS ? *(const float4*)&d.bias[gc] : float4{0, 0, 0, 0};
                float4 v;
                v.x = cp[0] + bv.x; v.y = cp[1] + bv.y;
                v.z = cp[2] + bv.z; v.w = cp[3] + bv.w;
                *(float4*)&d.C[(size_t)gr * d.N + gc] = v;
            }
        }
    } else if (RSPLIT) {
        // ---- split epilogue: cols<256 -> relu(acc+b1+b2) -> Cbf (ld1);
        //      cols>=256 -> raw bf16 -> Cbf2 (ld2) ----
        #pragma unroll
        for (int mf = 0; mf < MF; ++mf) {
            #pragma unroll
            for (int f = 0; f < 4; ++f) {
                int col = col0 + f * 16 + cn;
                if (col >= d.N) continue;
                #pragma unroll
                for (int j = 0; j < 4; ++j) {
                    int r = row0 + w * (TM / 4) + mf * 16 + rj * 4 + j;
                    if (r < d.M) {
                        float val = acc[mf][f][j];
                        if (col < 256) {
                            val += d.bias[col] + d.bias2[col];
                            d.Cbf[(size_t)r * d.ld1 + col] = f2bf(fmaxf(val, 0.0f));
                        } else {
                            d.Cbf2[(size_t)r * d.ld2 + (col - 256)] = f2bf(val);
                        }
                    }
                }
            }
        }
    } else {
        // ---- direct epilogue [m89] ----
        #pragma unroll
        for (int mf = 0; mf < MF; ++mf) {
            #pragma unroll
            for (int f = 0; f < 4; ++f) {
                int col = col0 + f * 16 + cn;
                if (col >= d.N) continue;
                float bv = BIAS ? d.bias[col] : 0.0f;
                #pragma unroll
                for (int j = 0; j < 4; ++j) {
                    int r = row0 + w * (TM / 4) + mf * 16 + rj * 4 + j;
                    if (r < d.M) {
                        float val = acc[mf][f][j] + bv;
                        if (WF32) d.C[(size_t)r * d.N + col] = val;
                        if (WBF)  d.Cbf[(size_t)r * d.N + col] = f2bf(val);
                    }
                }
            }
        }
    }
}

// ================= raw neighbor gather (L0 cell side, 64-dim gene rows) =================
__global__ __launch_bounds__(256)
void rawgather_kernel(const int* __restrict__ ptr, const int* __restrict__ nbr,
                      const float* __restrict__ val,
                      const unsigned short* __restrict__ gx,   // genex_bf 4000x64
                      unsigned short* __restrict__ cellx)      // stride CELL_FX
{
    int w = threadIdx.x >> 6, lane = threadIdx.x & 63;
    int r = blockIdx.x * 4 + w;
    int s = ptr[r], e = ptr[r + 1];
    int g = lane >> 4, sub = lane & 15;
    const ushort4* gx4 = (const ushort4*)gx;      // 16 ushort4 per gene row
    float4 acc = {0.0f, 0.0f, 0.0f, 0.0f};
    for (int base = s; base < e; base += 16) {
        int nb = 0; float vb = 0.0f;
        if (lane < 16 && base + lane < e) { nb = nbr[base + lane]; vb = val[base + lane]; }
        #pragma unroll
        for (int jj = 0; jj < 4; ++jj) {
            int ei = jj * 4 + g;
            int j  = __shfl(nb, ei);
            float v = __shfl(vb, ei);
            ushort4 a = gx4[(size_t)j * 16 + sub];
            acc.x += v * bf2f(a.x);
            acc.y += v * bf2f(a.y);
            acc.z += v * bf2f(a.z);
            acc.w += v * bf2f(a.w);
        }
    }
    acc.x += __shfl_xor(acc.x, 16); acc.x += __shfl_xor(acc.x, 32);
    acc.y += __shfl_xor(acc.y, 16); acc.y += __shfl_xor(acc.y, 32);
    acc.z += __shfl_xor(acc.z, 16); acc.z += __shfl_xor(acc.z, 32);
    acc.w += __shfl_xor(acc.w, 16); acc.w += __shfl_xor(acc.w, 32);
    if (lane < 16) {
        ushort4 o;
        o.x = f2bf(acc.x); o.y = f2bf(acc.y); o.z = f2bf(acc.z); o.w = f2bf(acc.w);
        ((ushort4*)(cellx + (size_t)r * CELL_FX + 2048))[sub] = o;
    }
}

// ================= prep: count + input-cvt + weight packs =================
struct PackDesc {
    const float* W1; const float* W2; const float* W3; unsigned short* BT;
    int Kr, Kp, N1, N2, Np, xb, blk0, kcat;
};
struct PackArgs { PackDesc d[8]; };

#define CNT_BLK   2500
#define CVTC_BLK  10000
#define CVTG_BLK  125
#define PACK_BLK0 (CNT_BLK + CVTC_BLK + CVTG_BLK)

__global__ __launch_bounds__(256)
void prep_kernel(const int* __restrict__ er, const int* __restrict__ ec,
                 int* __restrict__ cnt_c, int* __restrict__ cnt_g,
                 const float* __restrict__ cell_x, unsigned short* __restrict__ cellx_bf,
                 const float* __restrict__ gene_x, unsigned short* __restrict__ genex_bf,
                 PackArgs pa)
{
    __shared__ float tile[32][33];
    int b = blockIdx.x;
    int tid = threadIdx.x;
    if (b < CNT_BLK) {
        int e = b * 256 + tid;
        atomicAdd(&cnt_c[er[e]], 1);
        atomicAdd(&cnt_g[ec[e]], 1);
        return;
    }
    if (b < CNT_BLK + CVTC_BLK) {
        int row = b - CNT_BLK;
        int col = tid * 8;                 // cols 0:2048 (neigh cols from rawgather)
        u16x8 v = {0, 0, 0, 0, 0, 0, 0, 0};
        if (col < CELL_F) {
            const float* src = cell_x + (size_t)row * CELL_F + col;
            float4 f0 = *(const float4*)src;
            float4 f1 = *(const float4*)(src + 4);
            v[0] = f2bf(f0.x); v[1] = f2bf(f0.y); v[2] = f2bf(f0.z); v[3] = f2bf(f0.w);
            v[4] = f2bf(f1.x); v[5] = f2bf(f1.y); v[6] = f2bf(f1.z); v[7] = f2bf(f1.w);
        }
        ((u16x8*)(cellx_bf + (size_t)row * CELL_FX))[tid] = v;
        return;
    }
    if (b < PACK_BLK0) {
        int idx = (b - CNT_BLK - CVTC_BLK) * 256 + tid;
        int row = idx >> 3, c8 = idx & 7;
        int col = c8 * 8;
        u16x8 v = {0, 0, 0, 0, 0, 0, 0, 0};
        #pragma unroll
        for (int j = 0; j < 8; ++j)
            if (col + j < GENE_F) v[j] = f2bf(gene_x[(size_t)row * GENE_F + col + j]);
        ((u16x8*)(genex_bf + (size_t)row * GENE_FP))[c8] = v;
        return;
    }
    int pb = b;
    int p = 0;
    #pragma unroll
    for (int i = 1; i < 8; ++i) if (pb >= pa.d[i].blk0) p = i;
    const PackDesc d = pa.d[p];
    int local = pb - d.blk0;
    int kb = local % d.xb, nb = local / d.xb;
    int k0 = kb * 32, n0 = nb * 32;
    int tx = tid & 31, ty = tid >> 5;
    #pragma unroll
    for (int yy = 0; yy < 4; ++yy) {
        int k = k0 + ty + yy * 8;
        int n = n0 + tx;
        float v = 0.0f;
        if (d.kcat) {
            // K-concat: rows 0:256 = W1, rows 256:512 = W2 (both KxN1, N=Np)
            if (n < d.Np)
                v = (k < 256) ? d.W1[(size_t)k * d.N1 + n]
                              : d.W2[(size_t)(k - 256) * d.N1 + n];
        } else if (k < d.Kr) {
            if (n < d.N1) v = d.W1[(size_t)k * d.N1 + n];
            else if (n < d.N1 + d.N2) v = d.W2[(size_t)k * d.N2 + (n - d.N1)];
        } else if (d.W3 && k >= 2048) {
            int kk = k - 2048;                       // cn_w zone: K rows 2048:2112
            if (kk < GENE_F && n < HID) v = d.W3[(size_t)kk * HID + n];
        }
        tile[ty + yy * 8][tx] = v;
    }
    __syncthreads();
    #pragma unroll
    for (int yy = 0; yy < 4; ++yy) {
        int n = n0 + ty + yy * 8;
        int k = k0 + tx;
        if (n < d.Np)
            d.BT[(size_t)n * d.Kp + k] = f2bf(tile[tx][ty + yy * 8]);
    }
}

// ================= CSR scan =================
__global__ __launch_bounds__(1024)
void scan2_kernel(const int* __restrict__ cnt_c, int* __restrict__ ptr_c, int* __restrict__ cur_c,
                  const int* __restrict__ cnt_g, int* __restrict__ ptr_g, int* __restrict__ cur_g)
{
    const int* cnt = blockIdx.x ? cnt_g : cnt_c;
    int* ptr = blockIdx.x ? ptr_g : ptr_c;
    int* cur = blockIdx.x ? cur_g : cur_c;
    int  n   = blockIdx.x ? N_GENES : N_CELLS;
    __shared__ int part[1024];
    int t = threadIdx.x;
    int chunk = (n + 1023) / 1024;
    int lo = t * chunk, hi = min(lo + chunk, n);
    int s = 0;
    for (int i = lo; i < hi; ++i) s += cnt[i];
    part[t] = s;
    __syncthreads();
    #pragma unroll
    for (int off = 1; off < 1024; off <<= 1) {
        int v = (t >= off) ? part[t - off] : 0;
        __syncthreads();
        part[t] += v;
        __syncthreads();
    }
    if (t == 1023) ptr[n] = part[1023];
    int run = part[t] - s;
    for (int i = lo; i < hi; ++i) { ptr[i] = run; cur[i] = run; run += cnt[i]; }
}

// ================= agg (gene L0): gather + pre + biases + relu =================
struct AggSide {
    const int *ptr, *nbr; const float *val;
    const unsigned short *src, *pre;
    const float *b1, *b2;
    unsigned short *out;
    int srcRow4, srcOff4, preRow, outLd;
};

__global__ __launch_bounds__(256)
void agg1_kernel(AggSide S)
{
    __shared__ __align__(16) float red[4][256];
    int r = blockIdx.x;
    int t = threadIdx.x;
    int w = t >> 6;
    int lane = t & 63;
    int s = S.ptr[r], e = S.ptr[r + 1];
    int n = e - s;
    int chunk = (n + 3) >> 2;
    int ws = s + w * chunk;
    int we = min(ws + chunk, e);
    const ushort4* src4 = (const ushort4*)S.src;
    float4 acc = {0.0f, 0.0f, 0.0f, 0.0f};
    for (int base = ws; base < we; base += 16) {
        int   nb = 0;
        float vb = 0.0f;
        if (lane < 16 && base + lane < we) {
            nb = S.nbr[base + lane];
            vb = S.val[base + lane];
        }
        #pragma unroll
        for (int j = 0; j < 16; ++j) {
            int   jj = __shfl(nb, j);
            float vv = __shfl(vb, j);
            ushort4 a = src4[(size_t)jj * S.srcRow4 + S.srcOff4 + lane];
            acc.x += vv * bf2f(a.x);
            acc.y += vv * bf2f(a.y);
            acc.z += vv * bf2f(a.z);
            acc.w += vv * bf2f(a.w);
        }
    }
    *(float4*)&red[w][lane * 4] = acc;
    __syncthreads();
    float x = red[0][t] + red[1][t] + red[2][t] + red[3][t]
            + bf2f(S.pre[(size_t)r * S.preRow + t]) + S.b1[t] + S.b2[t];
    S.out[(size_t)r * S.outLd + t] = f2bf(fmaxf(x, 0.0f));
}

// ================= neighsum (L1): raw gather -> bf16 K-ext columns =================
struct NsSide {
    const int *ptr, *nbr; const float *val;
    const unsigned short *src;
    unsigned short *out;
    int srcRow4, srcOff4, outLd, outOff;
};
struct NsArgs { NsSide s[2]; int n0; };

__global__ __launch_bounds__(256)
void neighsum_kernel(NsArgs na)
{
    __shared__ __align__(16) float red[4][256];
    int b = blockIdx.x;
    int side = (b >= na.n0) ? 1 : 0;
    const NsSide S = na.s[side];
    int r = side ? b - na.n0 : b;
    int t = threadIdx.x;
    int w = t >> 6;
    int lane = t & 63;
    int s = S.ptr[r], e = S.ptr[r + 1];
    int n = e - s;
    int chunk = (n + 3) >> 2;
    int ws = s + w * chunk;
    int we = min(ws + chunk, e);
    const ushort4* src4 = (const ushort4*)S.src;
    float4 acc = {0.0f, 0.0f, 0.0f, 0.0f};
    for (int base = ws; base < we; base += 16) {
        int   nb = 0;
        float vb = 0.0f;
        if (lane < 16 && base + lane < we) {
            nb = S.nbr[base + lane];
            vb = S.val[base + lane];
        }
        #pragma unroll
        for (int j = 0; j < 16; ++j) {
            int   jj = __shfl(nb, j);
            float vv = __shfl(vb, j);
            ushort4 a = src4[(size_t)jj * S.srcRow4 + S.srcOff4 + lane];
            acc.x += vv * bf2f(a.x);
            acc.y += vv * bf2f(a.y);
            acc.z += vv * bf2f(a.z);
            acc.w += vv * bf2f(a.w);
        }
    }
    *(float4*)&red[w][lane * 4] = acc;
    __syncthreads();
    float x = red[0][t] + red[1][t] + red[2][t] + red[3][t];
    S.out[(size_t)r * S.outLd + S.outOff + t] = f2bf(x);
}

extern "C" void kernel_launch(void* const* d_in, const int* in_sizes, int n_in,
                              void* d_out, int out_size, void* d_ws, size_t ws_size,
                              hipStream_t stream)
{
    const float* cell_x  = (const float*)d_in[0];
    const float* gene_x  = (const float*)d_in[1];
    const int*   er      = (const int*)d_in[2];
    const int*   ec      = (const int*)d_in[3];
    const float* ev      = (const float*)d_in[4];
    const float* l0_cs_w = (const float*)d_in[5];  const float* l0_cs_b = (const float*)d_in[6];
    const float* l0_cn_w = (const float*)d_in[7];  const float* l0_cn_b = (const float*)d_in[8];
    const float* l0_gs_w = (const float*)d_in[9];  const float* l0_gs_b = (const float*)d_in[10];
    const float* l0_gn_w = (const float*)d_in[11]; const float* l0_gn_b = (const float*)d_in[12];
    const float* l1_cs_w = (const float*)d_in[13]; const float* l1_cs_b = (const float*)d_in[14];
    const float* l1_cn_w = (const float*)d_in[15]; const float* l1_cn_b = (const float*)d_in[16];
    const float* l1_gs_w = (const float*)d_in[17]; const float* l1_gs_b = (const float*)d_in[18];
    const float* l1_gn_w = (const float*)d_in[19]; const float* l1_gn_b = (const float*)d_in[20];
    const float* cl_w = (const float*)d_in[21]; const float* cl_b = (const float*)d_in[22];
    const float* gl_w = (const float*)d_in[23]; const float* gl_b = (const float*)d_in[24];
    const float* cd_w = (const float*)d_in[25]; const float* cd_b = (const float*)d_in[26];
    const float* gd_w = (const float*)d_in[27]; const float* gd_b = (const float*)d_in[28];
    const float* centers = (const float*)d_in[29];

    float* out = (float*)d_out;
    float* z_cells    = out;
    float* z_genes    = out + 640000;
    float* cell_recon = out + 896000;
    float* gene_recon = out + 40896000;
    float* q          = out + 80896000;

    // ---- workspace arena ----
    char* wsp = (char*)d_ws;
    auto alloc = [&](size_t bytes) -> void* {
        void* p = (void*)wsp;
        wsp += (bytes + 255) & ~(size_t)255;
        return p;
    };
    unsigned short* c1x_bf   = (unsigned short*)alloc((size_t)N_CELLS * 512 * 2);  // [c1 | A@g1]
    unsigned short* g1x_bf   = (unsigned short*)alloc((size_t)N_GENES * 512 * 2);  // [g1 | A^T@c1]
    unsigned short* pre_gs_bf  = (unsigned short*)alloc((size_t)N_GENES * 256 * 2);
    unsigned short* pre_cgn_bf = (unsigned short*)alloc((size_t)N_CELLS * 256 * 2);
    unsigned short* c2_bf    = (unsigned short*)alloc((size_t)N_CELLS * 256 * 2);
    unsigned short* g2_bf    = (unsigned short*)alloc((size_t)N_GENES * 256 * 2);
    unsigned short* zc_bf    = (unsigned short*)alloc((size_t)N_CELLS * 64 * 2);
    unsigned short* zg_bf    = (unsigned short*)alloc((size_t)N_GENES * 64 * 2);
    unsigned short* cellx_bf = (unsigned short*)alloc((size_t)N_CELLS * CELL_FX * 2);
    unsigned short* genex_bf = (unsigned short*)alloc((size_t)N_GENES * GENE_FP * 2);
    unsigned short* W0cT = (unsigned short*)alloc((size_t)512 * CELL_FX * 2);
    unsigned short* W0gT = (unsigned short*)alloc((size_t)256 * GENE_FP * 2);
    unsigned short* W1cT = (unsigned short*)alloc((size_t)256 * 512 * 2);
    unsigned short* W1gT = (unsigned short*)alloc((size_t)256 * 512 * 2);
    unsigned short* WzcT = (unsigned short*)alloc((size_t)64 * HID * 2);
    unsigned short* WzgT = (unsigned short*)alloc((size_t)64 * HID * 2);
    unsigned short* WdcT = (unsigned short*)alloc((size_t)4032 * 64 * 2);
    unsigned short* WdgT = (unsigned short*)alloc((size_t)10048 * 64 * 2);
    int* cnt_c = (int*)alloc((size_t)(N_CELLS + N_GENES) * 4);
    int* cnt_g = cnt_c + N_CELLS;
    int* ptr_c = (int*)alloc((size_t)(N_CELLS + 1) * 4);
    int* ptr_g = (int*)alloc((size_t)(N_GENES + 1) * 4);
    int* cur_c = (int*)alloc((size_t)N_CELLS * 4);
    int* cur_g = (int*)alloc((size_t)N_GENES * 4);
    int*   ci = (int*)alloc((size_t)N_EDGES * 4);
    float* cv = (float*)alloc((size_t)N_EDGES * 4);
    int*   gi = (int*)alloc((size_t)N_EDGES * 4);
    float* gv = (float*)alloc((size_t)N_EDGES * 4);

    // ---- D1: zero counters ----
    hipMemsetAsync(cnt_c, 0, (size_t)(N_CELLS + N_GENES) * 4, stream);

    // ---- D2: count + input cvt + weight packs ----
    {
        PackArgs pa;
        auto set = [&](int i, const float* W1, const float* W2, const float* W3,
                       unsigned short* BT, int Kr, int Kp, int N1, int N2, int Np,
                       int kcat, int blk0) -> int {
            int xb = Kp / 32, yb = Np / 32;
            pa.d[i] = {W1, W2, W3, BT, Kr, Kp, N1, N2, Np, xb, blk0, kcat};
            return blk0 + xb * yb;
        };
        int nb = PACK_BLK0;
        nb = set(0, l0_cs_w, l0_gn_w, l0_cn_w, W0cT, CELL_F, CELL_FX, HID, HID, 512, 0, nb);
        nb = set(1, l0_gs_w, nullptr, nullptr, W0gT, GENE_F, GENE_FP, HID, 0, 256, 0, nb);
        nb = set(2, l1_cs_w, l1_cn_w, nullptr, W1cT, 512, 512, HID, 0, 256, 1, nb);
        nb = set(3, l1_gs_w, l1_gn_w, nullptr, W1gT, 512, 512, HID, 0, 256, 1, nb);
        nb = set(4, cl_w, nullptr, nullptr, WzcT, HID, HID, LAT, 0, 64, 0, nb);
        nb = set(5, gl_w, nullptr, nullptr, WzgT, HID, HID, LAT, 0, 64, 0, nb);
        nb = set(6, cd_w, nullptr, nullptr, WdcT, LAT, LAT, N_GENES, 0, 4032, 0, nb);
        nb = set(7, gd_w, nullptr, nullptr, WdgT, LAT, LAT, N_CELLS, 0, 10048, 0, nb);
        prep_kernel<<<nb, 256, 0, stream>>>(er, ec, cnt_c, cnt_g,
                                            cell_x, cellx_bf, gene_x, genex_bf, pa);
    }

    // ---- D3: scan (seeds cur = ptr) ----
    scan2_kernel<<<2, 1024, 0, stream>>>(cnt_c, ptr_c, cur_c, cnt_g, ptr_g, cur_g);

    auto mkdesc = [](const unsigned short* A, const unsigned short* BT, const float* bias,
                     float* C, unsigned short* Cbf, int M, int N, int K, int TMv,
                     int blk0) -> GemmDesc {
        int gx = (N + 63) / 64, gy = (M + TMv - 1) / TMv;
        return {A, BT, bias, C, Cbf, M, N, K, gx, gx * gy, blk0, nullptr, nullptr, 0, 0};
    };
    ScatArgs sa0 = {er, ec, ev, cur_c, cur_g, ci, cv, gi, gv};
    ScatArgs saN = {};

    // ---- D4: scatter + gene L0 GEMM (N=256 self-projection only) ----
    {
        GemmArgs2 ga;
        ga.d[0] = mkdesc(genex_bf, W0gT, nullptr, nullptr, pre_gs_bf, N_GENES, 256, GENE_FP, 128, CNT_BLK);
        ga.d[1] = ga.d[0]; ga.d[1].blk0 = 1 << 30;
        gemm_multi<128, false, false, true, false, false, true, false>
            <<<CNT_BLK + ga.d[0].nwg, 256, 0, stream>>>(
            ga, CNT_BLK, 1 << 30, nullptr, nullptr, nullptr, sa0);
    }

    // ---- D5: raw gene-feature gather into cellx_bf[:, 2048:2112] ----
    rawgather_kernel<<<N_CELLS / 4, 256, 0, stream>>>(ptr_c, ci, cv, genex_bf, cellx_bf);

    // ---- D6: cell L0 GEMM (K=2112; split epilogue -> c1x[:,0:256] + pre_cgn) ----
    {
        GemmArgs2 ga;
        ga.d[0] = mkdesc(cellx_bf, W0cT, l0_cs_b, nullptr, c1x_bf, N_CELLS, 512, CELL_FX, 128, 0);
        ga.d[0].bias2 = l0_cn_b;
        ga.d[0].Cbf2  = pre_cgn_bf;
        ga.d[0].ld1 = 512; ga.d[0].ld2 = 256;
        ga.d[1] = ga.d[0]; ga.d[1].blk0 = 1 << 30;
        gemm_multi<128, false, false, false, false, false, false, true>
            <<<ga.d[0].nwg, 256, 0, stream>>>(
            ga, 0, 1 << 30, nullptr, nullptr, nullptr, saN);
    }

    // ---- D7: L0 gene aggregation (gather pre_cgn) -> g1x[:,0:256] ----
    {
        AggSide S = {ptr_g, gi, gv, pre_cgn_bf, pre_gs_bf, l0_gs_b, l0_gn_b,
                     g1x_bf, 64, 0, 256, 512};
        agg1_kernel<<<N_GENES, 256, 0, stream>>>(S);
    }

    // ---- D8: L1 neighbor sums -> K-ext columns (both sides) ----
    {
        NsArgs na;
        na.n0 = N_CELLS;
        na.s[0] = {ptr_c, ci, cv, g1x_bf, c1x_bf, 128, 0, 512, 256};   // A@g1 -> c1x[:,256:512]
        na.s[1] = {ptr_g, gi, gv, c1x_bf, g1x_bf, 128, 0, 512, 256};   // A^T@c1 -> g1x[:,256:512]
        neighsum_kernel<<<N_CELLS + N_GENES, 256, 0, stream>>>(na);
    }

    // ---- D9: L1 GEMMs (K=512, N=256, fused relu+biases -> c2, g2) ----
    {
        GemmArgs2 ga;
        ga.d[0] = mkdesc(c1x_bf, W1cT, l1_cs_b, nullptr, c2_bf, N_CELLS, 256, 512, 128, 0);
        ga.d[0].bias2 = l1_cn_b; ga.d[0].ld1 = 256;
        ga.d[1] = mkdesc(g1x_bf, W1gT, l1_gs_b, nullptr, g2_bf, N_GENES, 256, 512, 128,
                         ga.d[0].nwg);
        ga.d[1].bias2 = l1_gn_b; ga.d[1].ld1 = 256;
        gemm_multi<128, false, false, false, false, false, false, true>
            <<<ga.d[1].blk0 + ga.d[1].nwg, 256, 0, stream>>>(
            ga, 0, 1 << 30, nullptr, nullptr, nullptr, saN);
    }

    // ---- D10: latent heads (TM=64) ----
    {
        GemmArgs2 ga;
        ga.d[0] = mkdesc(c2_bf, WzcT, cl_b, z_cells, zc_bf, N_CELLS, LAT, HID, 64, 0);
        ga.d[1] = mkdesc(g2_bf, WzgT, gl_b, z_genes, zg_bf, N_GENES, LAT, HID, 64, ga.d[0].nwg);
        gemm_multi<64, true, true, true, false, false, false, false>
            <<<ga.d[1].blk0 + ga.d[1].nwg, 256, 0, stream>>>(
            ga, 0, 1 << 30, nullptr, nullptr, nullptr, saN);
    }

    // ---- D11: decoders (TM=64, transpose epilogue) + q tail ----
    {
        GemmArgs2 ga;
        ga.d[0] = mkdesc(zc_bf, WdcT, cd_b, cell_recon, nullptr, N_CELLS, N_GENES, LAT, 64, 0);
        ga.d[1] = mkdesc(zg_bf, WdgT, gd_b, gene_recon, nullptr, N_GENES, N_CELLS, LAT, 64,
                         ga.d[0].nwg);
        int qstart = ga.d[1].blk0 + ga.d[1].nwg;
        int qblocks = (N_CELLS + 255) / 256;
        gemm_multi<64, true, true, false, true, true, false, false>
            <<<qstart + qblocks, 256, 0, stream>>>(
            ga, 0, qstart, z_cells, centers, q, saN);
    }
}